// Round 4
// baseline (545.167 us; speedup 1.0000x reference)
//
#include <hip/hip_runtime.h>

typedef unsigned short u16;
typedef __attribute__((ext_vector_type(8))) short short8;
typedef __attribute__((ext_vector_type(4))) float f32x4;

#define DD 1024
#define NN 1024
#define MODS_LD 9216

__device__ __forceinline__ float bf2f(u16 v) {
  unsigned int u = ((unsigned int)v) << 16;
  return __builtin_bit_cast(float, u);
}
__device__ __forceinline__ u16 f2bf(float f) {
  unsigned int u = __builtin_bit_cast(unsigned int, f);
  unsigned int lsb = (u >> 16) & 1;
  u += 0x7fffu + lsb;
  return (u16)(u >> 16);
}

__device__ __forceinline__ void gload_lds16(const u16* g, u16* l) {
  __builtin_amdgcn_global_load_lds(
      (const __attribute__((address_space(1))) unsigned int*)g,
      (__attribute__((address_space(3))) unsigned int*)l, 16, 0, 0);
}

// ---------------- weight transpose + fp32->bf16 -------------------------
__global__ void transpose_convert(const float* __restrict__ src, u16* __restrict__ dst,
                                  int R, int C, int R2, int C2) {
  __shared__ float tile[32][33];
  int tx = threadIdx.x, ty = threadIdx.y;
  int r0 = blockIdx.x * 32, c0 = blockIdx.y * 32;
#pragma unroll
  for (int i = 0; i < 4; ++i) {
    int r = r0 + ty + i * 8, c = c0 + tx;
    tile[ty + i * 8][tx] = (r < R && c < C) ? src[(long)r * C + c] : 0.f;
  }
  __syncthreads();
#pragma unroll
  for (int i = 0; i < 4; ++i) {
    int c = c0 + ty + i * 8, r = r0 + tx;
    if (c < C2 && r < R2) dst[(long)c * R2 + r] = f2bf(tile[tx][ty + i * 8]);
  }
}

// ---------------- fp32 -> bf16 (vector) ---------------------------------
__global__ void cvt_bf16_kernel(const float* __restrict__ in, u16* __restrict__ out, long n4) {
  long i = (long)blockIdx.x * 256 + threadIdx.x;
  if (i >= n4) return;
  float4 v = *(const float4*)&in[i * 4];
  ushort4 pk = {f2bf(v.x), f2bf(v.y), f2bf(v.z), f2bf(v.w)};
  *(ushort4*)&out[i * 4] = pk;
}

// ---------------- silu(c) + mods matvec (k-split, deterministic) ----------
__global__ void silu_kernel(const float* __restrict__ c, float* __restrict__ sc) {
  int i = blockIdx.x * 256 + threadIdx.x;
  float v = c[i];
  sc[i] = v / (1.f + __expf(-v));
}

#define MODS_KS 32
__global__ __launch_bounds__(256) void mods_partial(const float* __restrict__ sc,
                                                    const float* __restrict__ aw,
                                                    float* __restrict__ part) {
  int j = blockIdx.x * 256 + threadIdx.x;
  int ks = blockIdx.y;
  int d0 = ks * (DD / MODS_KS);
  float a0 = 0.f, a1 = 0.f, a2 = 0.f, a3 = 0.f;
#pragma unroll 8
  for (int d = d0; d < d0 + DD / MODS_KS; ++d) {
    float w = aw[(long)d * MODS_LD + j];
    a0 = fmaf(sc[d], w, a0);
    a1 = fmaf(sc[DD + d], w, a1);
    a2 = fmaf(sc[2 * DD + d], w, a2);
    a3 = fmaf(sc[3 * DD + d], w, a3);
  }
  long base = (long)ks * 4 * MODS_LD + j;
  part[base] = a0;
  part[base + MODS_LD] = a1;
  part[base + 2 * MODS_LD] = a2;
  part[base + 3 * MODS_LD] = a3;
}

__global__ __launch_bounds__(256) void mods_reduce(const float* __restrict__ part,
                                                   const float* __restrict__ ab,
                                                   float* __restrict__ mods) {
  int j = blockIdx.x * 256 + threadIdx.x;
  int b = blockIdx.y;
  float acc = ab[j];
#pragma unroll
  for (int ks = 0; ks < MODS_KS; ++ks) acc += part[((long)ks * 4 + b) * MODS_LD + j];
  mods[(long)b * MODS_LD + j] = acc;
}

// ---------------- fused RMSNorm + modulate -> bf16 ------------------------
__global__ __launch_bounds__(256) void rmsmod_kernel(const float* __restrict__ x,
                                                     const float* __restrict__ w,
                                                     const float* __restrict__ mods,
                                                     int shiftOff, int scaleOff,
                                                     u16* __restrict__ out) {
  long row = blockIdx.x;
  int b = (int)(row >> 10);
  int t = threadIdx.x;
  const float* xr = x + row * DD;
  float4 v = *(const float4*)&xr[t * 4];
  float ss = v.x * v.x + v.y * v.y + v.z * v.z + v.w * v.w;
#pragma unroll
  for (int msk = 1; msk < 64; msk <<= 1) ss += __shfl_xor(ss, msk);
  __shared__ float red[4];
  if ((t & 63) == 0) red[t >> 6] = ss;
  __syncthreads();
  float tot = red[0] + red[1] + red[2] + red[3];
  float inv = rsqrtf(tot * (1.f / DD) + 1e-6f);
  const float* mrow = mods + (long)b * MODS_LD;
  float vv[4] = {v.x, v.y, v.z, v.w};
  u16 tmp[4];
#pragma unroll
  for (int j = 0; j < 4; ++j) {
    int c = t * 4 + j;
    float rr = vv[j] * inv * w[c] * (1.f + mrow[scaleOff + c]) + mrow[shiftOff + c];
    tmp[j] = f2bf(rr);
  }
  ushort4 pk = {tmp[0], tmp[1], tmp[2], tmp[3]};
  *(ushort4*)&out[row * DD + t * 4] = pk;
}

// ---------------- q/k head-RMS-norm, in-place, vectorized -----------------
__global__ __launch_bounds__(256) void qknorm_kernel(u16* __restrict__ buf, int ld,
                                                     const float* __restrict__ w, float scale) {
  long row = blockIdx.x;
  int t = threadIdx.x;
  int g = t >> 4, p = t & 15;
  u16* ptr = buf + row * ld + g * 64 + p * 4;
  ushort4 a = *(ushort4*)ptr;
  float v[4] = {bf2f(a.x), bf2f(a.y), bf2f(a.z), bf2f(a.w)};
  float ss = v[0] * v[0] + v[1] * v[1] + v[2] * v[2] + v[3] * v[3];
  ss += __shfl_xor(ss, 1);
  ss += __shfl_xor(ss, 2);
  ss += __shfl_xor(ss, 4);
  ss += __shfl_xor(ss, 8);
  float inv = rsqrtf(ss * (1.f / 64) + 1e-6f) * scale;
  u16 o[4];
#pragma unroll
  for (int j = 0; j < 4; ++j) o[j] = f2bf(v[j] * inv * w[p * 4 + j]);
  ushort4 pk = {o[0], o[1], o[2], o[3]};
  *(ushort4*)ptr = pk;
}

// ---------------- V pre-transpose: v[b, kv, (h,d)] -> vt[(b,h), d, kv] -----
__global__ void vtrans_kernel(const u16* __restrict__ vb, int kvStride, int Mpb,
                              u16* __restrict__ vt) {
  __shared__ u16 tile[64][66];
  int t = threadIdx.x;
  int kt = blockIdx.x, h = blockIdx.y, b = blockIdx.z;
  const u16* base = vb + ((long)(b * Mpb + kt * 64)) * kvStride + h * 64;
#pragma unroll
  for (int sh = 0; sh < 2; ++sh) {
    int r = sh * 32 + (t >> 3);
    int c0 = (t & 7) * 8;
    short8 vv = *(const short8*)(base + (long)r * kvStride + c0);
#pragma unroll
    for (int j = 0; j < 8; ++j) tile[c0 + j][r] = (u16)vv[j];
  }
  __syncthreads();
  u16* obase = vt + ((long)(b * 16 + h) * 64) * 1024 + kt * 64;
#pragma unroll
  for (int sh = 0; sh < 2; ++sh) {
    int d = sh * 32 + (t >> 3);
    int c0 = (t & 7) * 8;
    u16 tmp[8];
#pragma unroll
    for (int j = 0; j < 8; ++j) tmp[j] = tile[d][c0 + j];
    *(short8*)(obase + (long)d * 1024 + c0) = *(short8*)tmp;
  }
}

// ---------------- small GEMM (128x128 tiles) ------------------------------
// MODE 0: outb = bf16(acc+bias).  MODE 1: outf = xin + gate*(acc+bias)
template <int MODE>
__global__ __launch_bounds__(256, 2) void gemm_bf16(
    const u16* __restrict__ A, const u16* __restrict__ Bt, int K, int ldc,
    const float* __restrict__ bias, int biasN, u16* __restrict__ outb,
    float* __restrict__ outf, const float* __restrict__ xin,
    const float* __restrict__ mods, int gateOff) {
  __shared__ u16 As[128 * 64];
  __shared__ u16 Bs[128 * 64];
  int t = threadIdx.x;
  int l = t & 63, w = t >> 6;
  int wr = w >> 1, wc = w & 1;
  int lg = l >> 4, ll = l & 15;
  long rowTile = (long)blockIdx.y * 128;
  long colTile = (long)blockIdx.x * 128;
  const u16* Ap = A + rowTile * K;
  const u16* Bp = Bt + colTile * K;
  int srow = t >> 3;
  int scol = (t & 7) * 8;

  f32x4 acc[4][4] = {};

  for (int k0 = 0; k0 < K; k0 += 64) {
#pragma unroll
    for (int i = 0; i < 4; ++i)
      gload_lds16(Ap + (long)(i * 32 + srow) * K + k0 + scol, &As[(i * 256 + t) * 8]);
#pragma unroll
    for (int i = 0; i < 4; ++i)
      gload_lds16(Bp + (long)(i * 32 + srow) * K + k0 + scol, &Bs[(i * 256 + t) * 8]);
    __syncthreads();
#pragma unroll
    for (int kk = 0; kk < 2; ++kk) {
      short8 af[4], bfr[4];
#pragma unroll
      for (int m2 = 0; m2 < 4; ++m2)
        af[m2] = *(const short8*)&As[(wr * 64 + m2 * 16 + ll) * 64 + kk * 32 + lg * 8];
#pragma unroll
      for (int n2 = 0; n2 < 4; ++n2)
        bfr[n2] = *(const short8*)&Bs[(wc * 64 + n2 * 16 + ll) * 64 + kk * 32 + lg * 8];
#pragma unroll
      for (int m2 = 0; m2 < 4; ++m2)
#pragma unroll
        for (int n2 = 0; n2 < 4; ++n2)
          acc[m2][n2] =
              __builtin_amdgcn_mfma_f32_16x16x32_bf16(af[m2], bfr[n2], acc[m2][n2], 0, 0, 0);
    }
    __syncthreads();
  }
#pragma unroll
  for (int n2 = 0; n2 < 4; ++n2) {
    long cg = colTile + wc * 64 + n2 * 16 + ll;
    float bv = (cg < biasN) ? bias[cg] : 0.f;
#pragma unroll
    for (int m2 = 0; m2 < 4; ++m2) {
#pragma unroll
      for (int r = 0; r < 4; ++r) {
        long rg = rowTile + wr * 64 + m2 * 16 + lg * 4 + r;
        float v = acc[m2][n2][r] + bv;
        long idx = rg * ldc + cg;
        if (MODE == 0) {
          outb[idx] = f2bf(v);
        } else {
          int bb = (int)(rg >> 10);
          outf[idx] = xin[idx] + mods[(long)bb * MODS_LD + gateOff + cg] * v;
        }
      }
    }
  }
}

// ---------------- big GEMM: 256x256 tile, 8-phase schedule (m201 port) -----
// A: rows x K bf16, Bt: cols x K bf16, C = A @ Bt^T + bias -> bf16.
// M fixed 4096 (GM=16). Grid = GM*GN, must be %8==0 for XCD swizzle.
// LDS: [dbuf][half] 128x64 per operand; chunk^(row&7) swizzle both sides.

#define LDA256(PBUF, MH)                                                          \
  {                                                                               \
    const u16* Ab = &As[PBUF][wr][0];                                             \
    _Pragma("unroll") for (int mq_ = 0; mq_ < 4; ++mq_)                           \
        _Pragma("unroll") for (int ks_ = 0; ks_ < 2; ++ks_) {                     \
      int rowl_ = ((MH)*4 + mq_) * 16 + ll;                                       \
      a[mq_][ks_] =                                                               \
          *(const short8*)&Ab[rowl_ * 64 + (((ks_ * 4 + lg) ^ (ll & 7)) << 3)];   \
    }                                                                             \
  }

#define LDB256(PBUF, NH, BR)                                                      \
  {                                                                               \
    const u16* Bb = &Bs[PBUF][wc >> 1][0];                                        \
    _Pragma("unroll") for (int nq_ = 0; nq_ < 2; ++nq_)                           \
        _Pragma("unroll") for (int ks_ = 0; ks_ < 2; ++ks_) {                     \
      int coll_ = (wc & 1) * 64 + ((NH)*2 + nq_) * 16 + ll;                       \
      BR[nq_][ks_] =                                                              \
          *(const short8*)&Bb[coll_ * 64 + (((ks_ * 4 + lg) ^ (ll & 7)) << 3)];   \
    }                                                                             \
  }

#define STAGE_A256(PBUF, H, KT)                                                   \
  if ((KT) < nt) {                                                                \
    _Pragma("unroll") for (int i_ = 0; i_ < 2; ++i_) {                            \
      int idx_ = i_ * 512 + t;                                                    \
      int rw_ = idx_ >> 3;                                                        \
      int sc_ = (idx_ & 7) ^ (rw_ & 7);                                           \
      gload_lds16(Aglob + (long)(rowTile + (H)*128 + rw_) * K + (KT)*64 + sc_ * 8,\
                  &As[PBUF][H][idx_ * 8]);                                        \
    }                                                                             \
  }

#define STAGE_B256(PBUF, H, KT)                                                   \
  if ((KT) < nt) {                                                                \
    _Pragma("unroll") for (int i_ = 0; i_ < 2; ++i_) {                            \
      int idx_ = i_ * 512 + t;                                                    \
      int rw_ = idx_ >> 3;                                                        \
      int sc_ = (idx_ & 7) ^ (rw_ & 7);                                           \
      gload_lds16(Bglob + (long)(colTile + (H)*128 + rw_) * K + (KT)*64 + sc_ * 8,\
                  &Bs[PBUF][H][idx_ * 8]);                                        \
    }                                                                             \
  }

#define MFMA_Q(MH, NH, BR)                                                        \
  _Pragma("unroll") for (int mq_ = 0; mq_ < 4; ++mq_)                             \
      _Pragma("unroll") for (int nq_ = 0; nq_ < 2; ++nq_)                         \
          _Pragma("unroll") for (int ks_ = 0; ks_ < 2; ++ks_)                     \
              acc[(MH)*4 + mq_][(NH)*2 + nq_] =                                   \
      __builtin_amdgcn_mfma_f32_16x16x32_bf16(                                    \
          a[mq_][ks_], BR[nq_][ks_], acc[(MH)*4 + mq_][(NH)*2 + nq_], 0, 0, 0);

#define PH_MFMA(MH, NH, BR)                                                       \
  __builtin_amdgcn_s_barrier();                                                   \
  asm volatile("s_waitcnt lgkmcnt(0)" ::: "memory");                              \
  __builtin_amdgcn_sched_barrier(0);                                              \
  __builtin_amdgcn_s_setprio(1);                                                  \
  MFMA_Q(MH, NH, BR);                                                             \
  __builtin_amdgcn_s_setprio(0);

// one K-tile (= 4 phases). P = dbuf of tile TT, Q = other dbuf.
#define HALF256(P, Q, TT)                                                         \
  LDA256(P, 0);                                                                   \
  LDB256(P, 0, b0);                                                               \
  STAGE_B256(Q, 1, (TT) + 1);                                                     \
  PH_MFMA(0, 0, b0);                                                              \
  __builtin_amdgcn_s_barrier();                                                   \
  LDB256(P, 1, b1);                                                               \
  STAGE_A256(Q, 1, (TT) + 1);                                                     \
  PH_MFMA(0, 1, b1);                                                              \
  __builtin_amdgcn_s_barrier();                                                   \
  LDA256(P, 1);                                                                   \
  STAGE_B256(P, 0, (TT) + 2);                                                     \
  PH_MFMA(1, 1, b1);                                                              \
  __builtin_amdgcn_s_barrier();                                                   \
  STAGE_A256(P, 0, (TT) + 2);                                                     \
  PH_MFMA(1, 0, b0);                                                              \
  if ((TT) + 2 < nt) {                                                            \
    asm volatile("s_waitcnt vmcnt(4)" ::: "memory");                              \
  } else {                                                                        \
    asm volatile("s_waitcnt vmcnt(0)" ::: "memory");                              \
  }                                                                               \
  __builtin_amdgcn_s_barrier();

__global__ __launch_bounds__(512, 2) void gemm256_bf16(
    const u16* __restrict__ Aglob, const u16* __restrict__ Bglob, int K, int ldc,
    const float* __restrict__ bias, int biasN, u16* __restrict__ outb) {
  __shared__ __align__(16) u16 As[2][2][128 * 64];
  __shared__ __align__(16) u16 Bs[2][2][128 * 64];
  const int nt = K >> 6;
  int t = threadIdx.x;
  int wid = t >> 6, l = t & 63;
  int wr = wid >> 2, wc = wid & 3;
  int lg = l >> 4, ll = l & 15;

  // bijective XCD swizzle (grid %8 == 0)
  int nwg = gridDim.x;
  int cpx = nwg >> 3;
  int id = blockIdx.x;
  int wg = (id & 7) * cpx + (id >> 3);
  int tm = wg & 15;        // GM = 16 (M = 4096)
  int tn = wg >> 4;
  long rowTile = (long)tm * 256;
  long colTile = (long)tn * 256;

  f32x4 acc[8][4] = {};
  short8 a[4][2], b0[2][2], b1[2][2];

  // prologue: tile0 (all 4 halves) + tile1 (B0, A0) = 12 loads
  STAGE_B256(0, 0, 0);
  STAGE_A256(0, 0, 0);
  STAGE_B256(0, 1, 0);
  STAGE_A256(0, 1, 0);
  STAGE_B256(1, 0, 1);
  STAGE_A256(1, 0, 1);
  asm volatile("s_waitcnt vmcnt(4)" ::: "memory");
  __builtin_amdgcn_s_barrier();

  for (int T = 0; T < nt; T += 2) {
    HALF256(0, 1, T);
    HALF256(1, 0, T + 1);
  }

#pragma unroll
  for (int m = 0; m < 8; ++m)
#pragma unroll
    for (int n = 0; n < 4; ++n) {
      long cg = colTile + wc * 64 + n * 16 + ll;
      float bv = (cg < biasN) ? bias[cg] : 0.f;
#pragma unroll
      for (int q = 0; q < 4; ++q) {
        long rg = rowTile + wr * 128 + m * 16 + lg * 4 + q;
        outb[rg * ldc + cg] = f2bf(acc[m][n][q] + bv);
      }
    }
}

// ---------------- flash attention v2 (unchanged from round 3) -------------
__global__ __launch_bounds__(256, 2) void attn_kernel(
    const u16* __restrict__ qb, int qStride, const u16* __restrict__ kb, int kvStride,
    const u16* __restrict__ vt, u16* __restrict__ outp, int Nk, int Mpb) {
  __shared__ u16 Qs[64 * 64];
  __shared__ u16 Ks[2][64 * 64];
  __shared__ u16 Vs[2][64 * 64];
  __shared__ u16 Ps[4][16 * 64];
  int t = threadIdx.x, w = t >> 6, l = t & 63;
  int qt = blockIdx.x, h = blockIdx.y, b = blockIdx.z;
  int lg = l >> 4, ll = l & 15;
  int rx = ll & 7;

  const u16* Qbase = qb + ((long)(b * NN + qt * 64)) * qStride + h * 64;
  const u16* Kbase = kb + ((long)b * Mpb) * kvStride + h * 64;
  const u16* Vbase = vt + ((long)(b * 16 + h) * 64) * 1024;

  int srow = t >> 3;
  int schunk = t & 7;

#pragma unroll
  for (int sh = 0; sh < 2; ++sh) {
    int row = sh * 32 + srow;
    int ck = schunk ^ (row & 7);
    gload_lds16(Qbase + (long)row * qStride + ck * 8, &Qs[sh * 2048 + t * 8]);
    gload_lds16(Kbase + (long)row * kvStride + ck * 8, &Ks[0][sh * 2048 + t * 8]);
    gload_lds16(Vbase + (long)row * 1024 + ck * 8, &Vs[0][sh * 2048 + t * 8]);
  }
  __syncthreads();

  short8 qf0 = *(const short8*)&Qs[(w * 16 + ll) * 64 + ((lg ^ rx) << 3)];
  short8 qf1 = *(const short8*)&Qs[(w * 16 + ll) * 64 + (((4 + lg) ^ rx) << 3)];

  float m[4], ssum[4];
  f32x4 o[4] = {};
#pragma unroll
  for (int r = 0; r < 4; ++r) { m[r] = -1e30f; ssum[r] = 0.f; }

  int nt = Nk >> 6;
  int cur = 0;
  for (int kt = 0; kt < nt; ++kt) {
    if (kt + 1 < nt) {
      const u16* kn = Kbase + (long)(kt + 1) * 64 * kvStride;
      const u16* vn = Vbase + (kt + 1) * 64;
#pragma unroll
      for (int sh = 0; sh < 2; ++sh) {
        int row = sh * 32 + srow;
        int ck = schunk ^ (row & 7);
        gload_lds16(kn + (long)row * kvStride + ck * 8, &Ks[cur ^ 1][sh * 2048 + t * 8]);
        gload_lds16(vn + (long)row * 1024 + ck * 8, &Vs[cur ^ 1][sh * 2048 + t * 8]);
      }
    }
    const u16* Kc = Ks[cur];
    f32x4 s[4] = {};
#pragma unroll
    for (int n = 0; n < 4; ++n) {
      short8 kf0 = *(const short8*)&Kc[(n * 16 + ll) * 64 + ((lg ^ rx) << 3)];
      short8 kf1 = *(const short8*)&Kc[(n * 16 + ll) * 64 + (((4 + lg) ^ rx) << 3)];
      s[n] = __builtin_amdgcn_mfma_f32_16x16x32_bf16(qf0, kf0, s[n], 0, 0, 0);
      s[n] = __builtin_amdgcn_mfma_f32_16x16x32_bf16(qf1, kf1, s[n], 0, 0, 0);
    }
    float p_[4][4];
#pragma unroll
    for (int r = 0; r < 4; ++r) {
      float pm = fmaxf(fmaxf(s[0][r], s[1][r]), fmaxf(s[2][r], s[3][r]));
      pm = fmaxf(pm, __shfl_xor(pm, 1));
      pm = fmaxf(pm, __shfl_xor(pm, 2));
      pm = fmaxf(pm, __shfl_xor(pm, 4));
      pm = fmaxf(pm, __shfl_xor(pm, 8));
      float nm = fmaxf(m[r], pm);
      float alpha = __expf(m[r] - nm);
      float rs = 0.f;
#pragma unroll
      for (int n = 0; n < 4; ++n) {
        float pv = __expf(s[n][r] - nm);
        p_[n][r] = pv;
        rs += pv;
      }
      rs += __shfl_xor(rs, 1);
      rs += __shfl_xor(rs, 2);
      rs += __shfl_xor(rs, 4);
      rs += __shfl_xor(rs, 8);
      ssum[r] = ssum[r] * alpha + rs;
      m[r] = nm;
#pragma unroll
      for (int n = 0; n < 4; ++n) o[n][r] *= alpha;
    }
#pragma unroll
    for (int n = 0; n < 4; ++n) {
      int chunk = n * 2 + (ll >> 3);
#pragma unroll
      for (int r = 0; r < 4; ++r) {
        int prow = lg * 4 + r;
        Ps[w][prow * 64 + (((chunk ^ (prow & 7)) << 3) | rx)] = f2bf(p_[n][r]);
      }
    }
    short8 pf0 = *(const short8*)&Ps[w][ll * 64 + ((lg ^ rx) << 3)];
    short8 pf1 = *(const short8*)&Ps[w][ll * 64 + (((4 + lg) ^ rx) << 3)];
    const u16* Vc = Vs[cur];
#pragma unroll
    for (int n = 0; n < 4; ++n) {
      short8 vf0 = *(const short8*)&Vc[(n * 16 + ll) * 64 + ((lg ^ rx) << 3)];
      short8 vf1 = *(const short8*)&Vc[(n * 16 + ll) * 64 + (((4 + lg) ^ rx) << 3)];
      o[n] = __builtin_amdgcn_mfma_f32_16x16x32_bf16(pf0, vf0, o[n], 0, 0, 0);
      o[n] = __builtin_amdgcn_mfma_f32_16x16x32_bf16(pf1, vf1, o[n], 0, 0, 0);
    }
    __syncthreads();
    cur ^= 1;
  }
#pragma unroll
  for (int n = 0; n < 4; ++n)
#pragma unroll
    for (int r = 0; r < 4; ++r) {
      long row = (long)b * NN + qt * 64 + w * 16 + lg * 4 + r;
      int col = h * 64 + n * 16 + ll;
      outp[row * DD + col] = f2bf(o[n][r] / ssum[r]);
    }
}

// ---------------- SwiGLU combine: h1 = silu(h1)*h2 ------------------------
__global__ void swiglu_kernel(u16* __restrict__ h1, const u16* __restrict__ h2, long n4) {
  long i = (long)blockIdx.x * 256 + threadIdx.x;
  if (i >= n4) return;
  ushort4 a = *(ushort4*)&h1[i * 4];
  ushort4 bq = *(const ushort4*)&h2[i * 4];
  u16 va[4] = {a.x, a.y, a.z, a.w}, vb[4] = {bq.x, bq.y, bq.z, bq.w};
  u16 oo[4];
#pragma unroll
  for (int j = 0; j < 4; ++j) {
    float f = bf2f(va[j]);
    float g = f / (1.f + __expf(-f));
    oo[j] = f2bf(g * bf2f(vb[j]));
  }
  ushort4 pk = {oo[0], oo[1], oo[2], oo[3]};
  *(ushort4*)&h1[i * 4] = pk;
}

extern "C" void kernel_launch(void* const* d_in, const int* in_sizes, int n_in,
                              void* d_out, int out_size, void* d_ws, size_t ws_size,
                              hipStream_t stream) {
  const float* x = (const float*)d_in[0];
  const float* src = (const float*)d_in[1];
  const float* c = (const float*)d_in[2];
  const float* ada_w = (const float*)d_in[3];
  const float* ada_b = (const float*)d_in[4];
  const float* n1_w = (const float*)d_in[5];
  const float* nc_w = (const float*)d_in[6];
  const float* n2_w = (const float*)d_in[7];
  const float* sa_qkv_w = (const float*)d_in[8];
  const float* sa_qkv_b = (const float*)d_in[9];
  const float* sa_qn_w = (const float*)d_in[10];
  const float* sa_kn_w = (const float*)d_in[11];
  const float* sa_o_w = (const float*)d_in[12];
  const float* sa_o_b = (const float*)d_in[13];
  const float* ca_q_w = (const float*)d_in[14];
  const float* ca_q_b = (const float*)d_in[15];
  const float* ca_kv_w = (const float*)d_in[16];
  const float* ca_kv_b = (const float*)d_in[17];
  const float* ca_qn_w = (const float*)d_in[18];
  const float* ca_kn_w = (const float*)d_in[19];
  const float* ca_o_w = (const float*)d_in[20];
  const float* ca_o_b = (const float*)d_in[21];
  const float* mlp_w1 = (const float*)d_in[22];
  const float* mlp_b1 = (const float*)d_in[23];
  const float* mlp_w2 = (const float*)d_in[24];
  const float* mlp_b2 = (const float*)d_in[25];
  const float* mlp_w3 = (const float*)d_in[26];
  const float* mlp_b3 = (const float*)d_in[27];
  float* out = (float*)d_out;

  char* p = (char*)d_ws;
  auto alloc = [&](size_t bytes) {
    char* r = p;
    p += (bytes + 255) & ~(size_t)255;
    return r;
  };
  float* mods = (float*)alloc(4l * 9216 * 4);
  float* sc = (float*)alloc(4096l * 4);
  float* part = (float*)alloc((long)MODS_KS * 4 * 9216 * 4);
  u16* qkvT = (u16*)alloc(3072l * 1024 * 2);
  u16* saoT = (u16*)alloc(1024l * 1024 * 2);
  u16* caqT = (u16*)alloc(1024l * 1024 * 2);
  u16* cakvT = (u16*)alloc(2048l * 1024 * 2);
  u16* caoT = (u16*)alloc(1024l * 1024 * 2);
  u16* w1T = (u16*)alloc(2816l * 1024 * 2);
  u16* w2T = (u16*)alloc(2816l * 1024 * 2);
  u16* w3T = (u16*)alloc(1024l * 2816 * 2);
  u16* xnb = (u16*)alloc(4096l * 1024 * 2);
  u16* srcb = (u16*)alloc(4096l * 1024 * 2);
  u16* bufA = (u16*)alloc(4096l * 3072 * 2);
  u16* bufB = (u16*)alloc(4096l * 2816 * 2);
  u16* attO = (u16*)alloc(4096l * 1024 * 2);
  u16* vtb = xnb;  // alias: xnb dead during attention

  dim3 tb(32, 8);
  transpose_convert<<<dim3(32, 96), tb, 0, stream>>>(sa_qkv_w, qkvT, 1024, 3072, 1024, 3072);
  transpose_convert<<<dim3(32, 32), tb, 0, stream>>>(sa_o_w, saoT, 1024, 1024, 1024, 1024);
  transpose_convert<<<dim3(32, 32), tb, 0, stream>>>(ca_q_w, caqT, 1024, 1024, 1024, 1024);
  transpose_convert<<<dim3(32, 64), tb, 0, stream>>>(ca_kv_w, cakvT, 1024, 2048, 1024, 2048);
  transpose_convert<<<dim3(32, 32), tb, 0, stream>>>(ca_o_w, caoT, 1024, 1024, 1024, 1024);
  transpose_convert<<<dim3(32, 88), tb, 0, stream>>>(mlp_w1, w1T, 1024, 2730, 1024, 2816);
  transpose_convert<<<dim3(32, 88), tb, 0, stream>>>(mlp_w2, w2T, 1024, 2730, 1024, 2816);
  transpose_convert<<<dim3(88, 32), tb, 0, stream>>>(mlp_w3, w3T, 2730, 1024, 2816, 1024);
  cvt_bf16_kernel<<<4096, 256, 0, stream>>>(src, srcb, 4096l * 1024 / 4);
  silu_kernel<<<16, 256, 0, stream>>>(c, sc);
  mods_partial<<<dim3(36, MODS_KS), 256, 0, stream>>>(sc, ada_w, part);
  mods_reduce<<<dim3(36, 4), 256, 0, stream>>>(part, ada_b, mods);

  // ---- self-attention sublayer
  rmsmod_kernel<<<4096, 256, 0, stream>>>(x, n1_w, mods, 0, 1024, xnb);
  gemm256_bf16<<<dim3(16 * 12), 512, 0, stream>>>(xnb, qkvT, 1024, 3072, sa_qkv_b, 3072, bufA);
  qknorm_kernel<<<4096, 256, 0, stream>>>(bufA, 3072, sa_qn_w, 0.125f);
  qknorm_kernel<<<4096, 256, 0, stream>>>(bufA + 1024, 3072, sa_kn_w, 1.0f);
  vtrans_kernel<<<dim3(16, 16, 4), 256, 0, stream>>>(bufA + 2048, 3072, 1024, vtb);
  attn_kernel<<<dim3(16, 16, 4), 256, 0, stream>>>(bufA, 3072, bufA + 1024, 3072, vtb, attO,
                                                   1024, 1024);
  gemm_bf16<1><<<dim3(8, 32), 256, 0, stream>>>(attO, saoT, 1024, 1024, sa_o_b, 1024, nullptr,
                                                out, x, mods, 2048);

  // ---- cross-attention sublayer
  rmsmod_kernel<<<4096, 256, 0, stream>>>(out, nc_w, mods, 3072, 4096, xnb);
  gemm_bf16<0><<<dim3(8, 32), 256, 0, stream>>>(xnb, caqT, 1024, 1024, ca_q_b, 1024, bufA,
                                                nullptr, nullptr, nullptr, 0);
  gemm256_bf16<<<dim3(16 * 8), 512, 0, stream>>>(srcb, cakvT, 1024, 2048, ca_kv_b, 2048, bufB);
  qknorm_kernel<<<4096, 256, 0, stream>>>(bufA, 1024, ca_qn_w, 0.125f);
  qknorm_kernel<<<4096, 256, 0, stream>>>(bufB, 2048, ca_kn_w, 1.0f);
  vtrans_kernel<<<dim3(16, 16, 4), 256, 0, stream>>>(bufB + 1024, 2048, 1024, vtb);
  attn_kernel<<<dim3(16, 16, 4), 256, 0, stream>>>(bufA, 1024, bufB, 2048, vtb, attO, 1024,
                                                   1024);
  gemm_bf16<1><<<dim3(8, 32), 256, 0, stream>>>(attO, caoT, 1024, 1024, ca_o_b, 1024, nullptr,
                                                out, out, mods, 5120);

  // ---- SwiGLU FFN sublayer
  rmsmod_kernel<<<4096, 256, 0, stream>>>(out, n2_w, mods, 6144, 7168, xnb);
  gemm256_bf16<<<dim3(16 * 11), 512, 0, stream>>>(xnb, w1T, 1024, 2816, mlp_b1, 2730, bufA);
  gemm256_bf16<<<dim3(16 * 11), 512, 0, stream>>>(xnb, w2T, 1024, 2816, mlp_b2, 2730, bufB);
  swiglu_kernel<<<(int)((4096l * 2816 / 4 + 255) / 256), 256, 0, stream>>>(bufA, bufB,
                                                                           4096l * 2816 / 4);
  gemm_bf16<1><<<dim3(8, 32), 256, 0, stream>>>(bufA, w3T, 2816, 1024, mlp_b3, 1024, nullptr,
                                                out, out, mods, 8192);
}

// Round 5
// 506.962 us; speedup vs baseline: 1.0754x; 1.0754x over previous
//
#include <hip/hip_runtime.h>

typedef unsigned short u16;
typedef __attribute__((ext_vector_type(8))) short short8;
typedef __attribute__((ext_vector_type(4))) float f32x4;

#define DD 1024
#define NN 1024
#define MODS_LD 9216

__device__ __forceinline__ float bf2f(u16 v) {
  unsigned int u = ((unsigned int)v) << 16;
  return __builtin_bit_cast(float, u);
}
__device__ __forceinline__ u16 f2bf(float f) {
  unsigned int u = __builtin_bit_cast(unsigned int, f);
  unsigned int lsb = (u >> 16) & 1;
  u += 0x7fffu + lsb;
  return (u16)(u >> 16);
}

__device__ __forceinline__ void gload_lds16(const u16* g, u16* l) {
  __builtin_amdgcn_global_load_lds(
      (const __attribute__((address_space(1))) unsigned int*)g,
      (__attribute__((address_space(3))) unsigned int*)l, 16, 0, 0);
}

// ---------------- weight transpose + fp32->bf16 -------------------------
__global__ void transpose_convert(const float* __restrict__ src, u16* __restrict__ dst,
                                  int R, int C, int R2, int C2) {
  __shared__ float tile[32][33];
  int tx = threadIdx.x, ty = threadIdx.y;
  int r0 = blockIdx.x * 32, c0 = blockIdx.y * 32;
#pragma unroll
  for (int i = 0; i < 4; ++i) {
    int r = r0 + ty + i * 8, c = c0 + tx;
    tile[ty + i * 8][tx] = (r < R && c < C) ? src[(long)r * C + c] : 0.f;
  }
  __syncthreads();
#pragma unroll
  for (int i = 0; i < 4; ++i) {
    int c = c0 + ty + i * 8, r = r0 + tx;
    if (c < C2 && r < R2) dst[(long)c * R2 + r] = f2bf(tile[tx][ty + i * 8]);
  }
}

// ---------------- fp32 -> bf16 (vector) ---------------------------------
__global__ void cvt_bf16_kernel(const float* __restrict__ in, u16* __restrict__ out, long n4) {
  long i = (long)blockIdx.x * 256 + threadIdx.x;
  if (i >= n4) return;
  float4 v = *(const float4*)&in[i * 4];
  ushort4 pk = {f2bf(v.x), f2bf(v.y), f2bf(v.z), f2bf(v.w)};
  *(ushort4*)&out[i * 4] = pk;
}

// ---------------- silu(c) + mods matvec (k-split, deterministic) ----------
__global__ void silu_kernel(const float* __restrict__ c, float* __restrict__ sc) {
  int i = blockIdx.x * 256 + threadIdx.x;
  float v = c[i];
  sc[i] = v / (1.f + __expf(-v));
}

#define MODS_KS 32
__global__ __launch_bounds__(256) void mods_partial(const float* __restrict__ sc,
                                                    const float* __restrict__ aw,
                                                    float* __restrict__ part) {
  int j = blockIdx.x * 256 + threadIdx.x;
  int ks = blockIdx.y;
  int d0 = ks * (DD / MODS_KS);
  float a0 = 0.f, a1 = 0.f, a2 = 0.f, a3 = 0.f;
#pragma unroll 8
  for (int d = d0; d < d0 + DD / MODS_KS; ++d) {
    float w = aw[(long)d * MODS_LD + j];
    a0 = fmaf(sc[d], w, a0);
    a1 = fmaf(sc[DD + d], w, a1);
    a2 = fmaf(sc[2 * DD + d], w, a2);
    a3 = fmaf(sc[3 * DD + d], w, a3);
  }
  long base = (long)ks * 4 * MODS_LD + j;
  part[base] = a0;
  part[base + MODS_LD] = a1;
  part[base + 2 * MODS_LD] = a2;
  part[base + 3 * MODS_LD] = a3;
}

__global__ __launch_bounds__(256) void mods_reduce(const float* __restrict__ part,
                                                   const float* __restrict__ ab,
                                                   float* __restrict__ mods) {
  int j = blockIdx.x * 256 + threadIdx.x;
  int b = blockIdx.y;
  float acc = ab[j];
#pragma unroll
  for (int ks = 0; ks < MODS_KS; ++ks) acc += part[((long)ks * 4 + b) * MODS_LD + j];
  mods[(long)b * MODS_LD + j] = acc;
}

// ---------------- fused RMSNorm + modulate -> bf16 ------------------------
__global__ __launch_bounds__(256) void rmsmod_kernel(const float* __restrict__ x,
                                                     const float* __restrict__ w,
                                                     const float* __restrict__ mods,
                                                     int shiftOff, int scaleOff,
                                                     u16* __restrict__ out) {
  long row = blockIdx.x;
  int b = (int)(row >> 10);
  int t = threadIdx.x;
  const float* xr = x + row * DD;
  float4 v = *(const float4*)&xr[t * 4];
  float ss = v.x * v.x + v.y * v.y + v.z * v.z + v.w * v.w;
#pragma unroll
  for (int msk = 1; msk < 64; msk <<= 1) ss += __shfl_xor(ss, msk);
  __shared__ float red[4];
  if ((t & 63) == 0) red[t >> 6] = ss;
  __syncthreads();
  float tot = red[0] + red[1] + red[2] + red[3];
  float inv = rsqrtf(tot * (1.f / DD) + 1e-6f);
  const float* mrow = mods + (long)b * MODS_LD;
  float vv[4] = {v.x, v.y, v.z, v.w};
  u16 tmp[4];
#pragma unroll
  for (int j = 0; j < 4; ++j) {
    int c = t * 4 + j;
    float rr = vv[j] * inv * w[c] * (1.f + mrow[scaleOff + c]) + mrow[shiftOff + c];
    tmp[j] = f2bf(rr);
  }
  ushort4 pk = {tmp[0], tmp[1], tmp[2], tmp[3]};
  *(ushort4*)&out[row * DD + t * 4] = pk;
}

// ---------------- q/k head-RMS-norm, in-place, vectorized -----------------
__global__ __launch_bounds__(256) void qknorm_kernel(u16* __restrict__ buf, int ld,
                                                     const float* __restrict__ w, float scale) {
  long row = blockIdx.x;
  int t = threadIdx.x;
  int g = t >> 4, p = t & 15;
  u16* ptr = buf + row * ld + g * 64 + p * 4;
  ushort4 a = *(ushort4*)ptr;
  float v[4] = {bf2f(a.x), bf2f(a.y), bf2f(a.z), bf2f(a.w)};
  float ss = v[0] * v[0] + v[1] * v[1] + v[2] * v[2] + v[3] * v[3];
  ss += __shfl_xor(ss, 1);
  ss += __shfl_xor(ss, 2);
  ss += __shfl_xor(ss, 4);
  ss += __shfl_xor(ss, 8);
  float inv = rsqrtf(ss * (1.f / 64) + 1e-6f) * scale;
  u16 o[4];
#pragma unroll
  for (int j = 0; j < 4; ++j) o[j] = f2bf(v[j] * inv * w[p * 4 + j]);
  ushort4 pk = {o[0], o[1], o[2], o[3]};
  *(ushort4*)ptr = pk;
}

// ---------------- V pre-transpose: v[b, kv, (h,d)] -> vt[(b,h), d, kv] -----
__global__ void vtrans_kernel(const u16* __restrict__ vb, int kvStride, int Mpb,
                              u16* __restrict__ vt) {
  __shared__ u16 tile[64][66];
  int t = threadIdx.x;
  int kt = blockIdx.x, h = blockIdx.y, b = blockIdx.z;
  const u16* base = vb + ((long)(b * Mpb + kt * 64)) * kvStride + h * 64;
#pragma unroll
  for (int sh = 0; sh < 2; ++sh) {
    int r = sh * 32 + (t >> 3);
    int c0 = (t & 7) * 8;
    short8 vv = *(const short8*)(base + (long)r * kvStride + c0);
#pragma unroll
    for (int j = 0; j < 8; ++j) tile[c0 + j][r] = (u16)vv[j];
  }
  __syncthreads();
  u16* obase = vt + ((long)(b * 16 + h) * 64) * 1024 + kt * 64;
#pragma unroll
  for (int sh = 0; sh < 2; ++sh) {
    int d = sh * 32 + (t >> 3);
    int c0 = (t & 7) * 8;
    u16 tmp[8];
#pragma unroll
    for (int j = 0; j < 8; ++j) tmp[j] = tile[d][c0 + j];
    *(short8*)(obase + (long)d * 1024 + c0) = *(short8*)tmp;
  }
}

// ---------------- small GEMM (128 x BN tiles, BN in {128, 64}) ------------
// MODE 0: outb = bf16(acc+bias).  MODE 1: outf = xin + gate*(acc+bias)
template <int MODE, int BN>
__global__ __launch_bounds__(256, 2) void gemm_bf16(
    const u16* __restrict__ A, const u16* __restrict__ Bt, int K, int ldc,
    const float* __restrict__ bias, int biasN, u16* __restrict__ outb,
    float* __restrict__ outf, const float* __restrict__ xin,
    const float* __restrict__ mods, int gateOff) {
  constexpr int WC = BN / 2;   // wave col width
  constexpr int NT = WC / 16;  // n tiles per wave
  __shared__ u16 As[128 * 64];
  __shared__ u16 Bs[BN * 64];
  int t = threadIdx.x;
  int l = t & 63, w = t >> 6;
  int wr = w >> 1, wc = w & 1;
  int lg = l >> 4, ll = l & 15;
  long rowTile = (long)blockIdx.y * 128;
  long colTile = (long)blockIdx.x * BN;
  const u16* Ap = A + rowTile * K;
  const u16* Bp = Bt + colTile * K;
  int srow = t >> 3;
  int scol = (t & 7) * 8;

  f32x4 acc[4][NT] = {};

  for (int k0 = 0; k0 < K; k0 += 64) {
#pragma unroll
    for (int i = 0; i < 4; ++i)
      gload_lds16(Ap + (long)(i * 32 + srow) * K + k0 + scol, &As[(i * 256 + t) * 8]);
#pragma unroll
    for (int i = 0; i < BN / 32; ++i)
      gload_lds16(Bp + (long)(i * 32 + srow) * K + k0 + scol, &Bs[(i * 256 + t) * 8]);
    __syncthreads();
#pragma unroll
    for (int kk = 0; kk < 2; ++kk) {
      short8 af[4], bfr[NT];
#pragma unroll
      for (int m2 = 0; m2 < 4; ++m2)
        af[m2] = *(const short8*)&As[(wr * 64 + m2 * 16 + ll) * 64 + kk * 32 + lg * 8];
#pragma unroll
      for (int n2 = 0; n2 < NT; ++n2)
        bfr[n2] = *(const short8*)&Bs[(wc * WC + n2 * 16 + ll) * 64 + kk * 32 + lg * 8];
#pragma unroll
      for (int m2 = 0; m2 < 4; ++m2)
#pragma unroll
        for (int n2 = 0; n2 < NT; ++n2)
          acc[m2][n2] =
              __builtin_amdgcn_mfma_f32_16x16x32_bf16(af[m2], bfr[n2], acc[m2][n2], 0, 0, 0);
    }
    __syncthreads();
  }
#pragma unroll
  for (int n2 = 0; n2 < NT; ++n2) {
    long cg = colTile + wc * WC + n2 * 16 + ll;
    float bv = (cg < biasN) ? bias[cg] : 0.f;
#pragma unroll
    for (int m2 = 0; m2 < 4; ++m2) {
#pragma unroll
      for (int r = 0; r < 4; ++r) {
        long rg = rowTile + wr * 64 + m2 * 16 + lg * 4 + r;
        float v = acc[m2][n2][r] + bv;
        long idx = rg * ldc + cg;
        if (MODE == 0) {
          outb[idx] = f2bf(v);
        } else {
          int bb = (int)(rg >> 10);
          outf[idx] = xin[idx] + mods[(long)bb * MODS_LD + gateOff + cg] * v;
        }
      }
    }
  }
}

// ---------------- big GEMM: 256x256 tile, 8-phase schedule (m201 port) -----
#define LDA256(PBUF, MH)                                                          \
  {                                                                               \
    const u16* Ab = &As[PBUF][wr][0];                                             \
    _Pragma("unroll") for (int mq_ = 0; mq_ < 4; ++mq_)                           \
        _Pragma("unroll") for (int ks_ = 0; ks_ < 2; ++ks_) {                     \
      int rowl_ = ((MH)*4 + mq_) * 16 + ll;                                       \
      a[mq_][ks_] =                                                               \
          *(const short8*)&Ab[rowl_ * 64 + (((ks_ * 4 + lg) ^ (ll & 7)) << 3)];   \
    }                                                                             \
  }

#define LDB256(PBUF, NH, BR)                                                      \
  {                                                                               \
    const u16* Bb = &Bs[PBUF][wc >> 1][0];                                        \
    _Pragma("unroll") for (int nq_ = 0; nq_ < 2; ++nq_)                           \
        _Pragma("unroll") for (int ks_ = 0; ks_ < 2; ++ks_) {                     \
      int coll_ = (wc & 1) * 64 + ((NH)*2 + nq_) * 16 + ll;                       \
      BR[nq_][ks_] =                                                              \
          *(const short8*)&Bb[coll_ * 64 + (((ks_ * 4 + lg) ^ (ll & 7)) << 3)];   \
    }                                                                             \
  }

#define STAGE_A256(PBUF, H, KT)                                                   \
  if ((KT) < nt) {                                                                \
    _Pragma("unroll") for (int i_ = 0; i_ < 2; ++i_) {                            \
      int idx_ = i_ * 512 + t;                                                    \
      int rw_ = idx_ >> 3;                                                        \
      int sc_ = (idx_ & 7) ^ (rw_ & 7);                                           \
      gload_lds16(Aglob + (long)(rowTile + (H)*128 + rw_) * K + (KT)*64 + sc_ * 8,\
                  &As[PBUF][H][idx_ * 8]);                                        \
    }                                                                             \
  }

#define STAGE_B256(PBUF, H, KT)                                                   \
  if ((KT) < nt) {                                                                \
    _Pragma("unroll") for (int i_ = 0; i_ < 2; ++i_) {                            \
      int idx_ = i_ * 512 + t;                                                    \
      int rw_ = idx_ >> 3;                                                        \
      int sc_ = (idx_ & 7) ^ (rw_ & 7);                                           \
      gload_lds16(Bglob + (long)(colTile + (H)*128 + rw_) * K + (KT)*64 + sc_ * 8,\
                  &Bs[PBUF][H][idx_ * 8]);                                        \
    }                                                                             \
  }

#define MFMA_Q(MH, NH, BR)                                                        \
  _Pragma("unroll") for (int mq_ = 0; mq_ < 4; ++mq_)                             \
      _Pragma("unroll") for (int nq_ = 0; nq_ < 2; ++nq_)                         \
          _Pragma("unroll") for (int ks_ = 0; ks_ < 2; ++ks_)                     \
              acc[(MH)*4 + mq_][(NH)*2 + nq_] =                                   \
      __builtin_amdgcn_mfma_f32_16x16x32_bf16(                                    \
          a[mq_][ks_], BR[nq_][ks_], acc[(MH)*4 + mq_][(NH)*2 + nq_], 0, 0, 0);

#define PH_MFMA(MH, NH, BR)                                                       \
  __builtin_amdgcn_s_barrier();                                                   \
  asm volatile("s_waitcnt lgkmcnt(0)" ::: "memory");                              \
  __builtin_amdgcn_sched_barrier(0);                                              \
  __builtin_amdgcn_s_setprio(1);                                                  \
  MFMA_Q(MH, NH, BR);                                                             \
  __builtin_amdgcn_s_setprio(0);

#define HALF256(P, Q, TT)                                                         \
  LDA256(P, 0);                                                                   \
  LDB256(P, 0, b0);                                                               \
  STAGE_B256(Q, 1, (TT) + 1);                                                     \
  PH_MFMA(0, 0, b0);                                                              \
  __builtin_amdgcn_s_barrier();                                                   \
  LDB256(P, 1, b1);                                                               \
  STAGE_A256(Q, 1, (TT) + 1);                                                     \
  PH_MFMA(0, 1, b1);                                                              \
  __builtin_amdgcn_s_barrier();                                                   \
  LDA256(P, 1);                                                                   \
  STAGE_B256(P, 0, (TT) + 2);                                                     \
  PH_MFMA(1, 1, b1);                                                              \
  __builtin_amdgcn_s_barrier();                                                   \
  STAGE_A256(P, 0, (TT) + 2);                                                     \
  PH_MFMA(1, 0, b0);                                                              \
  if ((TT) + 2 < nt) {                                                            \
    asm volatile("s_waitcnt vmcnt(4)" ::: "memory");                              \
  } else {                                                                        \
    asm volatile("s_waitcnt vmcnt(0)" ::: "memory");                              \
  }                                                                               \
  __builtin_amdgcn_s_barrier();

__global__ __launch_bounds__(512, 2) void gemm256_bf16(
    const u16* __restrict__ Aglob, const u16* __restrict__ Bglob, int K, int ldc,
    const float* __restrict__ bias, int biasN, u16* __restrict__ outb) {
  __shared__ __align__(16) u16 As[2][2][128 * 64];
  __shared__ __align__(16) u16 Bs[2][2][128 * 64];
  const int nt = K >> 6;
  int t = threadIdx.x;
  int wid = t >> 6, l = t & 63;
  int wr = wid >> 2, wc = wid & 3;
  int lg = l >> 4, ll = l & 15;

  int nwg = gridDim.x;
  int cpx = nwg >> 3;
  int id = blockIdx.x;
  int wg = (id & 7) * cpx + (id >> 3);
  int tm = wg & 15;  // GM = 16 (M = 4096)
  int tn = wg >> 4;
  long rowTile = (long)tm * 256;
  long colTile = (long)tn * 256;

  f32x4 acc[8][4] = {};
  short8 a[4][2], b0[2][2], b1[2][2];

  STAGE_B256(0, 0, 0);
  STAGE_A256(0, 0, 0);
  STAGE_B256(0, 1, 0);
  STAGE_A256(0, 1, 0);
  STAGE_B256(1, 0, 1);
  STAGE_A256(1, 0, 1);
  asm volatile("s_waitcnt vmcnt(4)" ::: "memory");
  __builtin_amdgcn_s_barrier();

  for (int T = 0; T < nt; T += 2) {
    HALF256(0, 1, T);
    HALF256(1, 0, T + 1);
  }

#pragma unroll
  for (int m = 0; m < 8; ++m)
#pragma unroll
    for (int n = 0; n < 4; ++n) {
      long cg = colTile + wc * 64 + n * 16 + ll;
      float bv = (cg < biasN) ? bias[cg] : 0.f;
#pragma unroll
      for (int q = 0; q < 4; ++q) {
        long rg = rowTile + wr * 128 + m * 16 + lg * 4 + q;
        outb[rg * ldc + cg] = f2bf(acc[m][n][q] + bv);
      }
    }
}

// ---------------- flash attention v2 -------------------------------------
__global__ __launch_bounds__(256, 2) void attn_kernel(
    const u16* __restrict__ qb, int qStride, const u16* __restrict__ kb, int kvStride,
    const u16* __restrict__ vt, u16* __restrict__ outp, int Nk, int Mpb) {
  __shared__ u16 Qs[64 * 64];
  __shared__ u16 Ks[2][64 * 64];
  __shared__ u16 Vs[2][64 * 64];
  __shared__ u16 Ps[4][16 * 64];
  int t = threadIdx.x, w = t >> 6, l = t & 63;
  int qt = blockIdx.x, h = blockIdx.y, b = blockIdx.z;
  int lg = l >> 4, ll = l & 15;
  int rx = ll & 7;

  const u16* Qbase = qb + ((long)(b * NN + qt * 64)) * qStride + h * 64;
  const u16* Kbase = kb + ((long)b * Mpb) * kvStride + h * 64;
  const u16* Vbase = vt + ((long)(b * 16 + h) * 64) * 1024;

  int srow = t >> 3;
  int schunk = t & 7;

#pragma unroll
  for (int sh = 0; sh < 2; ++sh) {
    int row = sh * 32 + srow;
    int ck = schunk ^ (row & 7);
    gload_lds16(Qbase + (long)row * qStride + ck * 8, &Qs[sh * 2048 + t * 8]);
    gload_lds16(Kbase + (long)row * kvStride + ck * 8, &Ks[0][sh * 2048 + t * 8]);
    gload_lds16(Vbase + (long)row * 1024 + ck * 8, &Vs[0][sh * 2048 + t * 8]);
  }
  __syncthreads();

  short8 qf0 = *(const short8*)&Qs[(w * 16 + ll) * 64 + ((lg ^ rx) << 3)];
  short8 qf1 = *(const short8*)&Qs[(w * 16 + ll) * 64 + (((4 + lg) ^ rx) << 3)];

  float m[4], ssum[4];
  f32x4 o[4] = {};
#pragma unroll
  for (int r = 0; r < 4; ++r) { m[r] = -1e30f; ssum[r] = 0.f; }

  int nt = Nk >> 6;
  int cur = 0;
  for (int kt = 0; kt < nt; ++kt) {
    if (kt + 1 < nt) {
      const u16* kn = Kbase + (long)(kt + 1) * 64 * kvStride;
      const u16* vn = Vbase + (kt + 1) * 64;
#pragma unroll
      for (int sh = 0; sh < 2; ++sh) {
        int row = sh * 32 + srow;
        int ck = schunk ^ (row & 7);
        gload_lds16(kn + (long)row * kvStride + ck * 8, &Ks[cur ^ 1][sh * 2048 + t * 8]);
        gload_lds16(vn + (long)row * 1024 + ck * 8, &Vs[cur ^ 1][sh * 2048 + t * 8]);
      }
    }
    const u16* Kc = Ks[cur];
    f32x4 s[4] = {};
#pragma unroll
    for (int n = 0; n < 4; ++n) {
      short8 kf0 = *(const short8*)&Kc[(n * 16 + ll) * 64 + ((lg ^ rx) << 3)];
      short8 kf1 = *(const short8*)&Kc[(n * 16 + ll) * 64 + (((4 + lg) ^ rx) << 3)];
      s[n] = __builtin_amdgcn_mfma_f32_16x16x32_bf16(qf0, kf0, s[n], 0, 0, 0);
      s[n] = __builtin_amdgcn_mfma_f32_16x16x32_bf16(qf1, kf1, s[n], 0, 0, 0);
    }
    float p_[4][4];
#pragma unroll
    for (int r = 0; r < 4; ++r) {
      float pm = fmaxf(fmaxf(s[0][r], s[1][r]), fmaxf(s[2][r], s[3][r]));
      pm = fmaxf(pm, __shfl_xor(pm, 1));
      pm = fmaxf(pm, __shfl_xor(pm, 2));
      pm = fmaxf(pm, __shfl_xor(pm, 4));
      pm = fmaxf(pm, __shfl_xor(pm, 8));
      float nm = fmaxf(m[r], pm);
      float alpha = __expf(m[r] - nm);
      float rs = 0.f;
#pragma unroll
      for (int n = 0; n < 4; ++n) {
        float pv = __expf(s[n][r] - nm);
        p_[n][r] = pv;
        rs += pv;
      }
      rs += __shfl_xor(rs, 1);
      rs += __shfl_xor(rs, 2);
      rs += __shfl_xor(rs, 4);
      rs += __shfl_xor(rs, 8);
      ssum[r] = ssum[r] * alpha + rs;
      m[r] = nm;
#pragma unroll
      for (int n = 0; n < 4; ++n) o[n][r] *= alpha;
    }
#pragma unroll
    for (int n = 0; n < 4; ++n) {
      int chunk = n * 2 + (ll >> 3);
#pragma unroll
      for (int r = 0; r < 4; ++r) {
        int prow = lg * 4 + r;
        Ps[w][prow * 64 + (((chunk ^ (prow & 7)) << 3) | rx)] = f2bf(p_[n][r]);
      }
    }
    short8 pf0 = *(const short8*)&Ps[w][ll * 64 + ((lg ^ rx) << 3)];
    short8 pf1 = *(const short8*)&Ps[w][ll * 64 + (((4 + lg) ^ rx) << 3)];
    const u16* Vc = Vs[cur];
#pragma unroll
    for (int n = 0; n < 4; ++n) {
      short8 vf0 = *(const short8*)&Vc[(n * 16 + ll) * 64 + ((lg ^ rx) << 3)];
      short8 vf1 = *(const short8*)&Vc[(n * 16 + ll) * 64 + (((4 + lg) ^ rx) << 3)];
      o[n] = __builtin_amdgcn_mfma_f32_16x16x32_bf16(pf0, vf0, o[n], 0, 0, 0);
      o[n] = __builtin_amdgcn_mfma_f32_16x16x32_bf16(pf1, vf1, o[n], 0, 0, 0);
    }
    __syncthreads();
    cur ^= 1;
  }
#pragma unroll
  for (int n = 0; n < 4; ++n)
#pragma unroll
    for (int r = 0; r < 4; ++r) {
      long row = (long)b * NN + qt * 64 + w * 16 + lg * 4 + r;
      int col = h * 64 + n * 16 + ll;
      outp[row * DD + col] = f2bf(o[n][r] / ssum[r]);
    }
}

// ---------------- SwiGLU combine: h1 = silu(h1)*h2 ------------------------
__global__ void swiglu_kernel(u16* __restrict__ h1, const u16* __restrict__ h2, long n4) {
  long i = (long)blockIdx.x * 256 + threadIdx.x;
  if (i >= n4) return;
  ushort4 a = *(ushort4*)&h1[i * 4];
  ushort4 bq = *(const ushort4*)&h2[i * 4];
  u16 va[4] = {a.x, a.y, a.z, a.w}, vb[4] = {bq.x, bq.y, bq.z, bq.w};
  u16 oo[4];
#pragma unroll
  for (int j = 0; j < 4; ++j) {
    float f = bf2f(va[j]);
    float g = f / (1.f + __expf(-f));
    oo[j] = f2bf(g * bf2f(vb[j]));
  }
  ushort4 pk = {oo[0], oo[1], oo[2], oo[3]};
  *(ushort4*)&h1[i * 4] = pk;
}

extern "C" void kernel_launch(void* const* d_in, const int* in_sizes, int n_in,
                              void* d_out, int out_size, void* d_ws, size_t ws_size,
                              hipStream_t stream) {
  const float* x = (const float*)d_in[0];
  const float* src = (const float*)d_in[1];
  const float* c = (const float*)d_in[2];
  const float* ada_w = (const float*)d_in[3];
  const float* ada_b = (const float*)d_in[4];
  const float* n1_w = (const float*)d_in[5];
  const float* nc_w = (const float*)d_in[6];
  const float* n2_w = (const float*)d_in[7];
  const float* sa_qkv_w = (const float*)d_in[8];
  const float* sa_qkv_b = (const float*)d_in[9];
  const float* sa_qn_w = (const float*)d_in[10];
  const float* sa_kn_w = (const float*)d_in[11];
  const float* sa_o_w = (const float*)d_in[12];
  const float* sa_o_b = (const float*)d_in[13];
  const float* ca_q_w = (const float*)d_in[14];
  const float* ca_q_b = (const float*)d_in[15];
  const float* ca_kv_w = (const float*)d_in[16];
  const float* ca_kv_b = (const float*)d_in[17];
  const float* ca_qn_w = (const float*)d_in[18];
  const float* ca_kn_w = (const float*)d_in[19];
  const float* ca_o_w = (const float*)d_in[20];
  const float* ca_o_b = (const float*)d_in[21];
  const float* mlp_w1 = (const float*)d_in[22];
  const float* mlp_b1 = (const float*)d_in[23];
  const float* mlp_w2 = (const float*)d_in[24];
  const float* mlp_b2 = (const float*)d_in[25];
  const float* mlp_w3 = (const float*)d_in[26];
  const float* mlp_b3 = (const float*)d_in[27];
  float* out = (float*)d_out;

  char* p = (char*)d_ws;
  auto alloc = [&](size_t bytes) {
    char* r = p;
    p += (bytes + 255) & ~(size_t)255;
    return r;
  };
  float* mods = (float*)alloc(4l * 9216 * 4);
  float* sc = (float*)alloc(4096l * 4);
  float* part = (float*)alloc((long)MODS_KS * 4 * 9216 * 4);
  u16* qkvT = (u16*)alloc(3072l * 1024 * 2);
  u16* saoT = (u16*)alloc(1024l * 1024 * 2);
  u16* caqT = (u16*)alloc(1024l * 1024 * 2);
  u16* cakvT = (u16*)alloc(2048l * 1024 * 2);
  u16* caoT = (u16*)alloc(1024l * 1024 * 2);
  u16* w1T = (u16*)alloc(2816l * 1024 * 2);
  u16* w2T = (u16*)alloc(2816l * 1024 * 2);
  u16* w3T = (u16*)alloc(1024l * 2816 * 2);
  u16* xnb = (u16*)alloc(4096l * 1024 * 2);
  u16* srcb = (u16*)alloc(4096l * 1024 * 2);
  u16* bufA = (u16*)alloc(4096l * 3072 * 2);
  u16* bufB = (u16*)alloc(4096l * 2816 * 2);
  u16* attO = (u16*)alloc(4096l * 1024 * 2);
  u16* vtb = xnb;  // alias: xnb dead during attention

  dim3 tb(32, 8);
  transpose_convert<<<dim3(32, 96), tb, 0, stream>>>(sa_qkv_w, qkvT, 1024, 3072, 1024, 3072);
  transpose_convert<<<dim3(32, 32), tb, 0, stream>>>(sa_o_w, saoT, 1024, 1024, 1024, 1024);
  transpose_convert<<<dim3(32, 32), tb, 0, stream>>>(ca_q_w, caqT, 1024, 1024, 1024, 1024);
  transpose_convert<<<dim3(32, 64), tb, 0, stream>>>(ca_kv_w, cakvT, 1024, 2048, 1024, 2048);
  transpose_convert<<<dim3(32, 32), tb, 0, stream>>>(ca_o_w, caoT, 1024, 1024, 1024, 1024);
  transpose_convert<<<dim3(32, 88), tb, 0, stream>>>(mlp_w1, w1T, 1024, 2730, 1024, 2816);
  transpose_convert<<<dim3(32, 88), tb, 0, stream>>>(mlp_w2, w2T, 1024, 2730, 1024, 2816);
  transpose_convert<<<dim3(88, 32), tb, 0, stream>>>(mlp_w3, w3T, 2730, 1024, 2816, 1024);
  cvt_bf16_kernel<<<4096, 256, 0, stream>>>(src, srcb, 4096l * 1024 / 4);
  silu_kernel<<<16, 256, 0, stream>>>(c, sc);
  mods_partial<<<dim3(36, MODS_KS), 256, 0, stream>>>(sc, ada_w, part);
  mods_reduce<<<dim3(36, 4), 256, 0, stream>>>(part, ada_b, mods);

  // ---- self-attention sublayer
  rmsmod_kernel<<<4096, 256, 0, stream>>>(x, n1_w, mods, 0, 1024, xnb);
  gemm_bf16<0, 128><<<dim3(24, 32), 256, 0, stream>>>(xnb, qkvT, 1024, 3072, sa_qkv_b, 3072,
                                                      bufA, nullptr, nullptr, nullptr, 0);
  qknorm_kernel<<<4096, 256, 0, stream>>>(bufA, 3072, sa_qn_w, 0.125f);
  qknorm_kernel<<<4096, 256, 0, stream>>>(bufA + 1024, 3072, sa_kn_w, 1.0f);
  vtrans_kernel<<<dim3(16, 16, 4), 256, 0, stream>>>(bufA + 2048, 3072, 1024, vtb);
  attn_kernel<<<dim3(16, 16, 4), 256, 0, stream>>>(bufA, 3072, bufA + 1024, 3072, vtb, attO,
                                                   1024, 1024);
  gemm_bf16<1, 64><<<dim3(16, 32), 256, 0, stream>>>(attO, saoT, 1024, 1024, sa_o_b, 1024,
                                                     nullptr, out, x, mods, 2048);

  // ---- cross-attention sublayer
  rmsmod_kernel<<<4096, 256, 0, stream>>>(out, nc_w, mods, 3072, 4096, xnb);
  gemm_bf16<0, 64><<<dim3(16, 32), 256, 0, stream>>>(xnb, caqT, 1024, 1024, ca_q_b, 1024, bufA,
                                                     nullptr, nullptr, nullptr, 0);
  gemm_bf16<0, 128><<<dim3(16, 32), 256, 0, stream>>>(srcb, cakvT, 1024, 2048, ca_kv_b, 2048,
                                                      bufB, nullptr, nullptr, nullptr, 0);
  qknorm_kernel<<<4096, 256, 0, stream>>>(bufA, 1024, ca_qn_w, 0.125f);
  qknorm_kernel<<<4096, 256, 0, stream>>>(bufB, 2048, ca_kn_w, 1.0f);
  vtrans_kernel<<<dim3(16, 16, 4), 256, 0, stream>>>(bufB + 1024, 2048, 1024, vtb);
  attn_kernel<<<dim3(16, 16, 4), 256, 0, stream>>>(bufA, 1024, bufB, 2048, vtb, attO, 1024,
                                                   1024);
  gemm_bf16<1, 64><<<dim3(16, 32), 256, 0, stream>>>(attO, caoT, 1024, 1024, ca_o_b, 1024,
                                                     nullptr, out, out, mods, 5120);

  // ---- SwiGLU FFN sublayer
  rmsmod_kernel<<<4096, 256, 0, stream>>>(out, n2_w, mods, 6144, 7168, xnb);
  gemm256_bf16<<<dim3(16 * 11), 512, 0, stream>>>(xnb, w1T, 1024, 2816, mlp_b1, 2730, bufA);
  gemm256_bf16<<<dim3(16 * 11), 512, 0, stream>>>(xnb, w2T, 1024, 2816, mlp_b2, 2730, bufB);
  swiglu_kernel<<<(int)((4096l * 2816 / 4 + 255) / 256), 256, 0, stream>>>(bufA, bufB,
                                                                           4096l * 2816 / 4);
  gemm_bf16<1, 64><<<dim3(16, 32), 256, 0, stream>>>(bufA, w3T, 2816, 1024, mlp_b3, 1024,
                                                     nullptr, out, out, mods, 8192);
}

// Round 6
// 469.099 us; speedup vs baseline: 1.1622x; 1.0807x over previous
//
#include <hip/hip_runtime.h>

typedef unsigned short u16;
typedef __attribute__((ext_vector_type(8))) short short8;
typedef __attribute__((ext_vector_type(4))) float f32x4;

#define DD 1024
#define NN 1024
#define MODS_LD 9216

__device__ __forceinline__ float bf2f(u16 v) {
  unsigned int u = ((unsigned int)v) << 16;
  return __builtin_bit_cast(float, u);
}
__device__ __forceinline__ u16 f2bf(float f) {
  unsigned int u = __builtin_bit_cast(unsigned int, f);
  unsigned int lsb = (u >> 16) & 1;
  u += 0x7fffu + lsb;
  return (u16)(u >> 16);
}
__device__ __forceinline__ unsigned cvtpk_bf16(float a, float b) {
  unsigned r;
  asm volatile("v_cvt_pk_bf16_f32 %0, %1, %2" : "=v"(r) : "v"(a), "v"(b));
  return r;
}

__device__ __forceinline__ void gload_lds16(const u16* g, u16* l) {
  __builtin_amdgcn_global_load_lds(
      (const __attribute__((address_space(1))) unsigned int*)g,
      (__attribute__((address_space(3))) unsigned int*)l, 16, 0, 0);
}

// ---------------- weight transpose + fp32->bf16 -------------------------
__global__ void transpose_convert(const float* __restrict__ src, u16* __restrict__ dst,
                                  int R, int C, int R2, int C2) {
  __shared__ float tile[32][33];
  int tx = threadIdx.x, ty = threadIdx.y;
  int r0 = blockIdx.x * 32, c0 = blockIdx.y * 32;
#pragma unroll
  for (int i = 0; i < 4; ++i) {
    int r = r0 + ty + i * 8, c = c0 + tx;
    tile[ty + i * 8][tx] = (r < R && c < C) ? src[(long)r * C + c] : 0.f;
  }
  __syncthreads();
#pragma unroll
  for (int i = 0; i < 4; ++i) {
    int c = c0 + ty + i * 8, r = r0 + tx;
    if (c < C2 && r < R2) dst[(long)c * R2 + r] = f2bf(tile[tx][ty + i * 8]);
  }
}

// ---------------- fp32 -> bf16 (vector) ---------------------------------
__global__ void cvt_bf16_kernel(const float* __restrict__ in, u16* __restrict__ out, long n4) {
  long i = (long)blockIdx.x * 256 + threadIdx.x;
  if (i >= n4) return;
  float4 v = *(const float4*)&in[i * 4];
  ushort4 pk = {f2bf(v.x), f2bf(v.y), f2bf(v.z), f2bf(v.w)};
  *(ushort4*)&out[i * 4] = pk;
}

// ---------------- silu(c) + mods matvec (k-split, deterministic) ----------
__global__ void silu_kernel(const float* __restrict__ c, float* __restrict__ sc) {
  int i = blockIdx.x * 256 + threadIdx.x;
  float v = c[i];
  sc[i] = v / (1.f + __expf(-v));
}

#define MODS_KS 32
__global__ __launch_bounds__(256) void mods_partial(const float* __restrict__ sc,
                                                    const float* __restrict__ aw,
                                                    float* __restrict__ part) {
  int j = blockIdx.x * 256 + threadIdx.x;
  int ks = blockIdx.y;
  int d0 = ks * (DD / MODS_KS);
  float a0 = 0.f, a1 = 0.f, a2 = 0.f, a3 = 0.f;
#pragma unroll 8
  for (int d = d0; d < d0 + DD / MODS_KS; ++d) {
    float w = aw[(long)d * MODS_LD + j];
    a0 = fmaf(sc[d], w, a0);
    a1 = fmaf(sc[DD + d], w, a1);
    a2 = fmaf(sc[2 * DD + d], w, a2);
    a3 = fmaf(sc[3 * DD + d], w, a3);
  }
  long base = (long)ks * 4 * MODS_LD + j;
  part[base] = a0;
  part[base + MODS_LD] = a1;
  part[base + 2 * MODS_LD] = a2;
  part[base + 3 * MODS_LD] = a3;
}

__global__ __launch_bounds__(256) void mods_reduce(const float* __restrict__ part,
                                                   const float* __restrict__ ab,
                                                   float* __restrict__ mods) {
  int j = blockIdx.x * 256 + threadIdx.x;
  int b = blockIdx.y;
  float acc = ab[j];
#pragma unroll
  for (int ks = 0; ks < MODS_KS; ++ks) acc += part[((long)ks * 4 + b) * MODS_LD + j];
  mods[(long)b * MODS_LD + j] = acc;
}

// ---------------- fused RMSNorm + modulate -> bf16 ------------------------
__global__ __launch_bounds__(256) void rmsmod_kernel(const float* __restrict__ x,
                                                     const float* __restrict__ w,
                                                     const float* __restrict__ mods,
                                                     int shiftOff, int scaleOff,
                                                     u16* __restrict__ out) {
  long row = blockIdx.x;
  int b = (int)(row >> 10);
  int t = threadIdx.x;
  const float* xr = x + row * DD;
  float4 v = *(const float4*)&xr[t * 4];
  float ss = v.x * v.x + v.y * v.y + v.z * v.z + v.w * v.w;
#pragma unroll
  for (int msk = 1; msk < 64; msk <<= 1) ss += __shfl_xor(ss, msk);
  __shared__ float red[4];
  if ((t & 63) == 0) red[t >> 6] = ss;
  __syncthreads();
  float tot = red[0] + red[1] + red[2] + red[3];
  float inv = rsqrtf(tot * (1.f / DD) + 1e-6f);
  const float* mrow = mods + (long)b * MODS_LD;
  float vv[4] = {v.x, v.y, v.z, v.w};
  u16 tmp[4];
#pragma unroll
  for (int j = 0; j < 4; ++j) {
    int c = t * 4 + j;
    float rr = vv[j] * inv * w[c] * (1.f + mrow[scaleOff + c]) + mrow[shiftOff + c];
    tmp[j] = f2bf(rr);
  }
  ushort4 pk = {tmp[0], tmp[1], tmp[2], tmp[3]};
  *(ushort4*)&out[row * DD + t * 4] = pk;
}

// ---------------- q/k head-RMS-norm, in-place, vectorized -----------------
__global__ __launch_bounds__(256) void qknorm_kernel(u16* __restrict__ buf, int ld,
                                                     const float* __restrict__ w, float scale) {
  long row = blockIdx.x;
  int t = threadIdx.x;
  int g = t >> 4, p = t & 15;
  u16* ptr = buf + row * ld + g * 64 + p * 4;
  ushort4 a = *(ushort4*)ptr;
  float v[4] = {bf2f(a.x), bf2f(a.y), bf2f(a.z), bf2f(a.w)};
  float ss = v[0] * v[0] + v[1] * v[1] + v[2] * v[2] + v[3] * v[3];
  ss += __shfl_xor(ss, 1);
  ss += __shfl_xor(ss, 2);
  ss += __shfl_xor(ss, 4);
  ss += __shfl_xor(ss, 8);
  float inv = rsqrtf(ss * (1.f / 64) + 1e-6f) * scale;
  u16 o[4];
#pragma unroll
  for (int j = 0; j < 4; ++j) o[j] = f2bf(v[j] * inv * w[p * 4 + j]);
  ushort4 pk = {o[0], o[1], o[2], o[3]};
  *(ushort4*)ptr = pk;
}

// ---------------- V pre-transpose: v[b, kv, (h,d)] -> vt[(b,h), d, kv] -----
__global__ void vtrans_kernel(const u16* __restrict__ vb, int kvStride, int Mpb,
                              u16* __restrict__ vt) {
  __shared__ u16 tile[64][66];
  int t = threadIdx.x;
  int kt = blockIdx.x, h = blockIdx.y, b = blockIdx.z;
  const u16* base = vb + ((long)(b * Mpb + kt * 64)) * kvStride + h * 64;
#pragma unroll
  for (int sh = 0; sh < 2; ++sh) {
    int r = sh * 32 + (t >> 3);
    int c0 = (t & 7) * 8;
    short8 vv = *(const short8*)(base + (long)r * kvStride + c0);
#pragma unroll
    for (int j = 0; j < 8; ++j) tile[c0 + j][r] = (u16)vv[j];
  }
  __syncthreads();
  u16* obase = vt + ((long)(b * 16 + h) * 64) * 1024 + kt * 64;
#pragma unroll
  for (int sh = 0; sh < 2; ++sh) {
    int d = sh * 32 + (t >> 3);
    int c0 = (t & 7) * 8;
    u16 tmp[8];
#pragma unroll
    for (int j = 0; j < 8; ++j) tmp[j] = tile[d][c0 + j];
    *(short8*)(obase + (long)d * 1024 + c0) = *(short8*)tmp;
  }
}

// ---------------- small GEMM (128 x BN tiles, BN in {128, 64}) ------------
template <int MODE, int BN>
__global__ __launch_bounds__(256, 2) void gemm_bf16(
    const u16* __restrict__ A, const u16* __restrict__ Bt, int K, int ldc,
    const float* __restrict__ bias, int biasN, u16* __restrict__ outb,
    float* __restrict__ outf, const float* __restrict__ xin,
    const float* __restrict__ mods, int gateOff) {
  constexpr int WC = BN / 2;
  constexpr int NT = WC / 16;
  __shared__ u16 As[128 * 64];
  __shared__ u16 Bs[BN * 64];
  int t = threadIdx.x;
  int l = t & 63, w = t >> 6;
  int wr = w >> 1, wc = w & 1;
  int lg = l >> 4, ll = l & 15;
  long rowTile = (long)blockIdx.y * 128;
  long colTile = (long)blockIdx.x * BN;
  const u16* Ap = A + rowTile * K;
  const u16* Bp = Bt + colTile * K;
  int srow = t >> 3;
  int scol = (t & 7) * 8;

  f32x4 acc[4][NT] = {};

  for (int k0 = 0; k0 < K; k0 += 64) {
#pragma unroll
    for (int i = 0; i < 4; ++i)
      gload_lds16(Ap + (long)(i * 32 + srow) * K + k0 + scol, &As[(i * 256 + t) * 8]);
#pragma unroll
    for (int i = 0; i < BN / 32; ++i)
      gload_lds16(Bp + (long)(i * 32 + srow) * K + k0 + scol, &Bs[(i * 256 + t) * 8]);
    __syncthreads();
#pragma unroll
    for (int kk = 0; kk < 2; ++kk) {
      short8 af[4], bfr[NT];
#pragma unroll
      for (int m2 = 0; m2 < 4; ++m2)
        af[m2] = *(const short8*)&As[(wr * 64 + m2 * 16 + ll) * 64 + kk * 32 + lg * 8];
#pragma unroll
      for (int n2 = 0; n2 < NT; ++n2)
        bfr[n2] = *(const short8*)&Bs[(wc * WC + n2 * 16 + ll) * 64 + kk * 32 + lg * 8];
#pragma unroll
      for (int m2 = 0; m2 < 4; ++m2)
#pragma unroll
        for (int n2 = 0; n2 < NT; ++n2)
          acc[m2][n2] =
              __builtin_amdgcn_mfma_f32_16x16x32_bf16(af[m2], bfr[n2], acc[m2][n2], 0, 0, 0);
    }
    __syncthreads();
  }
#pragma unroll
  for (int n2 = 0; n2 < NT; ++n2) {
    long cg = colTile + wc * WC + n2 * 16 + ll;
    float bv = (cg < biasN) ? bias[cg] : 0.f;
#pragma unroll
    for (int m2 = 0; m2 < 4; ++m2) {
#pragma unroll
      for (int r = 0; r < 4; ++r) {
        long rg = rowTile + wr * 64 + m2 * 16 + lg * 4 + r;
        float v = acc[m2][n2][r] + bv;
        long idx = rg * ldc + cg;
        if (MODE == 0) {
          outb[idx] = f2bf(v);
        } else {
          int bb = (int)(rg >> 10);
          outf[idx] = xin[idx] + mods[(long)bb * MODS_LD + gateOff + cg] * v;
        }
      }
    }
  }
}

// ---------------- big GEMM: 256x256 tile, 8-phase schedule (m201 port) -----
#define LDA256(PBUF, MH)                                                          \
  {                                                                               \
    const u16* Ab = &As[PBUF][wr][0];                                             \
    _Pragma("unroll") for (int mq_ = 0; mq_ < 4; ++mq_)                           \
        _Pragma("unroll") for (int ks_ = 0; ks_ < 2; ++ks_) {                     \
      int rowl_ = ((MH)*4 + mq_) * 16 + ll;                                       \
      a[mq_][ks_] =                                                               \
          *(const short8*)&Ab[rowl_ * 64 + (((ks_ * 4 + lg) ^ (ll & 7)) << 3)];   \
    }                                                                             \
  }

#define LDB256(PBUF, NH, BR)                                                      \
  {                                                                               \
    const u16* Bb = &Bs[PBUF][wc >> 1][0];                                        \
    _Pragma("unroll") for (int nq_ = 0; nq_ < 2; ++nq_)                           \
        _Pragma("unroll") for (int ks_ = 0; ks_ < 2; ++ks_) {                     \
      int coll_ = (wc & 1) * 64 + ((NH)*2 + nq_) * 16 + ll;                       \
      BR[nq_][ks_] =                                                              \
          *(const short8*)&Bb[coll_ * 64 + (((ks_ * 4 + lg) ^ (ll & 7)) << 3)];   \
    }                                                                             \
  }

#define STAGE_A256(PBUF, H, KT)                                                   \
  if ((KT) < nt) {                                                                \
    _Pragma("unroll") for (int i_ = 0; i_ < 2; ++i_) {                            \
      int idx_ = i_ * 512 + t;                                                    \
      int rw_ = idx_ >> 3;                                                        \
      int sc_ = (idx_ & 7) ^ (rw_ & 7);                                           \
      gload_lds16(Aglob + (long)(rowTile + (H)*128 + rw_) * K + (KT)*64 + sc_ * 8,\
                  &As[PBUF][H][idx_ * 8]);                                        \
    }                                                                             \
  }

#define STAGE_B256(PBUF, H, KT)                                                   \
  if ((KT) < nt) {                                                                \
    _Pragma("unroll") for (int i_ = 0; i_ < 2; ++i_) {                            \
      int idx_ = i_ * 512 + t;                                                    \
      int rw_ = idx_ >> 3;                                                        \
      int sc_ = (idx_ & 7) ^ (rw_ & 7);                                           \
      gload_lds16(Bglob + (long)(colTile + (H)*128 + rw_) * K + (KT)*64 + sc_ * 8,\
                  &Bs[PBUF][H][idx_ * 8]);                                        \
    }                                                                             \
  }

#define MFMA_Q(MH, NH, BR)                                                        \
  _Pragma("unroll") for (int mq_ = 0; mq_ < 4; ++mq_)                             \
      _Pragma("unroll") for (int nq_ = 0; nq_ < 2; ++nq_)                         \
          _Pragma("unroll") for (int ks_ = 0; ks_ < 2; ++ks_)                     \
              acc[(MH)*4 + mq_][(NH)*2 + nq_] =                                   \
      __builtin_amdgcn_mfma_f32_16x16x32_bf16(                                    \
          a[mq_][ks_], BR[nq_][ks_], acc[(MH)*4 + mq_][(NH)*2 + nq_], 0, 0, 0);

#define PH_MFMA(MH, NH, BR)                                                       \
  __builtin_amdgcn_s_barrier();                                                   \
  asm volatile("s_waitcnt lgkmcnt(0)" ::: "memory");                              \
  __builtin_amdgcn_sched_barrier(0);                                              \
  __builtin_amdgcn_s_setprio(1);                                                  \
  MFMA_Q(MH, NH, BR);                                                             \
  __builtin_amdgcn_s_setprio(0);

#define HALF256(P, Q, TT)                                                         \
  LDA256(P, 0);                                                                   \
  LDB256(P, 0, b0);                                                               \
  STAGE_B256(Q, 1, (TT) + 1);                                                     \
  PH_MFMA(0, 0, b0);                                                              \
  __builtin_amdgcn_s_barrier();                                                   \
  LDB256(P, 1, b1);                                                               \
  STAGE_A256(Q, 1, (TT) + 1);                                                     \
  PH_MFMA(0, 1, b1);                                                              \
  __builtin_amdgcn_s_barrier();                                                   \
  LDA256(P, 1);                                                                   \
  STAGE_B256(P, 0, (TT) + 2);                                                     \
  PH_MFMA(1, 1, b1);                                                              \
  __builtin_amdgcn_s_barrier();                                                   \
  STAGE_A256(P, 0, (TT) + 2);                                                     \
  PH_MFMA(1, 0, b0);                                                              \
  if ((TT) + 2 < nt) {                                                            \
    asm volatile("s_waitcnt vmcnt(4)" ::: "memory");                              \
  } else {                                                                        \
    asm volatile("s_waitcnt vmcnt(0)" ::: "memory");                              \
  }                                                                               \
  __builtin_amdgcn_s_barrier();

__global__ __launch_bounds__(512, 2) void gemm256_bf16(
    const u16* __restrict__ Aglob, const u16* __restrict__ Bglob, int K, int ldc,
    const float* __restrict__ bias, int biasN, u16* __restrict__ outb) {
  __shared__ __align__(16) u16 As[2][2][128 * 64];
  __shared__ __align__(16) u16 Bs[2][2][128 * 64];
  const int nt = K >> 6;
  int t = threadIdx.x;
  int wid = t >> 6, l = t & 63;
  int wr = wid >> 2, wc = wid & 3;
  int lg = l >> 4, ll = l & 15;

  int nwg = gridDim.x;
  int cpx = nwg >> 3;
  int id = blockIdx.x;
  int wg = (id & 7) * cpx + (id >> 3);
  int tm = wg & 15;
  int tn = wg >> 4;
  long rowTile = (long)tm * 256;
  long colTile = (long)tn * 256;

  f32x4 acc[8][4] = {};
  short8 a[4][2], b0[2][2], b1[2][2];

  STAGE_B256(0, 0, 0);
  STAGE_A256(0, 0, 0);
  STAGE_B256(0, 1, 0);
  STAGE_A256(0, 1, 0);
  STAGE_B256(1, 0, 1);
  STAGE_A256(1, 0, 1);
  asm volatile("s_waitcnt vmcnt(4)" ::: "memory");
  __builtin_amdgcn_s_barrier();

  for (int T = 0; T < nt; T += 2) {
    HALF256(0, 1, T);
    HALF256(1, 0, T + 1);
  }

#pragma unroll
  for (int m = 0; m < 8; ++m)
#pragma unroll
    for (int n = 0; n < 4; ++n) {
      long cg = colTile + wc * 64 + n * 16 + ll;
      float bv = (cg < biasN) ? bias[cg] : 0.f;
#pragma unroll
      for (int q = 0; q < 4; ++q) {
        long rg = rowTile + wr * 128 + m * 16 + lg * 4 + q;
        outb[rg * ldc + cg] = f2bf(acc[m][n][q] + bv);
      }
    }
}

// ---------------- flash attention v3: swapped QK^T, lane-local softmax -----
// grid (h, b, qt) so all q-tiles of one (b,h) share an XCD L2.
__global__ __launch_bounds__(256, 2) void attn_kernel(
    const u16* __restrict__ qb, int qStride, const u16* __restrict__ kb, int kvStride,
    const u16* __restrict__ vt, u16* __restrict__ outp, int Nk, int Mpb) {
  __shared__ u16 Qs[64 * 64];
  __shared__ u16 Ks[2][64 * 64];
  __shared__ u16 Vs[2][64 * 64];
  __shared__ u16 Ps[4][16 * 64];
  int t = threadIdx.x, w = t >> 6, l = t & 63;
  int h = blockIdx.x, b = blockIdx.y, qt = blockIdx.z;
  int lg = l >> 4, ll = l & 15;
  int rx = ll & 7;

  const u16* Qbase = qb + ((long)(b * NN + qt * 64)) * qStride + h * 64;
  const u16* Kbase = kb + ((long)b * Mpb) * kvStride + h * 64;
  const u16* Vbase = vt + ((long)(b * 16 + h) * 64) * 1024;

  int srow = t >> 3;
  int schunk = t & 7;

#pragma unroll
  for (int sh = 0; sh < 2; ++sh) {
    int row = sh * 32 + srow;
    int ck = schunk ^ (row & 7);
    gload_lds16(Qbase + (long)row * qStride + ck * 8, &Qs[sh * 2048 + t * 8]);
    gload_lds16(Kbase + (long)row * kvStride + ck * 8, &Ks[0][sh * 2048 + t * 8]);
    gload_lds16(Vbase + (long)row * 1024 + ck * 8, &Vs[0][sh * 2048 + t * 8]);
  }
  __syncthreads();

  short8 qf0 = *(const short8*)&Qs[(w * 16 + ll) * 64 + ((lg ^ rx) << 3)];
  short8 qf1 = *(const short8*)&Qs[(w * 16 + ll) * 64 + (((4 + lg) ^ rx) << 3)];

  float mrun = -1e30f, ssum = 0.f;
  f32x4 o[4] = {};

  int nt = Nk >> 6;
  int cur = 0;
  for (int kt = 0; kt < nt; ++kt) {
    if (kt + 1 < nt) {
      const u16* kn = Kbase + (long)(kt + 1) * 64 * kvStride;
      const u16* vn = Vbase + (kt + 1) * 64;
#pragma unroll
      for (int sh = 0; sh < 2; ++sh) {
        int row = sh * 32 + srow;
        int ck = schunk ^ (row & 7);
        gload_lds16(kn + (long)row * kvStride + ck * 8, &Ks[cur ^ 1][sh * 2048 + t * 8]);
        gload_lds16(vn + (long)row * 1024 + ck * 8, &Vs[cur ^ 1][sh * 2048 + t * 8]);
      }
    }
    const u16* Kc = Ks[cur];
    // S^T = K·Q^T : lane (ll,lg) holds S[key = n*16+lg*4+r][q = ll]
    f32x4 s[4] = {};
#pragma unroll
    for (int n = 0; n < 4; ++n) {
      short8 kf0 = *(const short8*)&Kc[(n * 16 + ll) * 64 + ((lg ^ rx) << 3)];
      short8 kf1 = *(const short8*)&Kc[(n * 16 + ll) * 64 + (((4 + lg) ^ rx) << 3)];
      s[n] = __builtin_amdgcn_mfma_f32_16x16x32_bf16(kf0, qf0, s[n], 0, 0, 0);
      s[n] = __builtin_amdgcn_mfma_f32_16x16x32_bf16(kf1, qf1, s[n], 0, 0, 0);
    }
    // lane-local row max (16 values) + 2 shuffles across the 4 replicas
    float t0 = fmaxf(fmaxf(s[0][0], s[0][1]), fmaxf(s[0][2], s[0][3]));
    float t1 = fmaxf(fmaxf(s[1][0], s[1][1]), fmaxf(s[1][2], s[1][3]));
    float t2 = fmaxf(fmaxf(s[2][0], s[2][1]), fmaxf(s[2][2], s[2][3]));
    float t3 = fmaxf(fmaxf(s[3][0], s[3][1]), fmaxf(s[3][2], s[3][3]));
    float pm = fmaxf(fmaxf(t0, t1), fmaxf(t2, t3));
    pm = fmaxf(pm, __shfl_xor(pm, 16));
    pm = fmaxf(pm, __shfl_xor(pm, 32));
    float nm = fmaxf(mrun, pm);
    float alpha = __expf(mrun - nm);
    float pn[4][4];
#pragma unroll
    for (int n = 0; n < 4; ++n)
#pragma unroll
      for (int r = 0; r < 4; ++r) pn[n][r] = __expf(s[n][r] - nm);
    float r0 = (pn[0][0] + pn[0][1]) + (pn[0][2] + pn[0][3]);
    float r1 = (pn[1][0] + pn[1][1]) + (pn[1][2] + pn[1][3]);
    float r2 = (pn[2][0] + pn[2][1]) + (pn[2][2] + pn[2][3]);
    float r3 = (pn[3][0] + pn[3][1]) + (pn[3][2] + pn[3][3]);
    float rs = (r0 + r1) + (r2 + r3);
    rs += __shfl_xor(rs, 16);
    rs += __shfl_xor(rs, 32);
    ssum = ssum * alpha + rs;
    mrun = nm;
    // pack P (q=ll row, keys n*16+lg*4..+3) -> swizzled b64 writes
#pragma unroll
    for (int n = 0; n < 4; ++n) {
      uint2 pkd;
      pkd.x = cvtpk_bf16(pn[n][0], pn[n][1]);
      pkd.y = cvtpk_bf16(pn[n][2], pn[n][3]);
      int gran = n * 2 + (lg >> 1);
      int perm = gran ^ rx;
      *(uint2*)&Ps[w][ll * 64 + perm * 8 + (lg & 1) * 4] = pkd;
    }
    // transport alpha to O-fragment rows (q = lg*4+r), rescale O
    float a0 = __shfl(alpha, lg * 4 + 0);
    float a1 = __shfl(alpha, lg * 4 + 1);
    float a2 = __shfl(alpha, lg * 4 + 2);
    float a3 = __shfl(alpha, lg * 4 + 3);
#pragma unroll
    for (int n = 0; n < 4; ++n) {
      o[n][0] *= a0;
      o[n][1] *= a1;
      o[n][2] *= a2;
      o[n][3] *= a3;
    }
    short8 pf0 = *(const short8*)&Ps[w][ll * 64 + ((lg ^ rx) << 3)];
    short8 pf1 = *(const short8*)&Ps[w][ll * 64 + (((4 + lg) ^ rx) << 3)];
    const u16* Vc = Vs[cur];
#pragma unroll
    for (int n = 0; n < 4; ++n) {
      short8 vf0 = *(const short8*)&Vc[(n * 16 + ll) * 64 + ((lg ^ rx) << 3)];
      short8 vf1 = *(const short8*)&Vc[(n * 16 + ll) * 64 + (((4 + lg) ^ rx) << 3)];
      o[n] = __builtin_amdgcn_mfma_f32_16x16x32_bf16(pf0, vf0, o[n], 0, 0, 0);
      o[n] = __builtin_amdgcn_mfma_f32_16x16x32_bf16(pf1, vf1, o[n], 0, 0, 0);
    }
    __syncthreads();
    cur ^= 1;
  }
  float s0 = __shfl(ssum, lg * 4 + 0);
  float s1 = __shfl(ssum, lg * 4 + 1);
  float s2 = __shfl(ssum, lg * 4 + 2);
  float s3 = __shfl(ssum, lg * 4 + 3);
  float i0 = 1.f / s0, i1 = 1.f / s1, i2 = 1.f / s2, i3 = 1.f / s3;
#pragma unroll
  for (int n = 0; n < 4; ++n) {
    float ir[4] = {i0, i1, i2, i3};
#pragma unroll
    for (int r = 0; r < 4; ++r) {
      long row = (long)b * NN + qt * 64 + w * 16 + lg * 4 + r;
      int col = h * 64 + n * 16 + ll;
      outp[row * DD + col] = f2bf(o[n][r] * ir[r]);
    }
  }
}

// ---------------- SwiGLU combine: h1 = silu(h1)*h2 ------------------------
__global__ void swiglu_kernel(u16* __restrict__ h1, const u16* __restrict__ h2, long n4) {
  long i = (long)blockIdx.x * 256 + threadIdx.x;
  if (i >= n4) return;
  ushort4 a = *(ushort4*)&h1[i * 4];
  ushort4 bq = *(const ushort4*)&h2[i * 4];
  u16 va[4] = {a.x, a.y, a.z, a.w}, vb[4] = {bq.x, bq.y, bq.z, bq.w};
  u16 oo[4];
#pragma unroll
  for (int j = 0; j < 4; ++j) {
    float f = bf2f(va[j]);
    float g = f / (1.f + __expf(-f));
    oo[j] = f2bf(g * bf2f(vb[j]));
  }
  ushort4 pk = {oo[0], oo[1], oo[2], oo[3]};
  *(ushort4*)&h1[i * 4] = pk;
}

extern "C" void kernel_launch(void* const* d_in, const int* in_sizes, int n_in,
                              void* d_out, int out_size, void* d_ws, size_t ws_size,
                              hipStream_t stream) {
  const float* x = (const float*)d_in[0];
  const float* src = (const float*)d_in[1];
  const float* c = (const float*)d_in[2];
  const float* ada_w = (const float*)d_in[3];
  const float* ada_b = (const float*)d_in[4];
  const float* n1_w = (const float*)d_in[5];
  const float* nc_w = (const float*)d_in[6];
  const float* n2_w = (const float*)d_in[7];
  const float* sa_qkv_w = (const float*)d_in[8];
  const float* sa_qkv_b = (const float*)d_in[9];
  const float* sa_qn_w = (const float*)d_in[10];
  const float* sa_kn_w = (const float*)d_in[11];
  const float* sa_o_w = (const float*)d_in[12];
  const float* sa_o_b = (const float*)d_in[13];
  const float* ca_q_w = (const float*)d_in[14];
  const float* ca_q_b = (const float*)d_in[15];
  const float* ca_kv_w = (const float*)d_in[16];
  const float* ca_kv_b = (const float*)d_in[17];
  const float* ca_qn_w = (const float*)d_in[18];
  const float* ca_kn_w = (const float*)d_in[19];
  const float* ca_o_w = (const float*)d_in[20];
  const float* ca_o_b = (const float*)d_in[21];
  const float* mlp_w1 = (const float*)d_in[22];
  const float* mlp_b1 = (const float*)d_in[23];
  const float* mlp_w2 = (const float*)d_in[24];
  const float* mlp_b2 = (const float*)d_in[25];
  const float* mlp_w3 = (const float*)d_in[26];
  const float* mlp_b3 = (const float*)d_in[27];
  float* out = (float*)d_out;

  char* p = (char*)d_ws;
  auto alloc = [&](size_t bytes) {
    char* r = p;
    p += (bytes + 255) & ~(size_t)255;
    return r;
  };
  float* mods = (float*)alloc(4l * 9216 * 4);
  float* sc = (float*)alloc(4096l * 4);
  float* part = (float*)alloc((long)MODS_KS * 4 * 9216 * 4);
  u16* qkvT = (u16*)alloc(3072l * 1024 * 2);
  u16* saoT = (u16*)alloc(1024l * 1024 * 2);
  u16* caqT = (u16*)alloc(1024l * 1024 * 2);
  u16* cakvT = (u16*)alloc(2048l * 1024 * 2);
  u16* caoT = (u16*)alloc(1024l * 1024 * 2);
  u16* w1T = (u16*)alloc(2816l * 1024 * 2);
  u16* w2T = (u16*)alloc(2816l * 1024 * 2);
  u16* w3T = (u16*)alloc(1024l * 2816 * 2);
  u16* xnb = (u16*)alloc(4096l * 1024 * 2);
  u16* srcb = (u16*)alloc(4096l * 1024 * 2);
  u16* bufA = (u16*)alloc(4096l * 3072 * 2);
  u16* bufB = (u16*)alloc(4096l * 2816 * 2);
  u16* attO = (u16*)alloc(4096l * 1024 * 2);
  u16* vtb = xnb;  // alias: xnb dead during attention

  dim3 tb(32, 8);
  transpose_convert<<<dim3(32, 96), tb, 0, stream>>>(sa_qkv_w, qkvT, 1024, 3072, 1024, 3072);
  transpose_convert<<<dim3(32, 32), tb, 0, stream>>>(sa_o_w, saoT, 1024, 1024, 1024, 1024);
  transpose_convert<<<dim3(32, 32), tb, 0, stream>>>(ca_q_w, caqT, 1024, 1024, 1024, 1024);
  transpose_convert<<<dim3(32, 64), tb, 0, stream>>>(ca_kv_w, cakvT, 1024, 2048, 1024, 2048);
  transpose_convert<<<dim3(32, 32), tb, 0, stream>>>(ca_o_w, caoT, 1024, 1024, 1024, 1024);
  transpose_convert<<<dim3(32, 88), tb, 0, stream>>>(mlp_w1, w1T, 1024, 2730, 1024, 2816);
  transpose_convert<<<dim3(32, 88), tb, 0, stream>>>(mlp_w2, w2T, 1024, 2730, 1024, 2816);
  transpose_convert<<<dim3(88, 32), tb, 0, stream>>>(mlp_w3, w3T, 2730, 1024, 2816, 1024);
  cvt_bf16_kernel<<<4096, 256, 0, stream>>>(src, srcb, 4096l * 1024 / 4);
  silu_kernel<<<16, 256, 0, stream>>>(c, sc);
  mods_partial<<<dim3(36, MODS_KS), 256, 0, stream>>>(sc, ada_w, part);
  mods_reduce<<<dim3(36, 4), 256, 0, stream>>>(part, ada_b, mods);

  // ---- self-attention sublayer
  rmsmod_kernel<<<4096, 256, 0, stream>>>(x, n1_w, mods, 0, 1024, xnb);
  gemm_bf16<0, 128><<<dim3(24, 32), 256, 0, stream>>>(xnb, qkvT, 1024, 3072, sa_qkv_b, 3072,
                                                      bufA, nullptr, nullptr, nullptr, 0);
  qknorm_kernel<<<4096, 256, 0, stream>>>(bufA, 3072, sa_qn_w, 0.125f);
  qknorm_kernel<<<4096, 256, 0, stream>>>(bufA + 1024, 3072, sa_kn_w, 1.0f);
  vtrans_kernel<<<dim3(16, 16, 4), 256, 0, stream>>>(bufA + 2048, 3072, 1024, vtb);
  attn_kernel<<<dim3(16, 4, 16), 256, 0, stream>>>(bufA, 3072, bufA + 1024, 3072, vtb, attO,
                                                   1024, 1024);
  gemm_bf16<1, 64><<<dim3(16, 32), 256, 0, stream>>>(attO, saoT, 1024, 1024, sa_o_b, 1024,
                                                     nullptr, out, x, mods, 2048);

  // ---- cross-attention sublayer
  rmsmod_kernel<<<4096, 256, 0, stream>>>(out, nc_w, mods, 3072, 4096, xnb);
  gemm_bf16<0, 64><<<dim3(16, 32), 256, 0, stream>>>(xnb, caqT, 1024, 1024, ca_q_b, 1024, bufA,
                                                     nullptr, nullptr, nullptr, 0);
  gemm_bf16<0, 128><<<dim3(16, 32), 256, 0, stream>>>(srcb, cakvT, 1024, 2048, ca_kv_b, 2048,
                                                      bufB, nullptr, nullptr, nullptr, 0);
  qknorm_kernel<<<4096, 256, 0, stream>>>(bufA, 1024, ca_qn_w, 0.125f);
  qknorm_kernel<<<4096, 256, 0, stream>>>(bufB, 2048, ca_kn_w, 1.0f);
  vtrans_kernel<<<dim3(16, 16, 4), 256, 0, stream>>>(bufB + 1024, 2048, 1024, vtb);
  attn_kernel<<<dim3(16, 4, 16), 256, 0, stream>>>(bufA, 1024, bufB, 2048, vtb, attO, 1024,
                                                   1024);
  gemm_bf16<1, 64><<<dim3(16, 32), 256, 0, stream>>>(attO, caoT, 1024, 1024, ca_o_b, 1024,
                                                     nullptr, out, out, mods, 5120);

  // ---- SwiGLU FFN sublayer
  rmsmod_kernel<<<4096, 256, 0, stream>>>(out, n2_w, mods, 6144, 7168, xnb);
  gemm256_bf16<<<dim3(16 * 11), 512, 0, stream>>>(xnb, w1T, 1024, 2816, mlp_b1, 2730, bufA);
  gemm256_bf16<<<dim3(16 * 11), 512, 0, stream>>>(xnb, w2T, 1024, 2816, mlp_b2, 2730, bufB);
  swiglu_kernel<<<(int)((4096l * 2816 / 4 + 255) / 256), 256, 0, stream>>>(bufA, bufB,
                                                                           4096l * 2816 / 4);
  gemm_bf16<1, 64><<<dim3(16, 32), 256, 0, stream>>>(bufA, w3T, 2816, 1024, mlp_b3, 1024,
                                                     nullptr, out, out, mods, 8192);
}

// Round 7
// 468.655 us; speedup vs baseline: 1.1633x; 1.0009x over previous
//
#include <hip/hip_runtime.h>

typedef unsigned short u16;
typedef __attribute__((ext_vector_type(8))) short short8;
typedef __attribute__((ext_vector_type(4))) float f32x4;

#define DD 1024
#define NN 1024
#define MODS_LD 9216

__device__ __forceinline__ float bf2f(u16 v) {
  unsigned int u = ((unsigned int)v) << 16;
  return __builtin_bit_cast(float, u);
}
__device__ __forceinline__ u16 f2bf(float f) {
  unsigned int u = __builtin_bit_cast(unsigned int, f);
  unsigned int lsb = (u >> 16) & 1;
  u += 0x7fffu + lsb;
  return (u16)(u >> 16);
}
__device__ __forceinline__ unsigned cvtpk_bf16(float a, float b) {
  unsigned r;
  asm volatile("v_cvt_pk_bf16_f32 %0, %1, %2" : "=v"(r) : "v"(a), "v"(b));
  return r;
}

__device__ __forceinline__ void gload_lds16(const u16* g, u16* l) {
  __builtin_amdgcn_global_load_lds(
      (const __attribute__((address_space(1))) unsigned int*)g,
      (__attribute__((address_space(3))) unsigned int*)l, 16, 0, 0);
}

// ---------------- weight transpose + fp32->bf16 -------------------------
__global__ void transpose_convert(const float* __restrict__ src, u16* __restrict__ dst,
                                  int R, int C, int R2, int C2) {
  __shared__ float tile[32][33];
  int tx = threadIdx.x, ty = threadIdx.y;
  int r0 = blockIdx.x * 32, c0 = blockIdx.y * 32;
#pragma unroll
  for (int i = 0; i < 4; ++i) {
    int r = r0 + ty + i * 8, c = c0 + tx;
    tile[ty + i * 8][tx] = (r < R && c < C) ? src[(long)r * C + c] : 0.f;
  }
  __syncthreads();
#pragma unroll
  for (int i = 0; i < 4; ++i) {
    int c = c0 + ty + i * 8, r = r0 + tx;
    if (c < C2 && r < R2) dst[(long)c * R2 + r] = f2bf(tile[tx][ty + i * 8]);
  }
}

// ---------------- fp32 -> bf16 (vector) ---------------------------------
__global__ void cvt_bf16_kernel(const float* __restrict__ in, u16* __restrict__ out, long n4) {
  long i = (long)blockIdx.x * 256 + threadIdx.x;
  if (i >= n4) return;
  float4 v = *(const float4*)&in[i * 4];
  ushort4 pk = {f2bf(v.x), f2bf(v.y), f2bf(v.z), f2bf(v.w)};
  *(ushort4*)&out[i * 4] = pk;
}

// ---------------- silu(c) + mods matvec (k-split, deterministic) ----------
__global__ void silu_kernel(const float* __restrict__ c, float* __restrict__ sc) {
  int i = blockIdx.x * 256 + threadIdx.x;
  float v = c[i];
  sc[i] = v / (1.f + __expf(-v));
}

#define MODS_KS 32
__global__ __launch_bounds__(256) void mods_partial(const float* __restrict__ sc,
                                                    const float* __restrict__ aw,
                                                    float* __restrict__ part) {
  int j = blockIdx.x * 256 + threadIdx.x;
  int ks = blockIdx.y;
  int d0 = ks * (DD / MODS_KS);
  float a0 = 0.f, a1 = 0.f, a2 = 0.f, a3 = 0.f;
#pragma unroll 8
  for (int d = d0; d < d0 + DD / MODS_KS; ++d) {
    float w = aw[(long)d * MODS_LD + j];
    a0 = fmaf(sc[d], w, a0);
    a1 = fmaf(sc[DD + d], w, a1);
    a2 = fmaf(sc[2 * DD + d], w, a2);
    a3 = fmaf(sc[3 * DD + d], w, a3);
  }
  long base = (long)ks * 4 * MODS_LD + j;
  part[base] = a0;
  part[base + MODS_LD] = a1;
  part[base + 2 * MODS_LD] = a2;
  part[base + 3 * MODS_LD] = a3;
}

__global__ __launch_bounds__(256) void mods_reduce(const float* __restrict__ part,
                                                   const float* __restrict__ ab,
                                                   float* __restrict__ mods) {
  int j = blockIdx.x * 256 + threadIdx.x;
  int b = blockIdx.y;
  float acc = ab[j];
#pragma unroll
  for (int ks = 0; ks < MODS_KS; ++ks) acc += part[((long)ks * 4 + b) * MODS_LD + j];
  mods[(long)b * MODS_LD + j] = acc;
}

// ---------------- fused RMSNorm + modulate -> bf16 ------------------------
__global__ __launch_bounds__(256) void rmsmod_kernel(const float* __restrict__ x,
                                                     const float* __restrict__ w,
                                                     const float* __restrict__ mods,
                                                     int shiftOff, int scaleOff,
                                                     u16* __restrict__ out) {
  long row = blockIdx.x;
  int b = (int)(row >> 10);
  int t = threadIdx.x;
  const float* xr = x + row * DD;
  float4 v = *(const float4*)&xr[t * 4];
  float ss = v.x * v.x + v.y * v.y + v.z * v.z + v.w * v.w;
#pragma unroll
  for (int msk = 1; msk < 64; msk <<= 1) ss += __shfl_xor(ss, msk);
  __shared__ float red[4];
  if ((t & 63) == 0) red[t >> 6] = ss;
  __syncthreads();
  float tot = red[0] + red[1] + red[2] + red[3];
  float inv = rsqrtf(tot * (1.f / DD) + 1e-6f);
  const float* mrow = mods + (long)b * MODS_LD;
  float vv[4] = {v.x, v.y, v.z, v.w};
  u16 tmp[4];
#pragma unroll
  for (int j = 0; j < 4; ++j) {
    int c = t * 4 + j;
    float rr = vv[j] * inv * w[c] * (1.f + mrow[scaleOff + c]) + mrow[shiftOff + c];
    tmp[j] = f2bf(rr);
  }
  ushort4 pk = {tmp[0], tmp[1], tmp[2], tmp[3]};
  *(ushort4*)&out[row * DD + t * 4] = pk;
}

// ---------------- q/k head-RMS-norm, in-place, vectorized -----------------
__global__ __launch_bounds__(256) void qknorm_kernel(u16* __restrict__ buf, int ld,
                                                     const float* __restrict__ w, float scale) {
  long row = blockIdx.x;
  int t = threadIdx.x;
  int g = t >> 4, p = t & 15;
  u16* ptr = buf + row * ld + g * 64 + p * 4;
  ushort4 a = *(ushort4*)ptr;
  float v[4] = {bf2f(a.x), bf2f(a.y), bf2f(a.z), bf2f(a.w)};
  float ss = v[0] * v[0] + v[1] * v[1] + v[2] * v[2] + v[3] * v[3];
  ss += __shfl_xor(ss, 1);
  ss += __shfl_xor(ss, 2);
  ss += __shfl_xor(ss, 4);
  ss += __shfl_xor(ss, 8);
  float inv = rsqrtf(ss * (1.f / 64) + 1e-6f) * scale;
  u16 o[4];
#pragma unroll
  for (int j = 0; j < 4; ++j) o[j] = f2bf(v[j] * inv * w[p * 4 + j]);
  ushort4 pk = {o[0], o[1], o[2], o[3]};
  *(ushort4*)ptr = pk;
}

// ---------------- V pre-transpose: v[b, kv, (h,d)] -> vt[(b,h), d, kv] -----
__global__ void vtrans_kernel(const u16* __restrict__ vb, int kvStride, int Mpb,
                              u16* __restrict__ vt) {
  __shared__ u16 tile[64][66];
  int t = threadIdx.x;
  int kt = blockIdx.x, h = blockIdx.y, b = blockIdx.z;
  const u16* base = vb + ((long)(b * Mpb + kt * 64)) * kvStride + h * 64;
#pragma unroll
  for (int sh = 0; sh < 2; ++sh) {
    int r = sh * 32 + (t >> 3);
    int c0 = (t & 7) * 8;
    short8 vv = *(const short8*)(base + (long)r * kvStride + c0);
#pragma unroll
    for (int j = 0; j < 8; ++j) tile[c0 + j][r] = (u16)vv[j];
  }
  __syncthreads();
  u16* obase = vt + ((long)(b * 16 + h) * 64) * 1024 + kt * 64;
#pragma unroll
  for (int sh = 0; sh < 2; ++sh) {
    int d = sh * 32 + (t >> 3);
    int c0 = (t & 7) * 8;
    u16 tmp[8];
#pragma unroll
    for (int j = 0; j < 8; ++j) tmp[j] = tile[d][c0 + j];
    *(short8*)(obase + (long)d * 1024 + c0) = *(short8*)tmp;
  }
}

// ---------------- small GEMM: 128 x BN tiles, 2-phase dbuf (T3-min) -------
// MODE 0: outb = bf16(acc+bias).  MODE 1: outf = xin + gate*(acc+bias)
template <int MODE, int BN, int MINW>
__global__ __launch_bounds__(256, MINW) void gemm_bf16(
    const u16* __restrict__ A, const u16* __restrict__ Bt, int K, int ldc,
    const float* __restrict__ bias, int biasN, u16* __restrict__ outb,
    float* __restrict__ outf, const float* __restrict__ xin,
    const float* __restrict__ mods, int gateOff) {
  constexpr int WC = BN / 2;
  constexpr int NT = WC / 16;
  __shared__ u16 As[2][128 * 64];
  __shared__ u16 Bs[2][BN * 64];
  int t = threadIdx.x;
  int l = t & 63, w = t >> 6;
  int wr = w >> 1, wc = w & 1;
  int lg = l >> 4, ll = l & 15;
  long rowTile = (long)blockIdx.y * 128;
  long colTile = (long)blockIdx.x * BN;
  const u16* Ap = A + rowTile * K;
  const u16* Bp = Bt + colTile * K;
  int srow = t >> 3;
  int scol = (t & 7) * 8;

  f32x4 acc[4][NT] = {};

  auto stage = [&](int buf, int k0) {
#pragma unroll
    for (int i = 0; i < 4; ++i)
      gload_lds16(Ap + (long)(i * 32 + srow) * K + k0 + scol, &As[buf][(i * 256 + t) * 8]);
#pragma unroll
    for (int i = 0; i < BN / 32; ++i)
      gload_lds16(Bp + (long)(i * 32 + srow) * K + k0 + scol, &Bs[buf][(i * 256 + t) * 8]);
  };

  stage(0, 0);
  __syncthreads();
  int cur = 0;
  for (int k0 = 0; k0 < K; k0 += 64) {
    if (k0 + 64 < K) stage(cur ^ 1, k0 + 64);  // prefetch next tile (overlaps compute)
    const u16* Ac = As[cur];
    const u16* Bc = Bs[cur];
#pragma unroll
    for (int kk = 0; kk < 2; ++kk) {
      short8 af[4], bfr[NT];
#pragma unroll
      for (int m2 = 0; m2 < 4; ++m2)
        af[m2] = *(const short8*)&Ac[(wr * 64 + m2 * 16 + ll) * 64 + kk * 32 + lg * 8];
#pragma unroll
      for (int n2 = 0; n2 < NT; ++n2)
        bfr[n2] = *(const short8*)&Bc[(wc * WC + n2 * 16 + ll) * 64 + kk * 32 + lg * 8];
#pragma unroll
      for (int m2 = 0; m2 < 4; ++m2)
#pragma unroll
        for (int n2 = 0; n2 < NT; ++n2)
          acc[m2][n2] =
              __builtin_amdgcn_mfma_f32_16x16x32_bf16(af[m2], bfr[n2], acc[m2][n2], 0, 0, 0);
    }
    __syncthreads();  // drains vmcnt (next tile staged) + lgkm; protects dbuf swap
    cur ^= 1;
  }
#pragma unroll
  for (int n2 = 0; n2 < NT; ++n2) {
    long cg = colTile + wc * WC + n2 * 16 + ll;
    float bv = (cg < biasN) ? bias[cg] : 0.f;
#pragma unroll
    for (int m2 = 0; m2 < 4; ++m2) {
#pragma unroll
      for (int r = 0; r < 4; ++r) {
        long rg = rowTile + wr * 64 + m2 * 16 + lg * 4 + r;
        float v = acc[m2][n2][r] + bv;
        long idx = rg * ldc + cg;
        if (MODE == 0) {
          outb[idx] = f2bf(v);
        } else {
          int bb = (int)(rg >> 10);
          outf[idx] = xin[idx] + mods[(long)bb * MODS_LD + gateOff + cg] * v;
        }
      }
    }
  }
}

// ---------------- big GEMM: 256x256 tile, 8-phase schedule (m201 port) -----
// FUSE 0: outb = bf16(acc+bias).  FUSE 1 (swiglu): outb = bf16(silu(h1)*(acc+bias))
#define LDA256(PBUF, MH)                                                          \
  {                                                                               \
    const u16* Ab = &As[PBUF][wr][0];                                             \
    _Pragma("unroll") for (int mq_ = 0; mq_ < 4; ++mq_)                           \
        _Pragma("unroll") for (int ks_ = 0; ks_ < 2; ++ks_) {                     \
      int rowl_ = ((MH)*4 + mq_) * 16 + ll;                                       \
      a[mq_][ks_] =                                                               \
          *(const short8*)&Ab[rowl_ * 64 + (((ks_ * 4 + lg) ^ (ll & 7)) << 3)];   \
    }                                                                             \
  }

#define LDB256(PBUF, NH, BR)                                                      \
  {                                                                               \
    const u16* Bb = &Bs[PBUF][wc >> 1][0];                                        \
    _Pragma("unroll") for (int nq_ = 0; nq_ < 2; ++nq_)                           \
        _Pragma("unroll") for (int ks_ = 0; ks_ < 2; ++ks_) {                     \
      int coll_ = (wc & 1) * 64 + ((NH)*2 + nq_) * 16 + ll;                       \
      BR[nq_][ks_] =                                                              \
          *(const short8*)&Bb[coll_ * 64 + (((ks_ * 4 + lg) ^ (ll & 7)) << 3)];   \
    }                                                                             \
  }

#define STAGE_A256(PBUF, H, KT)                                                   \
  if ((KT) < nt) {                                                                \
    _Pragma("unroll") for (int i_ = 0; i_ < 2; ++i_) {                            \
      int idx_ = i_ * 512 + t;                                                    \
      int rw_ = idx_ >> 3;                                                        \
      int sc_ = (idx_ & 7) ^ (rw_ & 7);                                           \
      gload_lds16(Aglob + (long)(rowTile + (H)*128 + rw_) * K + (KT)*64 + sc_ * 8,\
                  &As[PBUF][H][idx_ * 8]);                                        \
    }                                                                             \
  }

#define STAGE_B256(PBUF, H, KT)                                                   \
  if ((KT) < nt) {                                                                \
    _Pragma("unroll") for (int i_ = 0; i_ < 2; ++i_) {                            \
      int idx_ = i_ * 512 + t;                                                    \
      int rw_ = idx_ >> 3;                                                        \
      int sc_ = (idx_ & 7) ^ (rw_ & 7);                                           \
      gload_lds16(Bglob + (long)(colTile + (H)*128 + rw_) * K + (KT)*64 + sc_ * 8,\
                  &Bs[PBUF][H][idx_ * 8]);                                        \
    }                                                                             \
  }

#define MFMA_Q(MH, NH, BR)                                                        \
  _Pragma("unroll") for (int mq_ = 0; mq_ < 4; ++mq_)                             \
      _Pragma("unroll") for (int nq_ = 0; nq_ < 2; ++nq_)                         \
          _Pragma("unroll") for (int ks_ = 0; ks_ < 2; ++ks_)                     \
              acc[(MH)*4 + mq_][(NH)*2 + nq_] =                                   \
      __builtin_amdgcn_mfma_f32_16x16x32_bf16(                                    \
          a[mq_][ks_], BR[nq_][ks_], acc[(MH)*4 + mq_][(NH)*2 + nq_], 0, 0, 0);

#define PH_MFMA(MH, NH, BR)                                                       \
  __builtin_amdgcn_s_barrier();                                                   \
  asm volatile("s_waitcnt lgkmcnt(0)" ::: "memory");                              \
  __builtin_amdgcn_sched_barrier(0);                                              \
  __builtin_amdgcn_s_setprio(1);                                                  \
  MFMA_Q(MH, NH, BR);                                                             \
  __builtin_amdgcn_s_setprio(0);

#define HALF256(P, Q, TT)                                                         \
  LDA256(P, 0);                                                                   \
  LDB256(P, 0, b0);                                                               \
  STAGE_B256(Q, 1, (TT) + 1);                                                     \
  PH_MFMA(0, 0, b0);                                                              \
  __builtin_amdgcn_s_barrier();                                                   \
  LDB256(P, 1, b1);                                                               \
  STAGE_A256(Q, 1, (TT) + 1);                                                     \
  PH_MFMA(0, 1, b1);                                                              \
  __builtin_amdgcn_s_barrier();                                                   \
  LDA256(P, 1);                                                                   \
  STAGE_B256(P, 0, (TT) + 2);                                                     \
  PH_MFMA(1, 1, b1);                                                              \
  __builtin_amdgcn_s_barrier();                                                   \
  STAGE_A256(P, 0, (TT) + 2);                                                     \
  PH_MFMA(1, 0, b0);                                                              \
  if ((TT) + 2 < nt) {                                                            \
    asm volatile("s_waitcnt vmcnt(4)" ::: "memory");                              \
  } else {                                                                        \
    asm volatile("s_waitcnt vmcnt(0)" ::: "memory");                              \
  }                                                                               \
  __builtin_amdgcn_s_barrier();

template <int FUSE>
__global__ __launch_bounds__(512, 2) void gemm256_bf16(
    const u16* __restrict__ Aglob, const u16* __restrict__ Bglob, int K, int ldc,
    const float* __restrict__ bias, int biasN, u16* __restrict__ outb,
    const u16* __restrict__ h1) {
  __shared__ __align__(16) u16 As[2][2][128 * 64];
  __shared__ __align__(16) u16 Bs[2][2][128 * 64];
  const int nt = K >> 6;
  int t = threadIdx.x;
  int wid = t >> 6, l = t & 63;
  int wr = wid >> 2, wc = wid & 3;
  int lg = l >> 4, ll = l & 15;

  int nwg = gridDim.x;
  int cpx = nwg >> 3;
  int id = blockIdx.x;
  int wg = (id & 7) * cpx + (id >> 3);
  int tm = wg & 15;
  int tn = wg >> 4;
  long rowTile = (long)tm * 256;
  long colTile = (long)tn * 256;

  f32x4 acc[8][4] = {};
  short8 a[4][2], b0[2][2], b1[2][2];

  STAGE_B256(0, 0, 0);
  STAGE_A256(0, 0, 0);
  STAGE_B256(0, 1, 0);
  STAGE_A256(0, 1, 0);
  STAGE_B256(1, 0, 1);
  STAGE_A256(1, 0, 1);
  asm volatile("s_waitcnt vmcnt(4)" ::: "memory");
  __builtin_amdgcn_s_barrier();

  for (int T = 0; T < nt; T += 2) {
    HALF256(0, 1, T);
    HALF256(1, 0, T + 1);
  }

#pragma unroll
  for (int m = 0; m < 8; ++m)
#pragma unroll
    for (int n = 0; n < 4; ++n) {
      long cg = colTile + wc * 64 + n * 16 + ll;
      float bv = (cg < biasN) ? bias[cg] : 0.f;
#pragma unroll
      for (int q = 0; q < 4; ++q) {
        long rg = rowTile + wr * 128 + m * 16 + lg * 4 + q;
        long idx = rg * ldc + cg;
        float v = acc[m][n][q] + bv;
        if (FUSE == 1) {
          float g = bf2f(h1[idx]);
          float sg = g / (1.f + __expf(-g));
          outb[idx] = f2bf(sg * v);
        } else {
          outb[idx] = f2bf(v);
        }
      }
    }
}

// ---------------- flash attention v3: swapped QK^T, lane-local softmax -----
__global__ __launch_bounds__(256, 3) void attn_kernel(
    const u16* __restrict__ qb, int qStride, const u16* __restrict__ kb, int kvStride,
    const u16* __restrict__ vt, u16* __restrict__ outp, int Nk, int Mpb) {
  __shared__ u16 Qs[64 * 64];
  __shared__ u16 Ks[2][64 * 64];
  __shared__ u16 Vs[2][64 * 64];
  __shared__ u16 Ps[4][16 * 64];
  int t = threadIdx.x, w = t >> 6, l = t & 63;
  int h = blockIdx.x, b = blockIdx.y, qt = blockIdx.z;
  int lg = l >> 4, ll = l & 15;
  int rx = ll & 7;

  const u16* Qbase = qb + ((long)(b * NN + qt * 64)) * qStride + h * 64;
  const u16* Kbase = kb + ((long)b * Mpb) * kvStride + h * 64;
  const u16* Vbase = vt + ((long)(b * 16 + h) * 64) * 1024;

  int srow = t >> 3;
  int schunk = t & 7;

#pragma unroll
  for (int sh = 0; sh < 2; ++sh) {
    int row = sh * 32 + srow;
    int ck = schunk ^ (row & 7);
    gload_lds16(Qbase + (long)row * qStride + ck * 8, &Qs[sh * 2048 + t * 8]);
    gload_lds16(Kbase + (long)row * kvStride + ck * 8, &Ks[0][sh * 2048 + t * 8]);
    gload_lds16(Vbase + (long)row * 1024 + ck * 8, &Vs[0][sh * 2048 + t * 8]);
  }
  __syncthreads();

  short8 qf0 = *(const short8*)&Qs[(w * 16 + ll) * 64 + ((lg ^ rx) << 3)];
  short8 qf1 = *(const short8*)&Qs[(w * 16 + ll) * 64 + (((4 + lg) ^ rx) << 3)];

  float mrun = -1e30f, ssum = 0.f;
  f32x4 o[4] = {};

  int nt = Nk >> 6;
  int cur = 0;
  for (int kt = 0; kt < nt; ++kt) {
    if (kt + 1 < nt) {
      const u16* kn = Kbase + (long)(kt + 1) * 64 * kvStride;
      const u16* vn = Vbase + (kt + 1) * 64;
#pragma unroll
      for (int sh = 0; sh < 2; ++sh) {
        int row = sh * 32 + srow;
        int ck = schunk ^ (row & 7);
        gload_lds16(kn + (long)row * kvStride + ck * 8, &Ks[cur ^ 1][sh * 2048 + t * 8]);
        gload_lds16(vn + (long)row * 1024 + ck * 8, &Vs[cur ^ 1][sh * 2048 + t * 8]);
      }
    }
    const u16* Kc = Ks[cur];
    f32x4 s[4] = {};
#pragma unroll
    for (int n = 0; n < 4; ++n) {
      short8 kf0 = *(const short8*)&Kc[(n * 16 + ll) * 64 + ((lg ^ rx) << 3)];
      short8 kf1 = *(const short8*)&Kc[(n * 16 + ll) * 64 + (((4 + lg) ^ rx) << 3)];
      s[n] = __builtin_amdgcn_mfma_f32_16x16x32_bf16(kf0, qf0, s[n], 0, 0, 0);
      s[n] = __builtin_amdgcn_mfma_f32_16x16x32_bf16(kf1, qf1, s[n], 0, 0, 0);
    }
    float t0 = fmaxf(fmaxf(s[0][0], s[0][1]), fmaxf(s[0][2], s[0][3]));
    float t1 = fmaxf(fmaxf(s[1][0], s[1][1]), fmaxf(s[1][2], s[1][3]));
    float t2 = fmaxf(fmaxf(s[2][0], s[2][1]), fmaxf(s[2][2], s[2][3]));
    float t3 = fmaxf(fmaxf(s[3][0], s[3][1]), fmaxf(s[3][2], s[3][3]));
    float pm = fmaxf(fmaxf(t0, t1), fmaxf(t2, t3));
    pm = fmaxf(pm, __shfl_xor(pm, 16));
    pm = fmaxf(pm, __shfl_xor(pm, 32));
    float nm = fmaxf(mrun, pm);
    float alpha = __expf(mrun - nm);
    float pn[4][4];
#pragma unroll
    for (int n = 0; n < 4; ++n)
#pragma unroll
      for (int r = 0; r < 4; ++r) pn[n][r] = __expf(s[n][r] - nm);
    float r0 = (pn[0][0] + pn[0][1]) + (pn[0][2] + pn[0][3]);
    float r1 = (pn[1][0] + pn[1][1]) + (pn[1][2] + pn[1][3]);
    float r2 = (pn[2][0] + pn[2][1]) + (pn[2][2] + pn[2][3]);
    float r3 = (pn[3][0] + pn[3][1]) + (pn[3][2] + pn[3][3]);
    float rs = (r0 + r1) + (r2 + r3);
    rs += __shfl_xor(rs, 16);
    rs += __shfl_xor(rs, 32);
    ssum = ssum * alpha + rs;
    mrun = nm;
#pragma unroll
    for (int n = 0; n < 4; ++n) {
      uint2 pkd;
      pkd.x = cvtpk_bf16(pn[n][0], pn[n][1]);
      pkd.y = cvtpk_bf16(pn[n][2], pn[n][3]);
      int gran = n * 2 + (lg >> 1);
      int perm = gran ^ rx;
      *(uint2*)&Ps[w][ll * 64 + perm * 8 + (lg & 1) * 4] = pkd;
    }
    float a0 = __shfl(alpha, lg * 4 + 0);
    float a1 = __shfl(alpha, lg * 4 + 1);
    float a2 = __shfl(alpha, lg * 4 + 2);
    float a3 = __shfl(alpha, lg * 4 + 3);
#pragma unroll
    for (int n = 0; n < 4; ++n) {
      o[n][0] *= a0;
      o[n][1] *= a1;
      o[n][2] *= a2;
      o[n][3] *= a3;
    }
    short8 pf0 = *(const short8*)&Ps[w][ll * 64 + ((lg ^ rx) << 3)];
    short8 pf1 = *(const short8*)&Ps[w][ll * 64 + (((4 + lg) ^ rx) << 3)];
    const u16* Vc = Vs[cur];
#pragma unroll
    for (int n = 0; n < 4; ++n) {
      short8 vf0 = *(const short8*)&Vc[(n * 16 + ll) * 64 + ((lg ^ rx) << 3)];
      short8 vf1 = *(const short8*)&Vc[(n * 16 + ll) * 64 + (((4 + lg) ^ rx) << 3)];
      o[n] = __builtin_amdgcn_mfma_f32_16x16x32_bf16(pf0, vf0, o[n], 0, 0, 0);
      o[n] = __builtin_amdgcn_mfma_f32_16x16x32_bf16(pf1, vf1, o[n], 0, 0, 0);
    }
    __syncthreads();
    cur ^= 1;
  }
  float s0 = __shfl(ssum, lg * 4 + 0);
  float s1 = __shfl(ssum, lg * 4 + 1);
  float s2 = __shfl(ssum, lg * 4 + 2);
  float s3 = __shfl(ssum, lg * 4 + 3);
  float i0 = 1.f / s0, i1 = 1.f / s1, i2 = 1.f / s2, i3 = 1.f / s3;
#pragma unroll
  for (int n = 0; n < 4; ++n) {
    float ir[4] = {i0, i1, i2, i3};
#pragma unroll
    for (int r = 0; r < 4; ++r) {
      long row = (long)b * NN + qt * 64 + w * 16 + lg * 4 + r;
      int col = h * 64 + n * 16 + ll;
      outp[row * DD + col] = f2bf(o[n][r] * ir[r]);
    }
  }
}

extern "C" void kernel_launch(void* const* d_in, const int* in_sizes, int n_in,
                              void* d_out, int out_size, void* d_ws, size_t ws_size,
                              hipStream_t stream) {
  const float* x = (const float*)d_in[0];
  const float* src = (const float*)d_in[1];
  const float* c = (const float*)d_in[2];
  const float* ada_w = (const float*)d_in[3];
  const float* ada_b = (const float*)d_in[4];
  const float* n1_w = (const float*)d_in[5];
  const float* nc_w = (const float*)d_in[6];
  const float* n2_w = (const float*)d_in[7];
  const float* sa_qkv_w = (const float*)d_in[8];
  const float* sa_qkv_b = (const float*)d_in[9];
  const float* sa_qn_w = (const float*)d_in[10];
  const float* sa_kn_w = (const float*)d_in[11];
  const float* sa_o_w = (const float*)d_in[12];
  const float* sa_o_b = (const float*)d_in[13];
  const float* ca_q_w = (const float*)d_in[14];
  const float* ca_q_b = (const float*)d_in[15];
  const float* ca_kv_w = (const float*)d_in[16];
  const float* ca_kv_b = (const float*)d_in[17];
  const float* ca_qn_w = (const float*)d_in[18];
  const float* ca_kn_w = (const float*)d_in[19];
  const float* ca_o_w = (const float*)d_in[20];
  const float* ca_o_b = (const float*)d_in[21];
  const float* mlp_w1 = (const float*)d_in[22];
  const float* mlp_b1 = (const float*)d_in[23];
  const float* mlp_w2 = (const float*)d_in[24];
  const float* mlp_b2 = (const float*)d_in[25];
  const float* mlp_w3 = (const float*)d_in[26];
  const float* mlp_b3 = (const float*)d_in[27];
  float* out = (float*)d_out;

  char* p = (char*)d_ws;
  auto alloc = [&](size_t bytes) {
    char* r = p;
    p += (bytes + 255) & ~(size_t)255;
    return r;
  };
  float* mods = (float*)alloc(4l * 9216 * 4);
  float* sc = (float*)alloc(4096l * 4);
  float* part = (float*)alloc((long)MODS_KS * 4 * 9216 * 4);
  u16* qkvT = (u16*)alloc(3072l * 1024 * 2);
  u16* saoT = (u16*)alloc(1024l * 1024 * 2);
  u16* caqT = (u16*)alloc(1024l * 1024 * 2);
  u16* cakvT = (u16*)alloc(2048l * 1024 * 2);
  u16* caoT = (u16*)alloc(1024l * 1024 * 2);
  u16* w1T = (u16*)alloc(2816l * 1024 * 2);
  u16* w2T = (u16*)alloc(2816l * 1024 * 2);
  u16* w3T = (u16*)alloc(1024l * 2816 * 2);
  u16* xnb = (u16*)alloc(4096l * 1024 * 2);
  u16* srcb = (u16*)alloc(4096l * 1024 * 2);
  u16* bufA = (u16*)alloc(4096l * 3072 * 2);
  u16* bufB = (u16*)alloc(4096l * 2816 * 2);
  u16* attO = (u16*)alloc(4096l * 1024 * 2);
  u16* vtb = xnb;  // alias: xnb dead during attention

  dim3 tb(32, 8);
  transpose_convert<<<dim3(32, 96), tb, 0, stream>>>(sa_qkv_w, qkvT, 1024, 3072, 1024, 3072);
  transpose_convert<<<dim3(32, 32), tb, 0, stream>>>(sa_o_w, saoT, 1024, 1024, 1024, 1024);
  transpose_convert<<<dim3(32, 32), tb, 0, stream>>>(ca_q_w, caqT, 1024, 1024, 1024, 1024);
  transpose_convert<<<dim3(32, 64), tb, 0, stream>>>(ca_kv_w, cakvT, 1024, 2048, 1024, 2048);
  transpose_convert<<<dim3(32, 32), tb, 0, stream>>>(ca_o_w, caoT, 1024, 1024, 1024, 1024);
  transpose_convert<<<dim3(32, 88), tb, 0, stream>>>(mlp_w1, w1T, 1024, 2730, 1024, 2816);
  transpose_convert<<<dim3(32, 88), tb, 0, stream>>>(mlp_w2, w2T, 1024, 2730, 1024, 2816);
  transpose_convert<<<dim3(88, 32), tb, 0, stream>>>(mlp_w3, w3T, 2730, 1024, 2816, 1024);
  cvt_bf16_kernel<<<4096, 256, 0, stream>>>(src, srcb, 4096l * 1024 / 4);
  silu_kernel<<<16, 256, 0, stream>>>(c, sc);
  mods_partial<<<dim3(36, MODS_KS), 256, 0, stream>>>(sc, ada_w, part);
  mods_reduce<<<dim3(36, 4), 256, 0, stream>>>(part, ada_b, mods);

  // ---- self-attention sublayer
  rmsmod_kernel<<<4096, 256, 0, stream>>>(x, n1_w, mods, 0, 1024, xnb);
  gemm_bf16<0, 128, 2><<<dim3(24, 32), 256, 0, stream>>>(xnb, qkvT, 1024, 3072, sa_qkv_b, 3072,
                                                         bufA, nullptr, nullptr, nullptr, 0);
  qknorm_kernel<<<4096, 256, 0, stream>>>(bufA, 3072, sa_qn_w, 0.125f);
  qknorm_kernel<<<4096, 256, 0, stream>>>(bufA + 1024, 3072, sa_kn_w, 1.0f);
  vtrans_kernel<<<dim3(16, 16, 4), 256, 0, stream>>>(bufA + 2048, 3072, 1024, vtb);
  attn_kernel<<<dim3(16, 4, 16), 256, 0, stream>>>(bufA, 3072, bufA + 1024, 3072, vtb, attO,
                                                   1024, 1024);
  gemm_bf16<1, 64, 3><<<dim3(16, 32), 256, 0, stream>>>(attO, saoT, 1024, 1024, sa_o_b, 1024,
                                                        nullptr, out, x, mods, 2048);

  // ---- cross-attention sublayer
  rmsmod_kernel<<<4096, 256, 0, stream>>>(out, nc_w, mods, 3072, 4096, xnb);
  gemm_bf16<0, 64, 3><<<dim3(16, 32), 256, 0, stream>>>(xnb, caqT, 1024, 1024, ca_q_b, 1024,
                                                        bufA, nullptr, nullptr, nullptr, 0);
  gemm_bf16<0, 128, 2><<<dim3(16, 32), 256, 0, stream>>>(srcb, cakvT, 1024, 2048, ca_kv_b, 2048,
                                                         bufB, nullptr, nullptr, nullptr, 0);
  qknorm_kernel<<<4096, 256, 0, stream>>>(bufA, 1024, ca_qn_w, 0.125f);
  qknorm_kernel<<<4096, 256, 0, stream>>>(bufB, 2048, ca_kn_w, 1.0f);
  vtrans_kernel<<<dim3(16, 16, 4), 256, 0, stream>>>(bufB + 1024, 2048, 1024, vtb);
  attn_kernel<<<dim3(16, 4, 16), 256, 0, stream>>>(bufA, 1024, bufB, 2048, vtb, attO, 1024,
                                                   1024);
  gemm_bf16<1, 64, 3><<<dim3(16, 32), 256, 0, stream>>>(attO, caoT, 1024, 1024, ca_o_b, 1024,
                                                        nullptr, out, out, mods, 5120);

  // ---- SwiGLU FFN sublayer (swiglu fused into w2 epilogue)
  rmsmod_kernel<<<4096, 256, 0, stream>>>(out, n2_w, mods, 6144, 7168, xnb);
  gemm256_bf16<0><<<dim3(16 * 11), 512, 0, stream>>>(xnb, w1T, 1024, 2816, mlp_b1, 2730, bufA,
                                                     nullptr);
  gemm256_bf16<1><<<dim3(16 * 11), 512, 0, stream>>>(xnb, w2T, 1024, 2816, mlp_b2, 2730, bufA,
                                                     bufA);
  gemm_bf16<1, 64, 3><<<dim3(16, 32), 256, 0, stream>>>(bufA, w3T, 2816, 1024, mlp_b3, 1024,
                                                        nullptr, out, out, mods, 8192);
}

// Round 8
// 444.724 us; speedup vs baseline: 1.2259x; 1.0538x over previous
//
#include <hip/hip_runtime.h>

typedef unsigned short u16;
typedef __attribute__((ext_vector_type(8))) short short8;
typedef __attribute__((ext_vector_type(4))) float f32x4;

#define DD 1024
#define NN 1024
#define MODS_LD 9216

__device__ __forceinline__ float bf2f(u16 v) {
  unsigned int u = ((unsigned int)v) << 16;
  return __builtin_bit_cast(float, u);
}
__device__ __forceinline__ u16 f2bf(float f) {
  unsigned int u = __builtin_bit_cast(unsigned int, f);
  unsigned int lsb = (u >> 16) & 1;
  u += 0x7fffu + lsb;
  return (u16)(u >> 16);
}
__device__ __forceinline__ unsigned cvtpk_bf16(float a, float b) {
  unsigned r;
  asm volatile("v_cvt_pk_bf16_f32 %0, %1, %2" : "=v"(r) : "v"(a), "v"(b));
  return r;
}

__device__ __forceinline__ void gload_lds16(const u16* g, u16* l) {
  __builtin_amdgcn_global_load_lds(
      (const __attribute__((address_space(1))) unsigned int*)g,
      (__attribute__((address_space(3))) unsigned int*)l, 16, 0, 0);
}

// ---------------- weight transpose + fp32->bf16 -------------------------
__global__ void transpose_convert(const float* __restrict__ src, u16* __restrict__ dst,
                                  int R, int C, int R2, int C2) {
  __shared__ float tile[32][33];
  int tx = threadIdx.x, ty = threadIdx.y;
  int r0 = blockIdx.x * 32, c0 = blockIdx.y * 32;
#pragma unroll
  for (int i = 0; i < 4; ++i) {
    int r = r0 + ty + i * 8, c = c0 + tx;
    tile[ty + i * 8][tx] = (r < R && c < C) ? src[(long)r * C + c] : 0.f;
  }
  __syncthreads();
#pragma unroll
  for (int i = 0; i < 4; ++i) {
    int c = c0 + ty + i * 8, r = r0 + tx;
    if (c < C2 && r < R2) dst[(long)c * R2 + r] = f2bf(tile[tx][ty + i * 8]);
  }
}

// ---------------- fp32 -> bf16 (vector) ---------------------------------
__global__ void cvt_bf16_kernel(const float* __restrict__ in, u16* __restrict__ out, long n4) {
  long i = (long)blockIdx.x * 256 + threadIdx.x;
  if (i >= n4) return;
  float4 v = *(const float4*)&in[i * 4];
  ushort4 pk = {f2bf(v.x), f2bf(v.y), f2bf(v.z), f2bf(v.w)};
  *(ushort4*)&out[i * 4] = pk;
}

// ---------------- silu(c) + mods matvec (k-split, deterministic) ----------
__global__ void silu_kernel(const float* __restrict__ c, float* __restrict__ sc) {
  int i = blockIdx.x * 256 + threadIdx.x;
  float v = c[i];
  sc[i] = v / (1.f + __expf(-v));
}

#define MODS_KS 32
__global__ __launch_bounds__(256) void mods_partial(const float* __restrict__ sc,
                                                    const float* __restrict__ aw,
                                                    float* __restrict__ part) {
  int j = blockIdx.x * 256 + threadIdx.x;
  int ks = blockIdx.y;
  int d0 = ks * (DD / MODS_KS);
  float a0 = 0.f, a1 = 0.f, a2 = 0.f, a3 = 0.f;
#pragma unroll 8
  for (int d = d0; d < d0 + DD / MODS_KS; ++d) {
    float w = aw[(long)d * MODS_LD + j];
    a0 = fmaf(sc[d], w, a0);
    a1 = fmaf(sc[DD + d], w, a1);
    a2 = fmaf(sc[2 * DD + d], w, a2);
    a3 = fmaf(sc[3 * DD + d], w, a3);
  }
  long base = (long)ks * 4 * MODS_LD + j;
  part[base] = a0;
  part[base + MODS_LD] = a1;
  part[base + 2 * MODS_LD] = a2;
  part[base + 3 * MODS_LD] = a3;
}

__global__ __launch_bounds__(256) void mods_reduce(const float* __restrict__ part,
                                                   const float* __restrict__ ab,
                                                   float* __restrict__ mods) {
  int j = blockIdx.x * 256 + threadIdx.x;
  int b = blockIdx.y;
  float acc = ab[j];
#pragma unroll
  for (int ks = 0; ks < MODS_KS; ++ks) acc += part[((long)ks * 4 + b) * MODS_LD + j];
  mods[(long)b * MODS_LD + j] = acc;
}

// ---------------- fused RMSNorm + modulate -> bf16 ------------------------
__global__ __launch_bounds__(256) void rmsmod_kernel(const float* __restrict__ x,
                                                     const float* __restrict__ w,
                                                     const float* __restrict__ mods,
                                                     int shiftOff, int scaleOff,
                                                     u16* __restrict__ out) {
  long row = blockIdx.x;
  int b = (int)(row >> 10);
  int t = threadIdx.x;
  const float* xr = x + row * DD;
  float4 v = *(const float4*)&xr[t * 4];
  float ss = v.x * v.x + v.y * v.y + v.z * v.z + v.w * v.w;
#pragma unroll
  for (int msk = 1; msk < 64; msk <<= 1) ss += __shfl_xor(ss, msk);
  __shared__ float red[4];
  if ((t & 63) == 0) red[t >> 6] = ss;
  __syncthreads();
  float tot = red[0] + red[1] + red[2] + red[3];
  float inv = rsqrtf(tot * (1.f / DD) + 1e-6f);
  const float* mrow = mods + (long)b * MODS_LD;
  float vv[4] = {v.x, v.y, v.z, v.w};
  u16 tmp[4];
#pragma unroll
  for (int j = 0; j < 4; ++j) {
    int c = t * 4 + j;
    float rr = vv[j] * inv * w[c] * (1.f + mrow[scaleOff + c]) + mrow[shiftOff + c];
    tmp[j] = f2bf(rr);
  }
  ushort4 pk = {tmp[0], tmp[1], tmp[2], tmp[3]};
  *(ushort4*)&out[row * DD + t * 4] = pk;
}

// ---------------- q/k head-RMS-norm, in-place, vectorized -----------------
__global__ __launch_bounds__(256) void qknorm_kernel(u16* __restrict__ buf, int ld,
                                                     const float* __restrict__ w, float scale) {
  long row = blockIdx.x;
  int t = threadIdx.x;
  int g = t >> 4, p = t & 15;
  u16* ptr = buf + row * ld + g * 64 + p * 4;
  ushort4 a = *(ushort4*)ptr;
  float v[4] = {bf2f(a.x), bf2f(a.y), bf2f(a.z), bf2f(a.w)};
  float ss = v[0] * v[0] + v[1] * v[1] + v[2] * v[2] + v[3] * v[3];
  ss += __shfl_xor(ss, 1);
  ss += __shfl_xor(ss, 2);
  ss += __shfl_xor(ss, 4);
  ss += __shfl_xor(ss, 8);
  float inv = rsqrtf(ss * (1.f / 64) + 1e-6f) * scale;
  u16 o[4];
#pragma unroll
  for (int j = 0; j < 4; ++j) o[j] = f2bf(v[j] * inv * w[p * 4 + j]);
  ushort4 pk = {o[0], o[1], o[2], o[3]};
  *(ushort4*)ptr = pk;
}

// ---------------- V pre-transpose: v[b, kv, (h,d)] -> vt[(b,h), d, kv] -----
__global__ void vtrans_kernel(const u16* __restrict__ vb, int kvStride, int Mpb,
                              u16* __restrict__ vt) {
  __shared__ u16 tile[64][66];
  int t = threadIdx.x;
  int kt = blockIdx.x, h = blockIdx.y, b = blockIdx.z;
  const u16* base = vb + ((long)(b * Mpb + kt * 64)) * kvStride + h * 64;
#pragma unroll
  for (int sh = 0; sh < 2; ++sh) {
    int r = sh * 32 + (t >> 3);
    int c0 = (t & 7) * 8;
    short8 vv = *(const short8*)(base + (long)r * kvStride + c0);
#pragma unroll
    for (int j = 0; j < 8; ++j) tile[c0 + j][r] = (u16)vv[j];
  }
  __syncthreads();
  u16* obase = vt + ((long)(b * 16 + h) * 64) * 1024 + kt * 64;
#pragma unroll
  for (int sh = 0; sh < 2; ++sh) {
    int d = sh * 32 + (t >> 3);
    int c0 = (t & 7) * 8;
    u16 tmp[8];
#pragma unroll
    for (int j = 0; j < 8; ++j) tmp[j] = tile[d][c0 + j];
    *(short8*)(obase + (long)d * 1024 + c0) = *(short8*)tmp;
  }
}

// ---------------- small GEMM: 128 x BN tiles, counted-vmcnt pipeline ------
// MODE 0: outb = bf16(acc+bias).  MODE 1: outf = xin + gate*(acc+bias)
// 1D grid (%8==0), bijective XCD swizzle, row-major block decomposition.
template <int MODE, int BN, int MINW>
__global__ __launch_bounds__(256, MINW) void gemm_bf16(
    const u16* __restrict__ A, const u16* __restrict__ Bt, int K, int ldc,
    const float* __restrict__ bias, int biasN, u16* __restrict__ outb,
    float* __restrict__ outf, const float* __restrict__ xin,
    const float* __restrict__ mods, int gateOff, int ncol) {
  constexpr int WC = BN / 2;
  constexpr int NT = WC / 16;
  constexpr int LOADS = 4 + BN / 32;
  __shared__ u16 As[2][128 * 64];
  __shared__ u16 Bs[2][BN * 64];
  int t = threadIdx.x;
  int l = t & 63, w = t >> 6;
  int wr = w >> 1, wc = w & 1;
  int lg = l >> 4, ll = l & 15;
  int nwg = gridDim.x, cpx = nwg >> 3, id = blockIdx.x;
  int wg = (id & 7) * cpx + (id >> 3);
  int tn = wg % ncol, tm = wg / ncol;
  long rowTile = (long)tm * 128;
  long colTile = (long)tn * BN;
  const u16* Ap = A + rowTile * K;
  const u16* Bp = Bt + colTile * K;
  int srow = t >> 3;
  int scol = (t & 7) * 8;

  auto stage = [&](int buf, int k0) {
#pragma unroll
    for (int i = 0; i < 4; ++i)
      gload_lds16(Ap + (long)(i * 32 + srow) * K + k0 + scol, &As[buf][(i * 256 + t) * 8]);
#pragma unroll
    for (int i = 0; i < BN / 32; ++i)
      gload_lds16(Bp + (long)(i * 32 + srow) * K + k0 + scol, &Bs[buf][(i * 256 + t) * 8]);
  };

  const int ntk = K >> 6;
  stage(0, 0);
  if (ntk > 1) stage(1, 64);

  f32x4 acc[4][NT] = {};
  int cur = 0;
  for (int i = 0; i < ntk; ++i) {
    if (i + 1 < ntk) {
      asm volatile("s_waitcnt vmcnt(%0)" ::"i"(LOADS) : "memory");
    } else {
      asm volatile("s_waitcnt vmcnt(0)" ::: "memory");
    }
    __builtin_amdgcn_s_barrier();
    const u16* Ac = As[cur];
    const u16* Bc = Bs[cur];
    short8 af[2][4], bfr[2][NT];
#pragma unroll
    for (int kk = 0; kk < 2; ++kk) {
#pragma unroll
      for (int m2 = 0; m2 < 4; ++m2)
        af[kk][m2] = *(const short8*)&Ac[(wr * 64 + m2 * 16 + ll) * 64 + kk * 32 + lg * 8];
#pragma unroll
      for (int n2 = 0; n2 < NT; ++n2)
        bfr[kk][n2] = *(const short8*)&Bc[(wc * WC + n2 * 16 + ll) * 64 + kk * 32 + lg * 8];
    }
    asm volatile("s_waitcnt lgkmcnt(0)" ::: "memory");
    __builtin_amdgcn_sched_barrier(0);
    __builtin_amdgcn_s_barrier();
    if (i + 2 < ntk) stage(cur, (i + 2) * 64);  // overlaps MFMA + next full iter
    __builtin_amdgcn_s_setprio(1);
#pragma unroll
    for (int kk = 0; kk < 2; ++kk)
#pragma unroll
      for (int m2 = 0; m2 < 4; ++m2)
#pragma unroll
        for (int n2 = 0; n2 < NT; ++n2)
          acc[m2][n2] = __builtin_amdgcn_mfma_f32_16x16x32_bf16(af[kk][m2], bfr[kk][n2],
                                                                acc[m2][n2], 0, 0, 0);
    __builtin_amdgcn_s_setprio(0);
    cur ^= 1;
  }
#pragma unroll
  for (int n2 = 0; n2 < NT; ++n2) {
    long cg = colTile + wc * WC + n2 * 16 + ll;
    float bv = (cg < biasN) ? bias[cg] : 0.f;
#pragma unroll
    for (int m2 = 0; m2 < 4; ++m2) {
#pragma unroll
      for (int r = 0; r < 4; ++r) {
        long rg = rowTile + wr * 64 + m2 * 16 + lg * 4 + r;
        float v = acc[m2][n2][r] + bv;
        long idx = rg * ldc + cg;
        if (MODE == 0) {
          outb[idx] = f2bf(v);
        } else {
          int bb = (int)(rg >> 10);
          outf[idx] = xin[idx] + mods[(long)bb * MODS_LD + gateOff + cg] * v;
        }
      }
    }
  }
}

// ---------------- big GEMM: 256x256 tile, 8-phase schedule (m201 port) -----
#define LDA256(PBUF, MH)                                                          \
  {                                                                               \
    const u16* Ab = &As[PBUF][wr][0];                                             \
    _Pragma("unroll") for (int mq_ = 0; mq_ < 4; ++mq_)                           \
        _Pragma("unroll") for (int ks_ = 0; ks_ < 2; ++ks_) {                     \
      int rowl_ = ((MH)*4 + mq_) * 16 + ll;                                       \
      a[mq_][ks_] =                                                               \
          *(const short8*)&Ab[rowl_ * 64 + (((ks_ * 4 + lg) ^ (ll & 7)) << 3)];   \
    }                                                                             \
  }

#define LDB256(PBUF, NH, BR)                                                      \
  {                                                                               \
    const u16* Bb = &Bs[PBUF][wc >> 1][0];                                        \
    _Pragma("unroll") for (int nq_ = 0; nq_ < 2; ++nq_)                           \
        _Pragma("unroll") for (int ks_ = 0; ks_ < 2; ++ks_) {                     \
      int coll_ = (wc & 1) * 64 + ((NH)*2 + nq_) * 16 + ll;                       \
      BR[nq_][ks_] =                                                              \
          *(const short8*)&Bb[coll_ * 64 + (((ks_ * 4 + lg) ^ (ll & 7)) << 3)];   \
    }                                                                             \
  }

#define STAGE_A256(PBUF, H, KT)                                                   \
  if ((KT) < nt) {                                                                \
    _Pragma("unroll") for (int i_ = 0; i_ < 2; ++i_) {                            \
      int idx_ = i_ * 512 + t;                                                    \
      int rw_ = idx_ >> 3;                                                        \
      int sc_ = (idx_ & 7) ^ (rw_ & 7);                                           \
      gload_lds16(Aglob + (long)(rowTile + (H)*128 + rw_) * K + (KT)*64 + sc_ * 8,\
                  &As[PBUF][H][idx_ * 8]);                                        \
    }                                                                             \
  }

#define STAGE_B256(PBUF, H, KT)                                                   \
  if ((KT) < nt) {                                                                \
    _Pragma("unroll") for (int i_ = 0; i_ < 2; ++i_) {                            \
      int idx_ = i_ * 512 + t;                                                    \
      int rw_ = idx_ >> 3;                                                        \
      int sc_ = (idx_ & 7) ^ (rw_ & 7);                                           \
      gload_lds16(Bglob + (long)(colTile + (H)*128 + rw_) * K + (KT)*64 + sc_ * 8,\
                  &Bs[PBUF][H][idx_ * 8]);                                        \
    }                                                                             \
  }

#define MFMA_Q(MH, NH, BR)                                                        \
  _Pragma("unroll") for (int mq_ = 0; mq_ < 4; ++mq_)                             \
      _Pragma("unroll") for (int nq_ = 0; nq_ < 2; ++nq_)                         \
          _Pragma("unroll") for (int ks_ = 0; ks_ < 2; ++ks_)                     \
              acc[(MH)*4 + mq_][(NH)*2 + nq_] =                                   \
      __builtin_amdgcn_mfma_f32_16x16x32_bf16(                                    \
          a[mq_][ks_], BR[nq_][ks_], acc[(MH)*4 + mq_][(NH)*2 + nq_], 0, 0, 0);

#define PH_MFMA(MH, NH, BR)                                                       \
  __builtin_amdgcn_s_barrier();                                                   \
  asm volatile("s_waitcnt lgkmcnt(0)" ::: "memory");                              \
  __builtin_amdgcn_sched_barrier(0);                                              \
  __builtin_amdgcn_s_setprio(1);                                                  \
  MFMA_Q(MH, NH, BR);                                                             \
  __builtin_amdgcn_s_setprio(0);

#define HALF256(P, Q, TT)                                                         \
  LDA256(P, 0);                                                                   \
  LDB256(P, 0, b0);                                                               \
  STAGE_B256(Q, 1, (TT) + 1);                                                     \
  PH_MFMA(0, 0, b0);                                                              \
  __builtin_amdgcn_s_barrier();                                                   \
  LDB256(P, 1, b1);                                                               \
  STAGE_A256(Q, 1, (TT) + 1);                                                     \
  PH_MFMA(0, 1, b1);                                                              \
  __builtin_amdgcn_s_barrier();                                                   \
  LDA256(P, 1);                                                                   \
  STAGE_B256(P, 0, (TT) + 2);                                                     \
  PH_MFMA(1, 1, b1);                                                              \
  __builtin_amdgcn_s_barrier();                                                   \
  STAGE_A256(P, 0, (TT) + 2);                                                     \
  PH_MFMA(1, 0, b0);                                                              \
  if ((TT) + 2 < nt) {                                                            \
    asm volatile("s_waitcnt vmcnt(4)" ::: "memory");                              \
  } else {                                                                        \
    asm volatile("s_waitcnt vmcnt(0)" ::: "memory");                              \
  }                                                                               \
  __builtin_amdgcn_s_barrier();

template <int FUSE>
__global__ __launch_bounds__(512, 2) void gemm256_bf16(
    const u16* __restrict__ Aglob, const u16* __restrict__ Bglob, int K, int ldc,
    const float* __restrict__ bias, int biasN, u16* __restrict__ outb,
    const u16* __restrict__ h1) {
  __shared__ __align__(16) u16 As[2][2][128 * 64];
  __shared__ __align__(16) u16 Bs[2][2][128 * 64];
  const int nt = K >> 6;
  int t = threadIdx.x;
  int wid = t >> 6, l = t & 63;
  int wr = wid >> 2, wc = wid & 3;
  int lg = l >> 4, ll = l & 15;

  int nwg = gridDim.x;
  int cpx = nwg >> 3;
  int id = blockIdx.x;
  int wg = (id & 7) * cpx + (id >> 3);
  int tm = wg & 15;
  int tn = wg >> 4;
  long rowTile = (long)tm * 256;
  long colTile = (long)tn * 256;

  f32x4 acc[8][4] = {};
  short8 a[4][2], b0[2][2], b1[2][2];

  STAGE_B256(0, 0, 0);
  STAGE_A256(0, 0, 0);
  STAGE_B256(0, 1, 0);
  STAGE_A256(0, 1, 0);
  STAGE_B256(1, 0, 1);
  STAGE_A256(1, 0, 1);
  asm volatile("s_waitcnt vmcnt(4)" ::: "memory");
  __builtin_amdgcn_s_barrier();

  for (int T = 0; T < nt; T += 2) {
    HALF256(0, 1, T);
    HALF256(1, 0, T + 1);
  }

#pragma unroll
  for (int m = 0; m < 8; ++m)
#pragma unroll
    for (int n = 0; n < 4; ++n) {
      long cg = colTile + wc * 64 + n * 16 + ll;
      float bv = (cg < biasN) ? bias[cg] : 0.f;
#pragma unroll
      for (int q = 0; q < 4; ++q) {
        long rg = rowTile + wr * 128 + m * 16 + lg * 4 + q;
        long idx = rg * ldc + cg;
        float v = acc[m][n][q] + bv;
        if (FUSE == 1) {
          float g = bf2f(h1[idx]);
          float sg = g / (1.f + __expf(-g));
          outb[idx] = f2bf(sg * v);
        } else {
          outb[idx] = f2bf(v);
        }
      }
    }
}

// ---------------- flash attention v4: counted-vmcnt pipeline ---------------
__global__ __launch_bounds__(256, 3) void attn_kernel(
    const u16* __restrict__ qb, int qStride, const u16* __restrict__ kb, int kvStride,
    const u16* __restrict__ vt, u16* __restrict__ outp, int Nk, int Mpb) {
  __shared__ u16 Qs[64 * 64];
  __shared__ u16 Ks[2][64 * 64];
  __shared__ u16 Vs[2][64 * 64];
  __shared__ u16 Ps[4][16 * 64];
  int t = threadIdx.x, w = t >> 6, l = t & 63;
  int h = blockIdx.x, b = blockIdx.y, qt = blockIdx.z;
  int lg = l >> 4, ll = l & 15;
  int rx = ll & 7;

  const u16* Qbase = qb + ((long)(b * NN + qt * 64)) * qStride + h * 64;
  const u16* Kbase = kb + ((long)b * Mpb) * kvStride + h * 64;
  const u16* Vbase = vt + ((long)(b * 16 + h) * 64) * 1024;

  int srow = t >> 3;
  int schunk = t & 7;

#pragma unroll
  for (int sh = 0; sh < 2; ++sh) {
    int row = sh * 32 + srow;
    int ck = schunk ^ (row & 7);
    gload_lds16(Qbase + (long)row * qStride + ck * 8, &Qs[sh * 2048 + t * 8]);
  }
  auto stageKV = [&](int buf, int kt) {
    const u16* kn = Kbase + (long)kt * 64 * kvStride;
    const u16* vn = Vbase + kt * 64;
#pragma unroll
    for (int sh = 0; sh < 2; ++sh) {
      int row = sh * 32 + srow;
      int ck = schunk ^ (row & 7);
      gload_lds16(kn + (long)row * kvStride + ck * 8, &Ks[buf][sh * 2048 + t * 8]);
      gload_lds16(vn + (long)row * 1024 + ck * 8, &Vs[buf][sh * 2048 + t * 8]);
    }
  };
  const int ntk = Nk >> 6;
  stageKV(0, 0);
  if (ntk > 1) stageKV(1, 1);

  short8 qf0, qf1;
  float mrun = -1e30f, ssum = 0.f;
  f32x4 o[4] = {};

  int cur = 0;
  for (int kt = 0; kt < ntk; ++kt) {
    if (kt + 1 < ntk) {
      asm volatile("s_waitcnt vmcnt(4)" ::: "memory");
    } else {
      asm volatile("s_waitcnt vmcnt(0)" ::: "memory");
    }
    __builtin_amdgcn_s_barrier();
    if (kt == 0) {
      qf0 = *(const short8*)&Qs[(w * 16 + ll) * 64 + ((lg ^ rx) << 3)];
      qf1 = *(const short8*)&Qs[(w * 16 + ll) * 64 + (((4 + lg) ^ rx) << 3)];
    }
    const u16* Kc = Ks[cur];
    f32x4 s[4] = {};
#pragma unroll
    for (int n = 0; n < 4; ++n) {
      short8 kf0 = *(const short8*)&Kc[(n * 16 + ll) * 64 + ((lg ^ rx) << 3)];
      short8 kf1 = *(const short8*)&Kc[(n * 16 + ll) * 64 + (((4 + lg) ^ rx) << 3)];
      s[n] = __builtin_amdgcn_mfma_f32_16x16x32_bf16(kf0, qf0, s[n], 0, 0, 0);
      s[n] = __builtin_amdgcn_mfma_f32_16x16x32_bf16(kf1, qf1, s[n], 0, 0, 0);
    }
    float t0 = fmaxf(fmaxf(s[0][0], s[0][1]), fmaxf(s[0][2], s[0][3]));
    float t1 = fmaxf(fmaxf(s[1][0], s[1][1]), fmaxf(s[1][2], s[1][3]));
    float t2 = fmaxf(fmaxf(s[2][0], s[2][1]), fmaxf(s[2][2], s[2][3]));
    float t3 = fmaxf(fmaxf(s[3][0], s[3][1]), fmaxf(s[3][2], s[3][3]));
    float pm = fmaxf(fmaxf(t0, t1), fmaxf(t2, t3));
    pm = fmaxf(pm, __shfl_xor(pm, 16));
    pm = fmaxf(pm, __shfl_xor(pm, 32));
    float nm = fmaxf(mrun, pm);
    float alpha = __expf(mrun - nm);
    float pn[4][4];
#pragma unroll
    for (int n = 0; n < 4; ++n)
#pragma unroll
      for (int r = 0; r < 4; ++r) pn[n][r] = __expf(s[n][r] - nm);
    float r0 = (pn[0][0] + pn[0][1]) + (pn[0][2] + pn[0][3]);
    float r1 = (pn[1][0] + pn[1][1]) + (pn[1][2] + pn[1][3]);
    float r2 = (pn[2][0] + pn[2][1]) + (pn[2][2] + pn[2][3]);
    float r3 = (pn[3][0] + pn[3][1]) + (pn[3][2] + pn[3][3]);
    float rs = (r0 + r1) + (r2 + r3);
    rs += __shfl_xor(rs, 16);
    rs += __shfl_xor(rs, 32);
    ssum = ssum * alpha + rs;
    mrun = nm;
#pragma unroll
    for (int n = 0; n < 4; ++n) {
      uint2 pkd;
      pkd.x = cvtpk_bf16(pn[n][0], pn[n][1]);
      pkd.y = cvtpk_bf16(pn[n][2], pn[n][3]);
      int gran = n * 2 + (lg >> 1);
      int perm = gran ^ rx;
      *(uint2*)&Ps[w][ll * 64 + perm * 8 + (lg & 1) * 4] = pkd;
    }
    float a0 = __shfl(alpha, lg * 4 + 0);
    float a1 = __shfl(alpha, lg * 4 + 1);
    float a2 = __shfl(alpha, lg * 4 + 2);
    float a3 = __shfl(alpha, lg * 4 + 3);
#pragma unroll
    for (int n = 0; n < 4; ++n) {
      o[n][0] *= a0;
      o[n][1] *= a1;
      o[n][2] *= a2;
      o[n][3] *= a3;
    }
    // read P + V fragments into regs, then release the buffer
    short8 pf0 = *(const short8*)&Ps[w][ll * 64 + ((lg ^ rx) << 3)];
    short8 pf1 = *(const short8*)&Ps[w][ll * 64 + (((4 + lg) ^ rx) << 3)];
    const u16* Vc = Vs[cur];
    short8 vfr[4][2];
#pragma unroll
    for (int n = 0; n < 4; ++n) {
      vfr[n][0] = *(const short8*)&Vc[(n * 16 + ll) * 64 + ((lg ^ rx) << 3)];
      vfr[n][1] = *(const short8*)&Vc[(n * 16 + ll) * 64 + (((4 + lg) ^ rx) << 3)];
    }
    asm volatile("s_waitcnt lgkmcnt(0)" ::: "memory");
    __builtin_amdgcn_sched_barrier(0);
    __builtin_amdgcn_s_barrier();
    if (kt + 2 < ntk) stageKV(cur, kt + 2);
    __builtin_amdgcn_s_setprio(1);
#pragma unroll
    for (int n = 0; n < 4; ++n) {
      o[n] = __builtin_amdgcn_mfma_f32_16x16x32_bf16(pf0, vfr[n][0], o[n], 0, 0, 0);
      o[n] = __builtin_amdgcn_mfma_f32_16x16x32_bf16(pf1, vfr[n][1], o[n], 0, 0, 0);
    }
    __builtin_amdgcn_s_setprio(0);
    cur ^= 1;
  }
  float s0 = __shfl(ssum, lg * 4 + 0);
  float s1 = __shfl(ssum, lg * 4 + 1);
  float s2 = __shfl(ssum, lg * 4 + 2);
  float s3 = __shfl(ssum, lg * 4 + 3);
  float i0 = 1.f / s0, i1 = 1.f / s1, i2 = 1.f / s2, i3 = 1.f / s3;
#pragma unroll
  for (int n = 0; n < 4; ++n) {
    float ir[4] = {i0, i1, i2, i3};
#pragma unroll
    for (int r = 0; r < 4; ++r) {
      long row = (long)b * NN + qt * 64 + w * 16 + lg * 4 + r;
      int col = h * 64 + n * 16 + ll;
      outp[row * DD + col] = f2bf(o[n][r] * ir[r]);
    }
  }
}

extern "C" void kernel_launch(void* const* d_in, const int* in_sizes, int n_in,
                              void* d_out, int out_size, void* d_ws, size_t ws_size,
                              hipStream_t stream) {
  const float* x = (const float*)d_in[0];
  const float* src = (const float*)d_in[1];
  const float* c = (const float*)d_in[2];
  const float* ada_w = (const float*)d_in[3];
  const float* ada_b = (const float*)d_in[4];
  const float* n1_w = (const float*)d_in[5];
  const float* nc_w = (const float*)d_in[6];
  const float* n2_w = (const float*)d_in[7];
  const float* sa_qkv_w = (const float*)d_in[8];
  const float* sa_qkv_b = (const float*)d_in[9];
  const float* sa_qn_w = (const float*)d_in[10];
  const float* sa_kn_w = (const float*)d_in[11];
  const float* sa_o_w = (const float*)d_in[12];
  const float* sa_o_b = (const float*)d_in[13];
  const float* ca_q_w = (const float*)d_in[14];
  const float* ca_q_b = (const float*)d_in[15];
  const float* ca_kv_w = (const float*)d_in[16];
  const float* ca_kv_b = (const float*)d_in[17];
  const float* ca_qn_w = (const float*)d_in[18];
  const float* ca_kn_w = (const float*)d_in[19];
  const float* ca_o_w = (const float*)d_in[20];
  const float* ca_o_b = (const float*)d_in[21];
  const float* mlp_w1 = (const float*)d_in[22];
  const float* mlp_b1 = (const float*)d_in[23];
  const float* mlp_w2 = (const float*)d_in[24];
  const float* mlp_b2 = (const float*)d_in[25];
  const float* mlp_w3 = (const float*)d_in[26];
  const float* mlp_b3 = (const float*)d_in[27];
  float* out = (float*)d_out;

  char* p = (char*)d_ws;
  auto alloc = [&](size_t bytes) {
    char* r = p;
    p += (bytes + 255) & ~(size_t)255;
    return r;
  };
  float* mods = (float*)alloc(4l * 9216 * 4);
  float* sc = (float*)alloc(4096l * 4);
  float* part = (float*)alloc((long)MODS_KS * 4 * 9216 * 4);
  u16* qkvT = (u16*)alloc(3072l * 1024 * 2);
  u16* saoT = (u16*)alloc(1024l * 1024 * 2);
  u16* caqT = (u16*)alloc(1024l * 1024 * 2);
  u16* cakvT = (u16*)alloc(2048l * 1024 * 2);
  u16* caoT = (u16*)alloc(1024l * 1024 * 2);
  u16* w1T = (u16*)alloc(2816l * 1024 * 2);
  u16* w2T = (u16*)alloc(2816l * 1024 * 2);
  u16* w3T = (u16*)alloc(1024l * 2816 * 2);
  u16* xnb = (u16*)alloc(4096l * 1024 * 2);
  u16* srcb = (u16*)alloc(4096l * 1024 * 2);
  u16* bufA = (u16*)alloc(4096l * 3072 * 2);
  u16* bufB = (u16*)alloc(4096l * 2816 * 2);
  u16* attO = (u16*)alloc(4096l * 1024 * 2);
  u16* vtb = xnb;  // alias: xnb dead during attention

  dim3 tb(32, 8);
  transpose_convert<<<dim3(32, 96), tb, 0, stream>>>(sa_qkv_w, qkvT, 1024, 3072, 1024, 3072);
  transpose_convert<<<dim3(32, 32), tb, 0, stream>>>(sa_o_w, saoT, 1024, 1024, 1024, 1024);
  transpose_convert<<<dim3(32, 32), tb, 0, stream>>>(ca_q_w, caqT, 1024, 1024, 1024, 1024);
  transpose_convert<<<dim3(32, 64), tb, 0, stream>>>(ca_kv_w, cakvT, 1024, 2048, 1024, 2048);
  transpose_convert<<<dim3(32, 32), tb, 0, stream>>>(ca_o_w, caoT, 1024, 1024, 1024, 1024);
  transpose_convert<<<dim3(32, 88), tb, 0, stream>>>(mlp_w1, w1T, 1024, 2730, 1024, 2816);
  transpose_convert<<<dim3(32, 88), tb, 0, stream>>>(mlp_w2, w2T, 1024, 2730, 1024, 2816);
  transpose_convert<<<dim3(88, 32), tb, 0, stream>>>(mlp_w3, w3T, 2730, 1024, 2816, 1024);
  cvt_bf16_kernel<<<4096, 256, 0, stream>>>(src, srcb, 4096l * 1024 / 4);
  silu_kernel<<<16, 256, 0, stream>>>(c, sc);
  mods_partial<<<dim3(36, MODS_KS), 256, 0, stream>>>(sc, ada_w, part);
  mods_reduce<<<dim3(36, 4), 256, 0, stream>>>(part, ada_b, mods);

  // ---- self-attention sublayer
  rmsmod_kernel<<<4096, 256, 0, stream>>>(x, n1_w, mods, 0, 1024, xnb);
  gemm_bf16<0, 128, 2><<<768, 256, 0, stream>>>(xnb, qkvT, 1024, 3072, sa_qkv_b, 3072, bufA,
                                                nullptr, nullptr, nullptr, 0, 24);
  qknorm_kernel<<<4096, 256, 0, stream>>>(bufA, 3072, sa_qn_w, 0.125f);
  qknorm_kernel<<<4096, 256, 0, stream>>>(bufA + 1024, 3072, sa_kn_w, 1.0f);
  vtrans_kernel<<<dim3(16, 16, 4), 256, 0, stream>>>(bufA + 2048, 3072, 1024, vtb);
  attn_kernel<<<dim3(16, 4, 16), 256, 0, stream>>>(bufA, 3072, bufA + 1024, 3072, vtb, attO,
                                                   1024, 1024);
  gemm_bf16<1, 64, 3><<<512, 256, 0, stream>>>(attO, saoT, 1024, 1024, sa_o_b, 1024, nullptr,
                                               out, x, mods, 2048, 16);

  // ---- cross-attention sublayer
  rmsmod_kernel<<<4096, 256, 0, stream>>>(out, nc_w, mods, 3072, 4096, xnb);
  gemm_bf16<0, 64, 3><<<512, 256, 0, stream>>>(xnb, caqT, 1024, 1024, ca_q_b, 1024, bufA,
                                               nullptr, nullptr, nullptr, 0, 16);
  gemm_bf16<0, 128, 2><<<512, 256, 0, stream>>>(srcb, cakvT, 1024, 2048, ca_kv_b, 2048, bufB,
                                                nullptr, nullptr, nullptr, 0, 16);
  qknorm_kernel<<<4096, 256, 0, stream>>>(bufA, 1024, ca_qn_w, 0.125f);
  qknorm_kernel<<<4096, 256, 0, stream>>>(bufB, 2048, ca_kn_w, 1.0f);
  vtrans_kernel<<<dim3(16, 16, 4), 256, 0, stream>>>(bufB + 1024, 2048, 1024, vtb);
  attn_kernel<<<dim3(16, 4, 16), 256, 0, stream>>>(bufA, 1024, bufB, 2048, vtb, attO, 1024,
                                                   1024);
  gemm_bf16<1, 64, 3><<<512, 256, 0, stream>>>(attO, caoT, 1024, 1024, ca_o_b, 1024, nullptr,
                                               out, out, mods, 5120, 16);

  // ---- SwiGLU FFN sublayer (swiglu fused into w2 epilogue)
  rmsmod_kernel<<<4096, 256, 0, stream>>>(out, n2_w, mods, 6144, 7168, xnb);
  gemm256_bf16<0><<<dim3(16 * 11), 512, 0, stream>>>(xnb, w1T, 1024, 2816, mlp_b1, 2730, bufA,
                                                     nullptr);
  gemm256_bf16<1><<<dim3(16 * 11), 512, 0, stream>>>(xnb, w2T, 1024, 2816, mlp_b2, 2730, bufA,
                                                     bufA);
  gemm_bf16<1, 64, 3><<<512, 256, 0, stream>>>(bufA, w3T, 2816, 1024, mlp_b3, 1024, nullptr,
                                               out, out, mods, 8192, 16);
}

// Round 9
// 426.019 us; speedup vs baseline: 1.2797x; 1.0439x over previous
//
#include <hip/hip_runtime.h>

typedef unsigned short u16;
typedef __attribute__((ext_vector_type(8))) short short8;
typedef __attribute__((ext_vector_type(4))) float f32x4;

#define DD 1024
#define NN 1024
#define MODS_LD 9216

__device__ __forceinline__ float bf2f(u16 v) {
  unsigned int u = ((unsigned int)v) << 16;
  return __builtin_bit_cast(float, u);
}
__device__ __forceinline__ u16 f2bf(float f) {
  unsigned int u = __builtin_bit_cast(unsigned int, f);
  unsigned int lsb = (u >> 16) & 1;
  u += 0x7fffu + lsb;
  return (u16)(u >> 16);
}
__device__ __forceinline__ unsigned cvtpk_bf16(float a, float b) {
  unsigned r;
  asm volatile("v_cvt_pk_bf16_f32 %0, %1, %2" : "=v"(r) : "v"(a), "v"(b));
  return r;
}

__device__ __forceinline__ void gload_lds16(const u16* g, u16* l) {
  __builtin_amdgcn_global_load_lds(
      (const __attribute__((address_space(1))) unsigned int*)g,
      (__attribute__((address_space(3))) unsigned int*)l, 16, 0, 0);
}

// ---------------- weight transpose + fp32->bf16 -------------------------
__global__ void transpose_convert(const float* __restrict__ src, u16* __restrict__ dst,
                                  int R, int C, int R2, int C2) {
  __shared__ float tile[32][33];
  int tx = threadIdx.x, ty = threadIdx.y;
  int r0 = blockIdx.x * 32, c0 = blockIdx.y * 32;
#pragma unroll
  for (int i = 0; i < 4; ++i) {
    int r = r0 + ty + i * 8, c = c0 + tx;
    tile[ty + i * 8][tx] = (r < R && c < C) ? src[(long)r * C + c] : 0.f;
  }
  __syncthreads();
#pragma unroll
  for (int i = 0; i < 4; ++i) {
    int c = c0 + ty + i * 8, r = r0 + tx;
    if (c < C2 && r < R2) dst[(long)c * R2 + r] = f2bf(tile[tx][ty + i * 8]);
  }
}

// ---------------- fp32 -> bf16 (vector) ---------------------------------
__global__ void cvt_bf16_kernel(const float* __restrict__ in, u16* __restrict__ out, long n4) {
  long i = (long)blockIdx.x * 256 + threadIdx.x;
  if (i >= n4) return;
  float4 v = *(const float4*)&in[i * 4];
  ushort4 pk = {f2bf(v.x), f2bf(v.y), f2bf(v.z), f2bf(v.w)};
  *(ushort4*)&out[i * 4] = pk;
}

// ---------------- silu(c) + mods matvec (k-split, deterministic) ----------
__global__ void silu_kernel(const float* __restrict__ c, float* __restrict__ sc) {
  int i = blockIdx.x * 256 + threadIdx.x;
  float v = c[i];
  sc[i] = v / (1.f + __expf(-v));
}

#define MODS_KS 32
__global__ __launch_bounds__(256) void mods_partial(const float* __restrict__ sc,
                                                    const float* __restrict__ aw,
                                                    float* __restrict__ part) {
  int j = blockIdx.x * 256 + threadIdx.x;
  int ks = blockIdx.y;
  int d0 = ks * (DD / MODS_KS);
  float a0 = 0.f, a1 = 0.f, a2 = 0.f, a3 = 0.f;
#pragma unroll 8
  for (int d = d0; d < d0 + DD / MODS_KS; ++d) {
    float w = aw[(long)d * MODS_LD + j];
    a0 = fmaf(sc[d], w, a0);
    a1 = fmaf(sc[DD + d], w, a1);
    a2 = fmaf(sc[2 * DD + d], w, a2);
    a3 = fmaf(sc[3 * DD + d], w, a3);
  }
  long base = (long)ks * 4 * MODS_LD + j;
  part[base] = a0;
  part[base + MODS_LD] = a1;
  part[base + 2 * MODS_LD] = a2;
  part[base + 3 * MODS_LD] = a3;
}

__global__ __launch_bounds__(256) void mods_reduce(const float* __restrict__ part,
                                                   const float* __restrict__ ab,
                                                   float* __restrict__ mods) {
  int j = blockIdx.x * 256 + threadIdx.x;
  int b = blockIdx.y;
  float acc = ab[j];
#pragma unroll
  for (int ks = 0; ks < MODS_KS; ++ks) acc += part[((long)ks * 4 + b) * MODS_LD + j];
  mods[(long)b * MODS_LD + j] = acc;
}

// ---------------- fused RMSNorm + modulate -> bf16 ------------------------
__global__ __launch_bounds__(256) void rmsmod_kernel(const float* __restrict__ x,
                                                     const float* __restrict__ w,
                                                     const float* __restrict__ mods,
                                                     int shiftOff, int scaleOff,
                                                     u16* __restrict__ out) {
  long row = blockIdx.x;
  int b = (int)(row >> 10);
  int t = threadIdx.x;
  const float* xr = x + row * DD;
  float4 v = *(const float4*)&xr[t * 4];
  float ss = v.x * v.x + v.y * v.y + v.z * v.z + v.w * v.w;
#pragma unroll
  for (int msk = 1; msk < 64; msk <<= 1) ss += __shfl_xor(ss, msk);
  __shared__ float red[4];
  if ((t & 63) == 0) red[t >> 6] = ss;
  __syncthreads();
  float tot = red[0] + red[1] + red[2] + red[3];
  float inv = rsqrtf(tot * (1.f / DD) + 1e-6f);
  const float* mrow = mods + (long)b * MODS_LD;
  float vv[4] = {v.x, v.y, v.z, v.w};
  u16 tmp[4];
#pragma unroll
  for (int j = 0; j < 4; ++j) {
    int c = t * 4 + j;
    float rr = vv[j] * inv * w[c] * (1.f + mrow[scaleOff + c]) + mrow[shiftOff + c];
    tmp[j] = f2bf(rr);
  }
  ushort4 pk = {tmp[0], tmp[1], tmp[2], tmp[3]};
  *(ushort4*)&out[row * DD + t * 4] = pk;
}

// ---------------- q/k head-RMS-norm, in-place, vectorized -----------------
__global__ __launch_bounds__(256) void qknorm_kernel(u16* __restrict__ buf, int ld,
                                                     const float* __restrict__ w, float scale) {
  long row = blockIdx.x;
  int t = threadIdx.x;
  int g = t >> 4, p = t & 15;
  u16* ptr = buf + row * ld + g * 64 + p * 4;
  ushort4 a = *(ushort4*)ptr;
  float v[4] = {bf2f(a.x), bf2f(a.y), bf2f(a.z), bf2f(a.w)};
  float ss = v[0] * v[0] + v[1] * v[1] + v[2] * v[2] + v[3] * v[3];
  ss += __shfl_xor(ss, 1);
  ss += __shfl_xor(ss, 2);
  ss += __shfl_xor(ss, 4);
  ss += __shfl_xor(ss, 8);
  float inv = rsqrtf(ss * (1.f / 64) + 1e-6f) * scale;
  u16 o[4];
#pragma unroll
  for (int j = 0; j < 4; ++j) o[j] = f2bf(v[j] * inv * w[p * 4 + j]);
  ushort4 pk = {o[0], o[1], o[2], o[3]};
  *(ushort4*)ptr = pk;
}

// ---------------- V pre-transpose: v[b, kv, (h,d)] -> vt[(b,h), d, kv] -----
__global__ void vtrans_kernel(const u16* __restrict__ vb, int kvStride, int Mpb,
                              u16* __restrict__ vt) {
  __shared__ u16 tile[64][66];
  int t = threadIdx.x;
  int kt = blockIdx.x, h = blockIdx.y, b = blockIdx.z;
  const u16* base = vb + ((long)(b * Mpb + kt * 64)) * kvStride + h * 64;
#pragma unroll
  for (int sh = 0; sh < 2; ++sh) {
    int r = sh * 32 + (t >> 3);
    int c0 = (t & 7) * 8;
    short8 vv = *(const short8*)(base + (long)r * kvStride + c0);
#pragma unroll
    for (int j = 0; j < 8; ++j) tile[c0 + j][r] = (u16)vv[j];
  }
  __syncthreads();
  u16* obase = vt + ((long)(b * 16 + h) * 64) * 1024 + kt * 64;
#pragma unroll
  for (int sh = 0; sh < 2; ++sh) {
    int d = sh * 32 + (t >> 3);
    int c0 = (t & 7) * 8;
    u16 tmp[8];
#pragma unroll
    for (int j = 0; j < 8; ++j) tmp[j] = tile[d][c0 + j];
    *(short8*)(obase + (long)d * 1024 + c0) = *(short8*)tmp;
  }
}

// ---------------- GEMM: 128 x BN tiles, counted-vmcnt + T2 swizzle --------
// MODE 0: outb = bf16(acc+bias)
// MODE 1: outf = xin + gate*(acc+bias)
// MODE 2: outb = bf16(silu(outb)*(acc+bias))   (swiglu, in-place h1=outb)
// LDS[row][c] holds global[row][c ^ (row&7)] (16B chunks); reads un-swizzle.
template <int MODE, int BN, int MINW>
__global__ __launch_bounds__(256, MINW) void gemm_bf16(
    const u16* __restrict__ A, const u16* __restrict__ Bt, int K, int ldc,
    const float* __restrict__ bias, int biasN, u16* __restrict__ outb,
    float* __restrict__ outf, const float* __restrict__ xin,
    const float* __restrict__ mods, int gateOff, int ncol) {
  constexpr int WC = BN / 2;
  constexpr int NT = WC / 16;
  constexpr int LOADS = 4 + BN / 32;
  __shared__ u16 As[2][128 * 64];
  __shared__ u16 Bs[2][BN * 64];
  int t = threadIdx.x;
  int l = t & 63, w = t >> 6;
  int wr = w >> 1, wc = w & 1;
  int lg = l >> 4, ll = l & 15;
  int rx = ll & 7;
  int nwg = gridDim.x, cpx = nwg >> 3, id = blockIdx.x;
  int wg = (id & 7) * cpx + (id >> 3);
  int tn = wg % ncol, tm = wg / ncol;
  long rowTile = (long)tm * 128;
  long colTile = (long)tn * BN;
  const u16* Ap = A + rowTile * K;
  const u16* Bp = Bt + colTile * K;
  int srow = t >> 3;
  int sck = ((t & 7) ^ (srow & 7)) * 8;  // inverse-swizzled global chunk

  auto stage = [&](int buf, int k0) {
#pragma unroll
    for (int i = 0; i < 4; ++i)
      gload_lds16(Ap + (long)(i * 32 + srow) * K + k0 + sck, &As[buf][(i * 256 + t) * 8]);
#pragma unroll
    for (int i = 0; i < BN / 32; ++i)
      gload_lds16(Bp + (long)(i * 32 + srow) * K + k0 + sck, &Bs[buf][(i * 256 + t) * 8]);
  };

  const int ntk = K >> 6;
  stage(0, 0);
  if (ntk > 1) stage(1, 64);

  f32x4 acc[4][NT] = {};
  int cur = 0;
  for (int i = 0; i < ntk; ++i) {
    if (i + 1 < ntk) {
      asm volatile("s_waitcnt vmcnt(%0)" ::"i"(LOADS) : "memory");
    } else {
      asm volatile("s_waitcnt vmcnt(0)" ::: "memory");
    }
    __builtin_amdgcn_s_barrier();
    const u16* Ac = As[cur];
    const u16* Bc = Bs[cur];
    short8 af[2][4], bfr[2][NT];
#pragma unroll
    for (int kk = 0; kk < 2; ++kk) {
#pragma unroll
      for (int m2 = 0; m2 < 4; ++m2)
        af[kk][m2] =
            *(const short8*)&Ac[(wr * 64 + m2 * 16 + ll) * 64 + (((kk * 4 + lg) ^ rx) << 3)];
#pragma unroll
      for (int n2 = 0; n2 < NT; ++n2)
        bfr[kk][n2] =
            *(const short8*)&Bc[(wc * WC + n2 * 16 + ll) * 64 + (((kk * 4 + lg) ^ rx) << 3)];
    }
    asm volatile("s_waitcnt lgkmcnt(0)" ::: "memory");
    __builtin_amdgcn_sched_barrier(0);
    __builtin_amdgcn_s_barrier();
    if (i + 2 < ntk) stage(cur, (i + 2) * 64);  // overlaps MFMA + next full iter
    __builtin_amdgcn_s_setprio(1);
#pragma unroll
    for (int kk = 0; kk < 2; ++kk)
#pragma unroll
      for (int m2 = 0; m2 < 4; ++m2)
#pragma unroll
        for (int n2 = 0; n2 < NT; ++n2)
          acc[m2][n2] = __builtin_amdgcn_mfma_f32_16x16x32_bf16(af[kk][m2], bfr[kk][n2],
                                                                acc[m2][n2], 0, 0, 0);
    __builtin_amdgcn_s_setprio(0);
    cur ^= 1;
  }
#pragma unroll
  for (int n2 = 0; n2 < NT; ++n2) {
    long cg = colTile + wc * WC + n2 * 16 + ll;
    float bv = (cg < biasN) ? bias[cg] : 0.f;
#pragma unroll
    for (int m2 = 0; m2 < 4; ++m2) {
#pragma unroll
      for (int r = 0; r < 4; ++r) {
        long rg = rowTile + wr * 64 + m2 * 16 + lg * 4 + r;
        float v = acc[m2][n2][r] + bv;
        long idx = rg * ldc + cg;
        if (MODE == 0) {
          outb[idx] = f2bf(v);
        } else if (MODE == 1) {
          int bb = (int)(rg >> 10);
          outf[idx] = xin[idx] + mods[(long)bb * MODS_LD + gateOff + cg] * v;
        } else {
          float g = bf2f(outb[idx]);
          float sg = g / (1.f + __expf(-g));
          outb[idx] = f2bf(sg * v);
        }
      }
    }
  }
}

// ---------------- flash attention v4: counted-vmcnt pipeline ---------------
__global__ __launch_bounds__(256, 3) void attn_kernel(
    const u16* __restrict__ qb, int qStride, const u16* __restrict__ kb, int kvStride,
    const u16* __restrict__ vt, u16* __restrict__ outp, int Nk, int Mpb) {
  __shared__ u16 Qs[64 * 64];
  __shared__ u16 Ks[2][64 * 64];
  __shared__ u16 Vs[2][64 * 64];
  __shared__ u16 Ps[4][16 * 64];
  int t = threadIdx.x, w = t >> 6, l = t & 63;
  int h = blockIdx.x, b = blockIdx.y, qt = blockIdx.z;
  int lg = l >> 4, ll = l & 15;
  int rx = ll & 7;

  const u16* Qbase = qb + ((long)(b * NN + qt * 64)) * qStride + h * 64;
  const u16* Kbase = kb + ((long)b * Mpb) * kvStride + h * 64;
  const u16* Vbase = vt + ((long)(b * 16 + h) * 64) * 1024;

  int srow = t >> 3;
  int schunk = t & 7;

#pragma unroll
  for (int sh = 0; sh < 2; ++sh) {
    int row = sh * 32 + srow;
    int ck = schunk ^ (row & 7);
    gload_lds16(Qbase + (long)row * qStride + ck * 8, &Qs[sh * 2048 + t * 8]);
  }
  auto stageKV = [&](int buf, int kt) {
    const u16* kn = Kbase + (long)kt * 64 * kvStride;
    const u16* vn = Vbase + kt * 64;
#pragma unroll
    for (int sh = 0; sh < 2; ++sh) {
      int row = sh * 32 + srow;
      int ck = schunk ^ (row & 7);
      gload_lds16(kn + (long)row * kvStride + ck * 8, &Ks[buf][sh * 2048 + t * 8]);
      gload_lds16(vn + (long)row * 1024 + ck * 8, &Vs[buf][sh * 2048 + t * 8]);
    }
  };
  const int ntk = Nk >> 6;
  stageKV(0, 0);
  if (ntk > 1) stageKV(1, 1);

  short8 qf0, qf1;
  float mrun = -1e30f, ssum = 0.f;
  f32x4 o[4] = {};

  int cur = 0;
  for (int kt = 0; kt < ntk; ++kt) {
    if (kt + 1 < ntk) {
      asm volatile("s_waitcnt vmcnt(4)" ::: "memory");
    } else {
      asm volatile("s_waitcnt vmcnt(0)" ::: "memory");
    }
    __builtin_amdgcn_s_barrier();
    if (kt == 0) {
      qf0 = *(const short8*)&Qs[(w * 16 + ll) * 64 + ((lg ^ rx) << 3)];
      qf1 = *(const short8*)&Qs[(w * 16 + ll) * 64 + (((4 + lg) ^ rx) << 3)];
    }
    const u16* Kc = Ks[cur];
    f32x4 s[4] = {};
#pragma unroll
    for (int n = 0; n < 4; ++n) {
      short8 kf0 = *(const short8*)&Kc[(n * 16 + ll) * 64 + ((lg ^ rx) << 3)];
      short8 kf1 = *(const short8*)&Kc[(n * 16 + ll) * 64 + (((4 + lg) ^ rx) << 3)];
      s[n] = __builtin_amdgcn_mfma_f32_16x16x32_bf16(kf0, qf0, s[n], 0, 0, 0);
      s[n] = __builtin_amdgcn_mfma_f32_16x16x32_bf16(kf1, qf1, s[n], 0, 0, 0);
    }
    float t0 = fmaxf(fmaxf(s[0][0], s[0][1]), fmaxf(s[0][2], s[0][3]));
    float t1 = fmaxf(fmaxf(s[1][0], s[1][1]), fmaxf(s[1][2], s[1][3]));
    float t2 = fmaxf(fmaxf(s[2][0], s[2][1]), fmaxf(s[2][2], s[2][3]));
    float t3 = fmaxf(fmaxf(s[3][0], s[3][1]), fmaxf(s[3][2], s[3][3]));
    float pm = fmaxf(fmaxf(t0, t1), fmaxf(t2, t3));
    pm = fmaxf(pm, __shfl_xor(pm, 16));
    pm = fmaxf(pm, __shfl_xor(pm, 32));
    float nm = fmaxf(mrun, pm);
    float alpha = __expf(mrun - nm);
    float pn[4][4];
#pragma unroll
    for (int n = 0; n < 4; ++n)
#pragma unroll
      for (int r = 0; r < 4; ++r) pn[n][r] = __expf(s[n][r] - nm);
    float r0 = (pn[0][0] + pn[0][1]) + (pn[0][2] + pn[0][3]);
    float r1 = (pn[1][0] + pn[1][1]) + (pn[1][2] + pn[1][3]);
    float r2 = (pn[2][0] + pn[2][1]) + (pn[2][2] + pn[2][3]);
    float r3 = (pn[3][0] + pn[3][1]) + (pn[3][2] + pn[3][3]);
    float rs = (r0 + r1) + (r2 + r3);
    rs += __shfl_xor(rs, 16);
    rs += __shfl_xor(rs, 32);
    ssum = ssum * alpha + rs;
    mrun = nm;
#pragma unroll
    for (int n = 0; n < 4; ++n) {
      uint2 pkd;
      pkd.x = cvtpk_bf16(pn[n][0], pn[n][1]);
      pkd.y = cvtpk_bf16(pn[n][2], pn[n][3]);
      int gran = n * 2 + (lg >> 1);
      int perm = gran ^ rx;
      *(uint2*)&Ps[w][ll * 64 + perm * 8 + (lg & 1) * 4] = pkd;
    }
    float a0 = __shfl(alpha, lg * 4 + 0);
    float a1 = __shfl(alpha, lg * 4 + 1);
    float a2 = __shfl(alpha, lg * 4 + 2);
    float a3 = __shfl(alpha, lg * 4 + 3);
#pragma unroll
    for (int n = 0; n < 4; ++n) {
      o[n][0] *= a0;
      o[n][1] *= a1;
      o[n][2] *= a2;
      o[n][3] *= a3;
    }
    short8 pf0 = *(const short8*)&Ps[w][ll * 64 + ((lg ^ rx) << 3)];
    short8 pf1 = *(const short8*)&Ps[w][ll * 64 + (((4 + lg) ^ rx) << 3)];
    const u16* Vc = Vs[cur];
    short8 vfr[4][2];
#pragma unroll
    for (int n = 0; n < 4; ++n) {
      vfr[n][0] = *(const short8*)&Vc[(n * 16 + ll) * 64 + ((lg ^ rx) << 3)];
      vfr[n][1] = *(const short8*)&Vc[(n * 16 + ll) * 64 + (((4 + lg) ^ rx) << 3)];
    }
    asm volatile("s_waitcnt lgkmcnt(0)" ::: "memory");
    __builtin_amdgcn_sched_barrier(0);
    __builtin_amdgcn_s_barrier();
    if (kt + 2 < ntk) stageKV(cur, kt + 2);
    __builtin_amdgcn_s_setprio(1);
#pragma unroll
    for (int n = 0; n < 4; ++n) {
      o[n] = __builtin_amdgcn_mfma_f32_16x16x32_bf16(pf0, vfr[n][0], o[n], 0, 0, 0);
      o[n] = __builtin_amdgcn_mfma_f32_16x16x32_bf16(pf1, vfr[n][1], o[n], 0, 0, 0);
    }
    __builtin_amdgcn_s_setprio(0);
    cur ^= 1;
  }
  float s0 = __shfl(ssum, lg * 4 + 0);
  float s1 = __shfl(ssum, lg * 4 + 1);
  float s2 = __shfl(ssum, lg * 4 + 2);
  float s3 = __shfl(ssum, lg * 4 + 3);
  float i0 = 1.f / s0, i1 = 1.f / s1, i2 = 1.f / s2, i3 = 1.f / s3;
#pragma unroll
  for (int n = 0; n < 4; ++n) {
    float ir[4] = {i0, i1, i2, i3};
#pragma unroll
    for (int r = 0; r < 4; ++r) {
      long row = (long)b * NN + qt * 64 + w * 16 + lg * 4 + r;
      int col = h * 64 + n * 16 + ll;
      outp[row * DD + col] = f2bf(o[n][r] * ir[r]);
    }
  }
}

extern "C" void kernel_launch(void* const* d_in, const int* in_sizes, int n_in,
                              void* d_out, int out_size, void* d_ws, size_t ws_size,
                              hipStream_t stream) {
  const float* x = (const float*)d_in[0];
  const float* src = (const float*)d_in[1];
  const float* c = (const float*)d_in[2];
  const float* ada_w = (const float*)d_in[3];
  const float* ada_b = (const float*)d_in[4];
  const float* n1_w = (const float*)d_in[5];
  const float* nc_w = (const float*)d_in[6];
  const float* n2_w = (const float*)d_in[7];
  const float* sa_qkv_w = (const float*)d_in[8];
  const float* sa_qkv_b = (const float*)d_in[9];
  const float* sa_qn_w = (const float*)d_in[10];
  const float* sa_kn_w = (const float*)d_in[11];
  const float* sa_o_w = (const float*)d_in[12];
  const float* sa_o_b = (const float*)d_in[13];
  const float* ca_q_w = (const float*)d_in[14];
  const float* ca_q_b = (const float*)d_in[15];
  const float* ca_kv_w = (const float*)d_in[16];
  const float* ca_kv_b = (const float*)d_in[17];
  const float* ca_qn_w = (const float*)d_in[18];
  const float* ca_kn_w = (const float*)d_in[19];
  const float* ca_o_w = (const float*)d_in[20];
  const float* ca_o_b = (const float*)d_in[21];
  const float* mlp_w1 = (const float*)d_in[22];
  const float* mlp_b1 = (const float*)d_in[23];
  const float* mlp_w2 = (const float*)d_in[24];
  const float* mlp_b2 = (const float*)d_in[25];
  const float* mlp_w3 = (const float*)d_in[26];
  const float* mlp_b3 = (const float*)d_in[27];
  float* out = (float*)d_out;

  char* p = (char*)d_ws;
  auto alloc = [&](size_t bytes) {
    char* r = p;
    p += (bytes + 255) & ~(size_t)255;
    return r;
  };
  float* mods = (float*)alloc(4l * 9216 * 4);
  float* sc = (float*)alloc(4096l * 4);
  float* part = (float*)alloc((long)MODS_KS * 4 * 9216 * 4);
  u16* qkvT = (u16*)alloc(3072l * 1024 * 2);
  u16* saoT = (u16*)alloc(1024l * 1024 * 2);
  u16* caqT = (u16*)alloc(1024l * 1024 * 2);
  u16* cakvT = (u16*)alloc(2048l * 1024 * 2);
  u16* caoT = (u16*)alloc(1024l * 1024 * 2);
  u16* w1T = (u16*)alloc(2816l * 1024 * 2);
  u16* w2T = (u16*)alloc(2816l * 1024 * 2);
  u16* w3T = (u16*)alloc(1024l * 2816 * 2);
  u16* xnb = (u16*)alloc(4096l * 1024 * 2);
  u16* srcb = (u16*)alloc(4096l * 1024 * 2);
  u16* bufA = (u16*)alloc(4096l * 3072 * 2);
  u16* bufB = (u16*)alloc(4096l * 2816 * 2);
  u16* attO = (u16*)alloc(4096l * 1024 * 2);
  u16* vtb = xnb;  // alias: xnb dead during attention

  dim3 tb(32, 8);
  transpose_convert<<<dim3(32, 96), tb, 0, stream>>>(sa_qkv_w, qkvT, 1024, 3072, 1024, 3072);
  transpose_convert<<<dim3(32, 32), tb, 0, stream>>>(sa_o_w, saoT, 1024, 1024, 1024, 1024);
  transpose_convert<<<dim3(32, 32), tb, 0, stream>>>(ca_q_w, caqT, 1024, 1024, 1024, 1024);
  transpose_convert<<<dim3(32, 64), tb, 0, stream>>>(ca_kv_w, cakvT, 1024, 2048, 1024, 2048);
  transpose_convert<<<dim3(32, 32), tb, 0, stream>>>(ca_o_w, caoT, 1024, 1024, 1024, 1024);
  transpose_convert<<<dim3(32, 88), tb, 0, stream>>>(mlp_w1, w1T, 1024, 2730, 1024, 2816);
  transpose_convert<<<dim3(32, 88), tb, 0, stream>>>(mlp_w2, w2T, 1024, 2730, 1024, 2816);
  transpose_convert<<<dim3(88, 32), tb, 0, stream>>>(mlp_w3, w3T, 2730, 1024, 2816, 1024);
  cvt_bf16_kernel<<<4096, 256, 0, stream>>>(src, srcb, 4096l * 1024 / 4);
  silu_kernel<<<16, 256, 0, stream>>>(c, sc);
  mods_partial<<<dim3(36, MODS_KS), 256, 0, stream>>>(sc, ada_w, part);
  mods_reduce<<<dim3(36, 4), 256, 0, stream>>>(part, ada_b, mods);

  // ---- self-attention sublayer
  rmsmod_kernel<<<4096, 256, 0, stream>>>(x, n1_w, mods, 0, 1024, xnb);
  gemm_bf16<0, 128, 2><<<768, 256, 0, stream>>>(xnb, qkvT, 1024, 3072, sa_qkv_b, 3072, bufA,
                                                nullptr, nullptr, nullptr, 0, 24);
  qknorm_kernel<<<4096, 256, 0, stream>>>(bufA, 3072, sa_qn_w, 0.125f);
  qknorm_kernel<<<4096, 256, 0, stream>>>(bufA + 1024, 3072, sa_kn_w, 1.0f);
  vtrans_kernel<<<dim3(16, 16, 4), 256, 0, stream>>>(bufA + 2048, 3072, 1024, vtb);
  attn_kernel<<<dim3(16, 4, 16), 256, 0, stream>>>(bufA, 3072, bufA + 1024, 3072, vtb, attO,
                                                   1024, 1024);
  gemm_bf16<1, 64, 3><<<512, 256, 0, stream>>>(attO, saoT, 1024, 1024, sa_o_b, 1024, nullptr,
                                               out, x, mods, 2048, 16);

  // ---- cross-attention sublayer
  rmsmod_kernel<<<4096, 256, 0, stream>>>(out, nc_w, mods, 3072, 4096, xnb);
  gemm_bf16<0, 64, 3><<<512, 256, 0, stream>>>(xnb, caqT, 1024, 1024, ca_q_b, 1024, bufA,
                                               nullptr, nullptr, nullptr, 0, 16);
  gemm_bf16<0, 128, 2><<<512, 256, 0, stream>>>(srcb, cakvT, 1024, 2048, ca_kv_b, 2048, bufB,
                                                nullptr, nullptr, nullptr, 0, 16);
  qknorm_kernel<<<4096, 256, 0, stream>>>(bufA, 1024, ca_qn_w, 0.125f);
  qknorm_kernel<<<4096, 256, 0, stream>>>(bufB, 2048, ca_kn_w, 1.0f);
  vtrans_kernel<<<dim3(16, 16, 4), 256, 0, stream>>>(bufB + 1024, 2048, 1024, vtb);
  attn_kernel<<<dim3(16, 4, 16), 256, 0, stream>>>(bufA, 1024, bufB, 2048, vtb, attO, 1024,
                                                   1024);
  gemm_bf16<1, 64, 3><<<512, 256, 0, stream>>>(attO, caoT, 1024, 1024, ca_o_b, 1024, nullptr,
                                               out, out, mods, 5120, 16);

  // ---- SwiGLU FFN sublayer (w1 -> bufA; w2 fused swiglu in-place on bufA)
  rmsmod_kernel<<<4096, 256, 0, stream>>>(out, n2_w, mods, 6144, 7168, xnb);
  gemm_bf16<0, 128, 2><<<704, 256, 0, stream>>>(xnb, w1T, 1024, 2816, mlp_b1, 2730, bufA,
                                                nullptr, nullptr, nullptr, 0, 22);
  gemm_bf16<2, 128, 2><<<704, 256, 0, stream>>>(xnb, w2T, 1024, 2816, mlp_b2, 2730, bufA,
                                                nullptr, nullptr, nullptr, 0, 22);
  gemm_bf16<1, 64, 3><<<512, 256, 0, stream>>>(bufA, w3T, 2816, 1024, mlp_b3, 1024, nullptr,
                                               out, out, mods, 8192, 16);
}

// Round 10
// 384.527 us; speedup vs baseline: 1.4178x; 1.1079x over previous
//
#include <hip/hip_runtime.h>

typedef unsigned short u16;
typedef __attribute__((ext_vector_type(8))) short short8;
typedef __attribute__((ext_vector_type(4))) float f32x4;

#define DD 1024
#define NN 1024
#define MODS_LD 9216

__device__ __forceinline__ float bf2f(u16 v) {
  unsigned int u = ((unsigned int)v) << 16;
  return __builtin_bit_cast(float, u);
}
__device__ __forceinline__ u16 f2bf(float f) {
  unsigned int u = __builtin_bit_cast(unsigned int, f);
  unsigned int lsb = (u >> 16) & 1;
  u += 0x7fffu + lsb;
  return (u16)(u >> 16);
}
__device__ __forceinline__ unsigned cvtpk_bf16(float a, float b) {
  unsigned r;
  asm volatile("v_cvt_pk_bf16_f32 %0, %1, %2" : "=v"(r) : "v"(a), "v"(b));
  return r;
}

__device__ __forceinline__ void gload_lds16(const u16* g, u16* l) {
  __builtin_amdgcn_global_load_lds(
      (const __attribute__((address_space(1))) unsigned int*)g,
      (__attribute__((address_space(3))) unsigned int*)l, 16, 0, 0);
}

// ---------------- weight transpose + fp32->bf16 -------------------------
__global__ void transpose_convert(const float* __restrict__ src, u16* __restrict__ dst,
                                  int R, int C, int R2, int C2) {
  __shared__ float tile[32][33];
  int tx = threadIdx.x, ty = threadIdx.y;
  int r0 = blockIdx.x * 32, c0 = blockIdx.y * 32;
#pragma unroll
  for (int i = 0; i < 4; ++i) {
    int r = r0 + ty + i * 8, c = c0 + tx;
    tile[ty + i * 8][tx] = (r < R && c < C) ? src[(long)r * C + c] : 0.f;
  }
  __syncthreads();
#pragma unroll
  for (int i = 0; i < 4; ++i) {
    int c = c0 + ty + i * 8, r = r0 + tx;
    if (c < C2 && r < R2) dst[(long)c * R2 + r] = f2bf(tile[tx][ty + i * 8]);
  }
}

// ---------------- fp32 -> bf16 (vector) ---------------------------------
__global__ void cvt_bf16_kernel(const float* __restrict__ in, u16* __restrict__ out, long n4) {
  long i = (long)blockIdx.x * 256 + threadIdx.x;
  if (i >= n4) return;
  float4 v = *(const float4*)&in[i * 4];
  ushort4 pk = {f2bf(v.x), f2bf(v.y), f2bf(v.z), f2bf(v.w)};
  *(ushort4*)&out[i * 4] = pk;
}

// ---------------- silu(c) + mods matvec (k-split, deterministic) ----------
__global__ void silu_kernel(const float* __restrict__ c, float* __restrict__ sc) {
  int i = blockIdx.x * 256 + threadIdx.x;
  float v = c[i];
  sc[i] = v / (1.f + __expf(-v));
}

#define MODS_KS 32
__global__ __launch_bounds__(256) void mods_partial(const float* __restrict__ sc,
                                                    const float* __restrict__ aw,
                                                    float* __restrict__ part) {
  int j = blockIdx.x * 256 + threadIdx.x;
  int ks = blockIdx.y;
  int d0 = ks * (DD / MODS_KS);
  float a0 = 0.f, a1 = 0.f, a2 = 0.f, a3 = 0.f;
#pragma unroll 8
  for (int d = d0; d < d0 + DD / MODS_KS; ++d) {
    float w = aw[(long)d * MODS_LD + j];
    a0 = fmaf(sc[d], w, a0);
    a1 = fmaf(sc[DD + d], w, a1);
    a2 = fmaf(sc[2 * DD + d], w, a2);
    a3 = fmaf(sc[3 * DD + d], w, a3);
  }
  long base = (long)ks * 4 * MODS_LD + j;
  part[base] = a0;
  part[base + MODS_LD] = a1;
  part[base + 2 * MODS_LD] = a2;
  part[base + 3 * MODS_LD] = a3;
}

__global__ __launch_bounds__(256) void mods_reduce(const float* __restrict__ part,
                                                   const float* __restrict__ ab,
                                                   float* __restrict__ mods) {
  int j = blockIdx.x * 256 + threadIdx.x;
  int b = blockIdx.y;
  float acc = ab[j];
#pragma unroll
  for (int ks = 0; ks < MODS_KS; ++ks) acc += part[((long)ks * 4 + b) * MODS_LD + j];
  mods[(long)b * MODS_LD + j] = acc;
}

// ---------------- fused RMSNorm + modulate -> bf16 ------------------------
__global__ __launch_bounds__(256) void rmsmod_kernel(const float* __restrict__ x,
                                                     const float* __restrict__ w,
                                                     const float* __restrict__ mods,
                                                     int shiftOff, int scaleOff,
                                                     u16* __restrict__ out) {
  long row = blockIdx.x;
  int b = (int)(row >> 10);
  int t = threadIdx.x;
  const float* xr = x + row * DD;
  float4 v = *(const float4*)&xr[t * 4];
  float ss = v.x * v.x + v.y * v.y + v.z * v.z + v.w * v.w;
#pragma unroll
  for (int msk = 1; msk < 64; msk <<= 1) ss += __shfl_xor(ss, msk);
  __shared__ float red[4];
  if ((t & 63) == 0) red[t >> 6] = ss;
  __syncthreads();
  float tot = red[0] + red[1] + red[2] + red[3];
  float inv = rsqrtf(tot * (1.f / DD) + 1e-6f);
  const float* mrow = mods + (long)b * MODS_LD;
  float vv[4] = {v.x, v.y, v.z, v.w};
  u16 tmp[4];
#pragma unroll
  for (int j = 0; j < 4; ++j) {
    int c = t * 4 + j;
    float rr = vv[j] * inv * w[c] * (1.f + mrow[scaleOff + c]) + mrow[shiftOff + c];
    tmp[j] = f2bf(rr);
  }
  ushort4 pk = {tmp[0], tmp[1], tmp[2], tmp[3]};
  *(ushort4*)&out[row * DD + t * 4] = pk;
}

// ---------------- q/k head-RMS-norm (both q and k in one launch) ----------
__global__ __launch_bounds__(256) void qknorm2_kernel(u16* __restrict__ bufq, int ldq,
                                                      const float* __restrict__ wq,
                                                      u16* __restrict__ bufk, int ldk,
                                                      const float* __restrict__ wk) {
  int which = blockIdx.y;
  u16* buf = which ? bufk : bufq;
  int ld = which ? ldk : ldq;
  const float* wgt = which ? wk : wq;
  float scale = which ? 1.0f : 0.125f;
  long row = blockIdx.x;
  int t = threadIdx.x;
  int g = t >> 4, p = t & 15;
  u16* ptr = buf + row * ld + g * 64 + p * 4;
  ushort4 a = *(ushort4*)ptr;
  float v[4] = {bf2f(a.x), bf2f(a.y), bf2f(a.z), bf2f(a.w)};
  float ss = v[0] * v[0] + v[1] * v[1] + v[2] * v[2] + v[3] * v[3];
  ss += __shfl_xor(ss, 1);
  ss += __shfl_xor(ss, 2);
  ss += __shfl_xor(ss, 4);
  ss += __shfl_xor(ss, 8);
  float inv = rsqrtf(ss * (1.f / 64) + 1e-6f) * scale;
  u16 o[4];
#pragma unroll
  for (int j = 0; j < 4; ++j) o[j] = f2bf(v[j] * inv * wgt[p * 4 + j]);
  ushort4 pk = {o[0], o[1], o[2], o[3]};
  *(ushort4*)ptr = pk;
}

// ---------------- V pre-transpose: v[b, kv, (h,d)] -> vt[(b,h), d, kv] -----
__global__ void vtrans_kernel(const u16* __restrict__ vb, int kvStride, int Mpb,
                              u16* __restrict__ vt) {
  __shared__ u16 tile[64][66];
  int t = threadIdx.x;
  int kt = blockIdx.x, h = blockIdx.y, b = blockIdx.z;
  const u16* base = vb + ((long)(b * Mpb + kt * 64)) * kvStride + h * 64;
#pragma unroll
  for (int sh = 0; sh < 2; ++sh) {
    int r = sh * 32 + (t >> 3);
    int c0 = (t & 7) * 8;
    short8 vv = *(const short8*)(base + (long)r * kvStride + c0);
#pragma unroll
    for (int j = 0; j < 8; ++j) tile[c0 + j][r] = (u16)vv[j];
  }
  __syncthreads();
  u16* obase = vt + ((long)(b * 16 + h) * 64) * 1024 + kt * 64;
#pragma unroll
  for (int sh = 0; sh < 2; ++sh) {
    int d = sh * 32 + (t >> 3);
    int c0 = (t & 7) * 8;
    u16 tmp[8];
#pragma unroll
    for (int j = 0; j < 8; ++j) tmp[j] = tile[d][c0 + j];
    *(short8*)(obase + (long)d * 1024 + c0) = *(short8*)tmp;
  }
}

// ---------------- GEMM: 128 x BN tiles, counted-vmcnt + T2 swizzle --------
// MODE 0: outb = bf16(acc+bias)
// MODE 1: outf = xin + gate*(acc+bias)
template <int MODE, int BN, int MINW>
__global__ __launch_bounds__(256, MINW) void gemm_bf16(
    const u16* __restrict__ A, const u16* __restrict__ Bt, int K, int ldc,
    const float* __restrict__ bias, int biasN, u16* __restrict__ outb,
    float* __restrict__ outf, const float* __restrict__ xin,
    const float* __restrict__ mods, int gateOff, int ncol) {
  constexpr int WC = BN / 2;
  constexpr int NT = WC / 16;
  constexpr int LOADS = 4 + BN / 32;
  __shared__ u16 As[2][128 * 64];
  __shared__ u16 Bs[2][BN * 64];
  int t = threadIdx.x;
  int l = t & 63, w = t >> 6;
  int wr = w >> 1, wc = w & 1;
  int lg = l >> 4, ll = l & 15;
  int rx = ll & 7;
  int nwg = gridDim.x, cpx = nwg >> 3, id = blockIdx.x;
  int wg = (id & 7) * cpx + (id >> 3);
  int tn = wg % ncol, tm = wg / ncol;
  long rowTile = (long)tm * 128;
  long colTile = (long)tn * BN;
  const u16* Ap = A + rowTile * K;
  const u16* Bp = Bt + colTile * K;
  int srow = t >> 3;
  int sck = ((t & 7) ^ (srow & 7)) * 8;

  auto stage = [&](int buf, int k0) {
#pragma unroll
    for (int i = 0; i < 4; ++i)
      gload_lds16(Ap + (long)(i * 32 + srow) * K + k0 + sck, &As[buf][(i * 256 + t) * 8]);
#pragma unroll
    for (int i = 0; i < BN / 32; ++i)
      gload_lds16(Bp + (long)(i * 32 + srow) * K + k0 + sck, &Bs[buf][(i * 256 + t) * 8]);
  };

  const int ntk = K >> 6;
  stage(0, 0);
  if (ntk > 1) stage(1, 64);

  f32x4 acc[4][NT] = {};
  int cur = 0;
  for (int i = 0; i < ntk; ++i) {
    if (i + 1 < ntk) {
      asm volatile("s_waitcnt vmcnt(%0)" ::"i"(LOADS) : "memory");
    } else {
      asm volatile("s_waitcnt vmcnt(0)" ::: "memory");
    }
    __builtin_amdgcn_s_barrier();
    const u16* Ac = As[cur];
    const u16* Bc = Bs[cur];
    short8 af[2][4], bfr[2][NT];
#pragma unroll
    for (int kk = 0; kk < 2; ++kk) {
#pragma unroll
      for (int m2 = 0; m2 < 4; ++m2)
        af[kk][m2] =
            *(const short8*)&Ac[(wr * 64 + m2 * 16 + ll) * 64 + (((kk * 4 + lg) ^ rx) << 3)];
#pragma unroll
      for (int n2 = 0; n2 < NT; ++n2)
        bfr[kk][n2] =
            *(const short8*)&Bc[(wc * WC + n2 * 16 + ll) * 64 + (((kk * 4 + lg) ^ rx) << 3)];
    }
    asm volatile("s_waitcnt lgkmcnt(0)" ::: "memory");
    __builtin_amdgcn_sched_barrier(0);
    __builtin_amdgcn_s_barrier();
    if (i + 2 < ntk) stage(cur, (i + 2) * 64);
    __builtin_amdgcn_s_setprio(1);
#pragma unroll
    for (int kk = 0; kk < 2; ++kk)
#pragma unroll
      for (int m2 = 0; m2 < 4; ++m2)
#pragma unroll
        for (int n2 = 0; n2 < NT; ++n2)
          acc[m2][n2] = __builtin_amdgcn_mfma_f32_16x16x32_bf16(af[kk][m2], bfr[kk][n2],
                                                                acc[m2][n2], 0, 0, 0);
    __builtin_amdgcn_s_setprio(0);
    cur ^= 1;
  }
#pragma unroll
  for (int n2 = 0; n2 < NT; ++n2) {
    long cg = colTile + wc * WC + n2 * 16 + ll;
    float bv = (cg < biasN) ? bias[cg] : 0.f;
#pragma unroll
    for (int m2 = 0; m2 < 4; ++m2) {
#pragma unroll
      for (int r = 0; r < 4; ++r) {
        long rg = rowTile + wr * 64 + m2 * 16 + lg * 4 + r;
        float v = acc[m2][n2][r] + bv;
        long idx = rg * ldc + cg;
        if (MODE == 0) {
          outb[idx] = f2bf(v);
        } else {
          int bb = (int)(rg >> 10);
          outf[idx] = xin[idx] + mods[(long)bb * MODS_LD + gateOff + cg] * v;
        }
      }
    }
  }
}

// ---------------- dual GEMM + swiglu: h = silu(A@B1+b1)*(A@B2+b2) ---------
// 128x64 tiles (per operand), counted-vmcnt, T2 swizzle. No h1 round-trip.
__global__ __launch_bounds__(256, 2) void gemm_dual_swiglu(
    const u16* __restrict__ A, const u16* __restrict__ B1t, const u16* __restrict__ B2t,
    int K, int ldc, const float* __restrict__ b1, const float* __restrict__ b2, int biasN,
    u16* __restrict__ outb, int ncol) {
  constexpr int BN = 64, WC = 32, NT = 2;
  __shared__ u16 As[2][128 * 64];
  __shared__ u16 B1s[2][BN * 64];
  __shared__ u16 B2s[2][BN * 64];
  int t = threadIdx.x;
  int l = t & 63, w = t >> 6;
  int wr = w >> 1, wc = w & 1;
  int lg = l >> 4, ll = l & 15;
  int rx = ll & 7;
  int nwg = gridDim.x, cpx = nwg >> 3, id = blockIdx.x;
  int wg = (id & 7) * cpx + (id >> 3);
  int tn = wg % ncol, tm = wg / ncol;
  long rowTile = (long)tm * 128;
  long colTile = (long)tn * BN;
  const u16* Ap = A + rowTile * K;
  const u16* B1p = B1t + colTile * K;
  const u16* B2p = B2t + colTile * K;
  int srow = t >> 3;
  int sck = ((t & 7) ^ (srow & 7)) * 8;

  auto stage = [&](int buf, int k0) {
#pragma unroll
    for (int i = 0; i < 4; ++i)
      gload_lds16(Ap + (long)(i * 32 + srow) * K + k0 + sck, &As[buf][(i * 256 + t) * 8]);
#pragma unroll
    for (int i = 0; i < 2; ++i) {
      gload_lds16(B1p + (long)(i * 32 + srow) * K + k0 + sck, &B1s[buf][(i * 256 + t) * 8]);
      gload_lds16(B2p + (long)(i * 32 + srow) * K + k0 + sck, &B2s[buf][(i * 256 + t) * 8]);
    }
  };

  const int ntk = K >> 6;
  stage(0, 0);
  if (ntk > 1) stage(1, 64);

  f32x4 acc1[4][NT] = {}, acc2[4][NT] = {};
  int cur = 0;
  for (int i = 0; i < ntk; ++i) {
    if (i + 1 < ntk) {
      asm volatile("s_waitcnt vmcnt(8)" ::: "memory");
    } else {
      asm volatile("s_waitcnt vmcnt(0)" ::: "memory");
    }
    __builtin_amdgcn_s_barrier();
    const u16* Ac = As[cur];
    const u16* B1c = B1s[cur];
    const u16* B2c = B2s[cur];
    short8 af[2][4], b1f[2][NT], b2f[2][NT];
#pragma unroll
    for (int kk = 0; kk < 2; ++kk) {
#pragma unroll
      for (int m2 = 0; m2 < 4; ++m2)
        af[kk][m2] =
            *(const short8*)&Ac[(wr * 64 + m2 * 16 + ll) * 64 + (((kk * 4 + lg) ^ rx) << 3)];
#pragma unroll
      for (int n2 = 0; n2 < NT; ++n2) {
        int off = (wc * WC + n2 * 16 + ll) * 64 + (((kk * 4 + lg) ^ rx) << 3);
        b1f[kk][n2] = *(const short8*)&B1c[off];
        b2f[kk][n2] = *(const short8*)&B2c[off];
      }
    }
    asm volatile("s_waitcnt lgkmcnt(0)" ::: "memory");
    __builtin_amdgcn_sched_barrier(0);
    __builtin_amdgcn_s_barrier();
    if (i + 2 < ntk) stage(cur, (i + 2) * 64);
    __builtin_amdgcn_s_setprio(1);
#pragma unroll
    for (int kk = 0; kk < 2; ++kk)
#pragma unroll
      for (int m2 = 0; m2 < 4; ++m2)
#pragma unroll
        for (int n2 = 0; n2 < NT; ++n2) {
          acc1[m2][n2] = __builtin_amdgcn_mfma_f32_16x16x32_bf16(af[kk][m2], b1f[kk][n2],
                                                                 acc1[m2][n2], 0, 0, 0);
          acc2[m2][n2] = __builtin_amdgcn_mfma_f32_16x16x32_bf16(af[kk][m2], b2f[kk][n2],
                                                                 acc2[m2][n2], 0, 0, 0);
        }
    __builtin_amdgcn_s_setprio(0);
    cur ^= 1;
  }
#pragma unroll
  for (int n2 = 0; n2 < NT; ++n2) {
    long cg = colTile + wc * WC + n2 * 16 + ll;
    float bv1 = (cg < biasN) ? b1[cg] : 0.f;
    float bv2 = (cg < biasN) ? b2[cg] : 0.f;
#pragma unroll
    for (int m2 = 0; m2 < 4; ++m2) {
#pragma unroll
      for (int r = 0; r < 4; ++r) {
        long rg = rowTile + wr * 64 + m2 * 16 + lg * 4 + r;
        float v1 = acc1[m2][n2][r] + bv1;
        float v2 = acc2[m2][n2][r] + bv2;
        float sg = v1 / (1.f + __expf(-v1));
        outb[rg * ldc + cg] = f2bf(sg * v2);
      }
    }
  }
}

// ---------------- flash attention v4: counted-vmcnt pipeline ---------------
__global__ __launch_bounds__(256, 3) void attn_kernel(
    const u16* __restrict__ qb, int qStride, const u16* __restrict__ kb, int kvStride,
    const u16* __restrict__ vt, u16* __restrict__ outp, int Nk, int Mpb) {
  __shared__ u16 Qs[64 * 64];
  __shared__ u16 Ks[2][64 * 64];
  __shared__ u16 Vs[2][64 * 64];
  __shared__ u16 Ps[4][16 * 64];
  int t = threadIdx.x, w = t >> 6, l = t & 63;
  int h = blockIdx.x, b = blockIdx.y, qt = blockIdx.z;
  int lg = l >> 4, ll = l & 15;
  int rx = ll & 7;

  const u16* Qbase = qb + ((long)(b * NN + qt * 64)) * qStride + h * 64;
  const u16* Kbase = kb + ((long)b * Mpb) * kvStride + h * 64;
  const u16* Vbase = vt + ((long)(b * 16 + h) * 64) * 1024;

  int srow = t >> 3;
  int schunk = t & 7;

#pragma unroll
  for (int sh = 0; sh < 2; ++sh) {
    int row = sh * 32 + srow;
    int ck = schunk ^ (row & 7);
    gload_lds16(Qbase + (long)row * qStride + ck * 8, &Qs[sh * 2048 + t * 8]);
  }
  auto stageKV = [&](int buf, int kt) {
    const u16* kn = Kbase + (long)kt * 64 * kvStride;
    const u16* vn = Vbase + kt * 64;
#pragma unroll
    for (int sh = 0; sh < 2; ++sh) {
      int row = sh * 32 + srow;
      int ck = schunk ^ (row & 7);
      gload_lds16(kn + (long)row * kvStride + ck * 8, &Ks[buf][sh * 2048 + t * 8]);
      gload_lds16(vn + (long)row * 1024 + ck * 8, &Vs[buf][sh * 2048 + t * 8]);
    }
  };
  const int ntk = Nk >> 6;
  stageKV(0, 0);
  if (ntk > 1) stageKV(1, 1);

  short8 qf0, qf1;
  float mrun = -1e30f, ssum = 0.f;
  f32x4 o[4] = {};

  int cur = 0;
  for (int kt = 0; kt < ntk; ++kt) {
    if (kt + 1 < ntk) {
      asm volatile("s_waitcnt vmcnt(4)" ::: "memory");
    } else {
      asm volatile("s_waitcnt vmcnt(0)" ::: "memory");
    }
    __builtin_amdgcn_s_barrier();
    if (kt == 0) {
      qf0 = *(const short8*)&Qs[(w * 16 + ll) * 64 + ((lg ^ rx) << 3)];
      qf1 = *(const short8*)&Qs[(w * 16 + ll) * 64 + (((4 + lg) ^ rx) << 3)];
    }
    const u16* Kc = Ks[cur];
    f32x4 s[4] = {};
#pragma unroll
    for (int n = 0; n < 4; ++n) {
      short8 kf0 = *(const short8*)&Kc[(n * 16 + ll) * 64 + ((lg ^ rx) << 3)];
      short8 kf1 = *(const short8*)&Kc[(n * 16 + ll) * 64 + (((4 + lg) ^ rx) << 3)];
      s[n] = __builtin_amdgcn_mfma_f32_16x16x32_bf16(kf0, qf0, s[n], 0, 0, 0);
      s[n] = __builtin_amdgcn_mfma_f32_16x16x32_bf16(kf1, qf1, s[n], 0, 0, 0);
    }
    float t0 = fmaxf(fmaxf(s[0][0], s[0][1]), fmaxf(s[0][2], s[0][3]));
    float t1 = fmaxf(fmaxf(s[1][0], s[1][1]), fmaxf(s[1][2], s[1][3]));
    float t2 = fmaxf(fmaxf(s[2][0], s[2][1]), fmaxf(s[2][2], s[2][3]));
    float t3 = fmaxf(fmaxf(s[3][0], s[3][1]), fmaxf(s[3][2], s[3][3]));
    float pm = fmaxf(fmaxf(t0, t1), fmaxf(t2, t3));
    pm = fmaxf(pm, __shfl_xor(pm, 16));
    pm = fmaxf(pm, __shfl_xor(pm, 32));
    float nm = fmaxf(mrun, pm);
    float alpha = __expf(mrun - nm);
    float pn[4][4];
#pragma unroll
    for (int n = 0; n < 4; ++n)
#pragma unroll
      for (int r = 0; r < 4; ++r) pn[n][r] = __expf(s[n][r] - nm);
    float r0 = (pn[0][0] + pn[0][1]) + (pn[0][2] + pn[0][3]);
    float r1 = (pn[1][0] + pn[1][1]) + (pn[1][2] + pn[1][3]);
    float r2 = (pn[2][0] + pn[2][1]) + (pn[2][2] + pn[2][3]);
    float r3 = (pn[3][0] + pn[3][1]) + (pn[3][2] + pn[3][3]);
    float rs = (r0 + r1) + (r2 + r3);
    rs += __shfl_xor(rs, 16);
    rs += __shfl_xor(rs, 32);
    ssum = ssum * alpha + rs;
    mrun = nm;
#pragma unroll
    for (int n = 0; n < 4; ++n) {
      uint2 pkd;
      pkd.x = cvtpk_bf16(pn[n][0], pn[n][1]);
      pkd.y = cvtpk_bf16(pn[n][2], pn[n][3]);
      int gran = n * 2 + (lg >> 1);
      int perm = gran ^ rx;
      *(uint2*)&Ps[w][ll * 64 + perm * 8 + (lg & 1) * 4] = pkd;
    }
    float a0 = __shfl(alpha, lg * 4 + 0);
    float a1 = __shfl(alpha, lg * 4 + 1);
    float a2 = __shfl(alpha, lg * 4 + 2);
    float a3 = __shfl(alpha, lg * 4 + 3);
#pragma unroll
    for (int n = 0; n < 4; ++n) {
      o[n][0] *= a0;
      o[n][1] *= a1;
      o[n][2] *= a2;
      o[n][3] *= a3;
    }
    short8 pf0 = *(const short8*)&Ps[w][ll * 64 + ((lg ^ rx) << 3)];
    short8 pf1 = *(const short8*)&Ps[w][ll * 64 + (((4 + lg) ^ rx) << 3)];
    const u16* Vc = Vs[cur];
    short8 vfr[4][2];
#pragma unroll
    for (int n = 0; n < 4; ++n) {
      vfr[n][0] = *(const short8*)&Vc[(n * 16 + ll) * 64 + ((lg ^ rx) << 3)];
      vfr[n][1] = *(const short8*)&Vc[(n * 16 + ll) * 64 + (((4 + lg) ^ rx) << 3)];
    }
    asm volatile("s_waitcnt lgkmcnt(0)" ::: "memory");
    __builtin_amdgcn_sched_barrier(0);
    __builtin_amdgcn_s_barrier();
    if (kt + 2 < ntk) stageKV(cur, kt + 2);
    __builtin_amdgcn_s_setprio(1);
#pragma unroll
    for (int n = 0; n < 4; ++n) {
      o[n] = __builtin_amdgcn_mfma_f32_16x16x32_bf16(pf0, vfr[n][0], o[n], 0, 0, 0);
      o[n] = __builtin_amdgcn_mfma_f32_16x16x32_bf16(pf1, vfr[n][1], o[n], 0, 0, 0);
    }
    __builtin_amdgcn_s_setprio(0);
    cur ^= 1;
  }
  float s0 = __shfl(ssum, lg * 4 + 0);
  float s1 = __shfl(ssum, lg * 4 + 1);
  float s2 = __shfl(ssum, lg * 4 + 2);
  float s3 = __shfl(ssum, lg * 4 + 3);
  float i0 = 1.f / s0, i1 = 1.f / s1, i2 = 1.f / s2, i3 = 1.f / s3;
#pragma unroll
  for (int n = 0; n < 4; ++n) {
    float ir[4] = {i0, i1, i2, i3};
#pragma unroll
    for (int r = 0; r < 4; ++r) {
      long row = (long)b * NN + qt * 64 + w * 16 + lg * 4 + r;
      int col = h * 64 + n * 16 + ll;
      outp[row * DD + col] = f2bf(o[n][r] * ir[r]);
    }
  }
}

extern "C" void kernel_launch(void* const* d_in, const int* in_sizes, int n_in,
                              void* d_out, int out_size, void* d_ws, size_t ws_size,
                              hipStream_t stream) {
  const float* x = (const float*)d_in[0];
  const float* src = (const float*)d_in[1];
  const float* c = (const float*)d_in[2];
  const float* ada_w = (const float*)d_in[3];
  const float* ada_b = (const float*)d_in[4];
  const float* n1_w = (const float*)d_in[5];
  const float* nc_w = (const float*)d_in[6];
  const float* n2_w = (const float*)d_in[7];
  const float* sa_qkv_w = (const float*)d_in[8];
  const float* sa_qkv_b = (const float*)d_in[9];
  const float* sa_qn_w = (const float*)d_in[10];
  const float* sa_kn_w = (const float*)d_in[11];
  const float* sa_o_w = (const float*)d_in[12];
  const float* sa_o_b = (const float*)d_in[13];
  const float* ca_q_w = (const float*)d_in[14];
  const float* ca_q_b = (const float*)d_in[15];
  const float* ca_kv_w = (const float*)d_in[16];
  const float* ca_kv_b = (const float*)d_in[17];
  const float* ca_qn_w = (const float*)d_in[18];
  const float* ca_kn_w = (const float*)d_in[19];
  const float* ca_o_w = (const float*)d_in[20];
  const float* ca_o_b = (const float*)d_in[21];
  const float* mlp_w1 = (const float*)d_in[22];
  const float* mlp_b1 = (const float*)d_in[23];
  const float* mlp_w2 = (const float*)d_in[24];
  const float* mlp_b2 = (const float*)d_in[25];
  const float* mlp_w3 = (const float*)d_in[26];
  const float* mlp_b3 = (const float*)d_in[27];
  float* out = (float*)d_out;

  char* p = (char*)d_ws;
  auto alloc = [&](size_t bytes) {
    char* r = p;
    p += (bytes + 255) & ~(size_t)255;
    return r;
  };
  float* mods = (float*)alloc(4l * 9216 * 4);
  float* sc = (float*)alloc(4096l * 4);
  float* part = (float*)alloc((long)MODS_KS * 4 * 9216 * 4);
  u16* qkvT = (u16*)alloc(3072l * 1024 * 2);
  u16* saoT = (u16*)alloc(1024l * 1024 * 2);
  u16* caqT = (u16*)alloc(1024l * 1024 * 2);
  u16* cakvT = (u16*)alloc(2048l * 1024 * 2);
  u16* caoT = (u16*)alloc(1024l * 1024 * 2);
  u16* w1T = (u16*)alloc(2816l * 1024 * 2);
  u16* w2T = (u16*)alloc(2816l * 1024 * 2);
  u16* w3T = (u16*)alloc(1024l * 2816 * 2);
  u16* xnb = (u16*)alloc(4096l * 1024 * 2);
  u16* srcb = (u16*)alloc(4096l * 1024 * 2);
  u16* bufA = (u16*)alloc(4096l * 3072 * 2);
  u16* bufB = (u16*)alloc(4096l * 2816 * 2);
  u16* attO = (u16*)alloc(4096l * 1024 * 2);
  u16* vtb = xnb;  // alias: xnb dead during attention

  dim3 tb(32, 8);
  transpose_convert<<<dim3(32, 96), tb, 0, stream>>>(sa_qkv_w, qkvT, 1024, 3072, 1024, 3072);
  transpose_convert<<<dim3(32, 32), tb, 0, stream>>>(sa_o_w, saoT, 1024, 1024, 1024, 1024);
  transpose_convert<<<dim3(32, 32), tb, 0, stream>>>(ca_q_w, caqT, 1024, 1024, 1024, 1024);
  transpose_convert<<<dim3(32, 64), tb, 0, stream>>>(ca_kv_w, cakvT, 1024, 2048, 1024, 2048);
  transpose_convert<<<dim3(32, 32), tb, 0, stream>>>(ca_o_w, caoT, 1024, 1024, 1024, 1024);
  transpose_convert<<<dim3(32, 88), tb, 0, stream>>>(mlp_w1, w1T, 1024, 2730, 1024, 2816);
  transpose_convert<<<dim3(32, 88), tb, 0, stream>>>(mlp_w2, w2T, 1024, 2730, 1024, 2816);
  transpose_convert<<<dim3(88, 32), tb, 0, stream>>>(mlp_w3, w3T, 2730, 1024, 2816, 1024);
  cvt_bf16_kernel<<<4096, 256, 0, stream>>>(src, srcb, 4096l * 1024 / 4);
  silu_kernel<<<16, 256, 0, stream>>>(c, sc);
  mods_partial<<<dim3(36, MODS_KS), 256, 0, stream>>>(sc, ada_w, part);
  mods_reduce<<<dim3(36, 4), 256, 0, stream>>>(part, ada_b, mods);

  // ---- self-attention sublayer
  rmsmod_kernel<<<4096, 256, 0, stream>>>(x, n1_w, mods, 0, 1024, xnb);
  gemm_bf16<0, 128, 2><<<768, 256, 0, stream>>>(xnb, qkvT, 1024, 3072, sa_qkv_b, 3072, bufA,
                                                nullptr, nullptr, nullptr, 0, 24);
  qknorm2_kernel<<<dim3(4096, 2), 256, 0, stream>>>(bufA, 3072, sa_qn_w, bufA + 1024, 3072,
                                                    sa_kn_w);
  vtrans_kernel<<<dim3(16, 16, 4), 256, 0, stream>>>(bufA + 2048, 3072, 1024, vtb);
  attn_kernel<<<dim3(16, 4, 16), 256, 0, stream>>>(bufA, 3072, bufA + 1024, 3072, vtb, attO,
                                                   1024, 1024);
  gemm_bf16<1, 64, 3><<<512, 256, 0, stream>>>(attO, saoT, 1024, 1024, sa_o_b, 1024, nullptr,
                                               out, x, mods, 2048, 16);

  // ---- cross-attention sublayer
  rmsmod_kernel<<<4096, 256, 0, stream>>>(out, nc_w, mods, 3072, 4096, xnb);
  gemm_bf16<0, 64, 3><<<512, 256, 0, stream>>>(xnb, caqT, 1024, 1024, ca_q_b, 1024, bufA,
                                               nullptr, nullptr, nullptr, 0, 16);
  gemm_bf16<0, 128, 2><<<512, 256, 0, stream>>>(srcb, cakvT, 1024, 2048, ca_kv_b, 2048, bufB,
                                                nullptr, nullptr, nullptr, 0, 16);
  qknorm2_kernel<<<dim3(4096, 2), 256, 0, stream>>>(bufA, 1024, ca_qn_w, bufB, 2048, ca_kn_w);
  vtrans_kernel<<<dim3(16, 16, 4), 256, 0, stream>>>(bufB + 1024, 2048, 1024, vtb);
  attn_kernel<<<dim3(16, 4, 16), 256, 0, stream>>>(bufA, 1024, bufB, 2048, vtb, attO, 1024,
                                                   1024);
  gemm_bf16<1, 64, 3><<<512, 256, 0, stream>>>(attO, caoT, 1024, 1024, ca_o_b, 1024, nullptr,
                                               out, out, mods, 5120, 16);

  // ---- SwiGLU FFN sublayer: fused dual GEMM, h1 never materialized
  rmsmod_kernel<<<4096, 256, 0, stream>>>(out, n2_w, mods, 6144, 7168, xnb);
  gemm_dual_swiglu<<<1408, 256, 0, stream>>>(xnb, w1T, w2T, 1024, 2816, mlp_b1, mlp_b2, 2730,
                                             bufA, 44);
  gemm_bf16<1, 64, 3><<<512, 256, 0, stream>>>(bufA, w3T, 2816, 1024, mlp_b3, 1024, nullptr,
                                               out, out, mods, 8192, 16);
}

// Round 11
// 372.249 us; speedup vs baseline: 1.4645x; 1.0330x over previous
//
#include <hip/hip_runtime.h>

typedef unsigned short u16;
typedef __attribute__((ext_vector_type(8))) short short8;
typedef __attribute__((ext_vector_type(4))) float f32x4;

#define DD 1024
#define NN 1024
#define MODS_LD 9216

__device__ __forceinline__ float bf2f(u16 v) {
  unsigned int u = ((unsigned int)v) << 16;
  return __builtin_bit_cast(float, u);
}
__device__ __forceinline__ u16 f2bf(float f) {
  unsigned int u = __builtin_bit_cast(unsigned int, f);
  unsigned int lsb = (u >> 16) & 1;
  u += 0x7fffu + lsb;
  return (u16)(u >> 16);
}
__device__ __forceinline__ unsigned cvtpk_bf16(float a, float b) {
  unsigned r;
  asm volatile("v_cvt_pk_bf16_f32 %0, %1, %2" : "=v"(r) : "v"(a), "v"(b));
  return r;
}

__device__ __forceinline__ void gload_lds16(const u16* g, u16* l) {
  __builtin_amdgcn_global_load_lds(
      (const __attribute__((address_space(1))) unsigned int*)g,
      (__attribute__((address_space(3))) unsigned int*)l, 16, 0, 0);
}

// XCD super-tile mapping: grid = 8*cr*cc blocks; XCD c gets a cr x cc tile rect.
__device__ __forceinline__ void xcd_tile(int ncolChunks, int cr, int cc, int& tm, int& tn) {
  int id = blockIdx.x;
  int c = id & 7, i = id >> 3;
  int chunkRow = c / ncolChunks, chunkCol = c % ncolChunks;
  tm = chunkRow * cr + (i % cr);
  tn = chunkCol * cc + (i / cr);
}

// ---------------- weight transpose + fp32->bf16 -------------------------
__global__ void transpose_convert(const float* __restrict__ src, u16* __restrict__ dst,
                                  int R, int C, int R2, int C2) {
  __shared__ float tile[32][33];
  int tx = threadIdx.x, ty = threadIdx.y;
  int r0 = blockIdx.x * 32, c0 = blockIdx.y * 32;
#pragma unroll
  for (int i = 0; i < 4; ++i) {
    int r = r0 + ty + i * 8, c = c0 + tx;
    tile[ty + i * 8][tx] = (r < R && c < C) ? src[(long)r * C + c] : 0.f;
  }
  __syncthreads();
#pragma unroll
  for (int i = 0; i < 4; ++i) {
    int c = c0 + ty + i * 8, r = r0 + tx;
    if (c < C2 && r < R2) dst[(long)c * R2 + r] = f2bf(tile[tx][ty + i * 8]);
  }
}

// ---------------- fp32 -> bf16 (vector) ---------------------------------
__global__ void cvt_bf16_kernel(const float* __restrict__ in, u16* __restrict__ out, long n4) {
  long i = (long)blockIdx.x * 256 + threadIdx.x;
  if (i >= n4) return;
  float4 v = *(const float4*)&in[i * 4];
  ushort4 pk = {f2bf(v.x), f2bf(v.y), f2bf(v.z), f2bf(v.w)};
  *(ushort4*)&out[i * 4] = pk;
}

// ---------------- silu(c) + mods matvec (k-split, deterministic) ----------
__global__ void silu_kernel(const float* __restrict__ c, float* __restrict__ sc) {
  int i = blockIdx.x * 256 + threadIdx.x;
  float v = c[i];
  sc[i] = v / (1.f + __expf(-v));
}

#define MODS_KS 32
__global__ __launch_bounds__(256) void mods_partial(const float* __restrict__ sc,
                                                    const float* __restrict__ aw,
                                                    float* __restrict__ part) {
  int j = blockIdx.x * 256 + threadIdx.x;
  int ks = blockIdx.y;
  int d0 = ks * (DD / MODS_KS);
  float a0 = 0.f, a1 = 0.f, a2 = 0.f, a3 = 0.f;
#pragma unroll 8
  for (int d = d0; d < d0 + DD / MODS_KS; ++d) {
    float w = aw[(long)d * MODS_LD + j];
    a0 = fmaf(sc[d], w, a0);
    a1 = fmaf(sc[DD + d], w, a1);
    a2 = fmaf(sc[2 * DD + d], w, a2);
    a3 = fmaf(sc[3 * DD + d], w, a3);
  }
  long base = (long)ks * 4 * MODS_LD + j;
  part[base] = a0;
  part[base + MODS_LD] = a1;
  part[base + 2 * MODS_LD] = a2;
  part[base + 3 * MODS_LD] = a3;
}

__global__ __launch_bounds__(256) void mods_reduce(const float* __restrict__ part,
                                                   const float* __restrict__ ab,
                                                   float* __restrict__ mods) {
  int j = blockIdx.x * 256 + threadIdx.x;
  int b = blockIdx.y;
  float acc = ab[j];
#pragma unroll
  for (int ks = 0; ks < MODS_KS; ++ks) acc += part[((long)ks * 4 + b) * MODS_LD + j];
  mods[(long)b * MODS_LD + j] = acc;
}

// ---------------- fused RMSNorm + modulate -> bf16 ------------------------
__global__ __launch_bounds__(256) void rmsmod_kernel(const float* __restrict__ x,
                                                     const float* __restrict__ w,
                                                     const float* __restrict__ mods,
                                                     int shiftOff, int scaleOff,
                                                     u16* __restrict__ out) {
  long row = blockIdx.x;
  int b = (int)(row >> 10);
  int t = threadIdx.x;
  const float* xr = x + row * DD;
  float4 v = *(const float4*)&xr[t * 4];
  float ss = v.x * v.x + v.y * v.y + v.z * v.z + v.w * v.w;
#pragma unroll
  for (int msk = 1; msk < 64; msk <<= 1) ss += __shfl_xor(ss, msk);
  __shared__ float red[4];
  if ((t & 63) == 0) red[t >> 6] = ss;
  __syncthreads();
  float tot = red[0] + red[1] + red[2] + red[3];
  float inv = rsqrtf(tot * (1.f / DD) + 1e-6f);
  const float* mrow = mods + (long)b * MODS_LD;
  float vv[4] = {v.x, v.y, v.z, v.w};
  u16 tmp[4];
#pragma unroll
  for (int j = 0; j < 4; ++j) {
    int c = t * 4 + j;
    float rr = vv[j] * inv * w[c] * (1.f + mrow[scaleOff + c]) + mrow[shiftOff + c];
    tmp[j] = f2bf(rr);
  }
  ushort4 pk = {tmp[0], tmp[1], tmp[2], tmp[3]};
  *(ushort4*)&out[row * DD + t * 4] = pk;
}

// ---------------- V pre-transpose: v[b, kv, (h,d)] -> vt[(b,h), d, kv] -----
__global__ void vtrans_kernel(const u16* __restrict__ vb, int kvStride, int Mpb,
                              u16* __restrict__ vt) {
  __shared__ u16 tile[64][66];
  int t = threadIdx.x;
  int kt = blockIdx.x, h = blockIdx.y, b = blockIdx.z;
  const u16* base = vb + ((long)(b * Mpb + kt * 64)) * kvStride + h * 64;
#pragma unroll
  for (int sh = 0; sh < 2; ++sh) {
    int r = sh * 32 + (t >> 3);
    int c0 = (t & 7) * 8;
    short8 vv = *(const short8*)(base + (long)r * kvStride + c0);
#pragma unroll
    for (int j = 0; j < 8; ++j) tile[c0 + j][r] = (u16)vv[j];
  }
  __syncthreads();
  u16* obase = vt + ((long)(b * 16 + h) * 64) * 1024 + kt * 64;
#pragma unroll
  for (int sh = 0; sh < 2; ++sh) {
    int d = sh * 32 + (t >> 3);
    int c0 = (t & 7) * 8;
    u16 tmp[8];
#pragma unroll
    for (int j = 0; j < 8; ++j) tmp[j] = tile[d][c0 + j];
    *(short8*)(obase + (long)d * 1024 + c0) = *(short8*)tmp;
  }
}

// ---------------- GEMM: 128 x BN tiles, counted-vmcnt + T2 swizzle --------
// MODE 0: outb = bf16(acc+bias)
// MODE 1: outf = xin + gate*(acc+bias)
// NORM 1 (BN=128 only): tiles tn in [normLo,normHi) get per-64-head RMS-norm
//   out = bf16((acc+bias) * rsqrt(mean sq) * nscale * nw[p])
template <int MODE, int BN, int MINW, int NORM>
__global__ __launch_bounds__(256, MINW) void gemm_bf16(
    const u16* __restrict__ A, const u16* __restrict__ Bt, int K, int ldc,
    const float* __restrict__ bias, int biasN, u16* __restrict__ outb,
    float* __restrict__ outf, const float* __restrict__ xin,
    const float* __restrict__ mods, int gateOff, int ncolChunks, int cr, int cc,
    const float* __restrict__ nw, int normLo, int normHi, float nscale) {
  constexpr int WC = BN / 2;
  constexpr int NT = WC / 16;
  constexpr int LOADS = 4 + BN / 32;
  __shared__ u16 As[2][128 * 64];
  __shared__ u16 Bs[2][BN * 64];
  int t = threadIdx.x;
  int l = t & 63, w = t >> 6;
  int wr = w >> 1, wc = w & 1;
  int lg = l >> 4, ll = l & 15;
  int rx = ll & 7;
  int tm, tn;
  xcd_tile(ncolChunks, cr, cc, tm, tn);
  long rowTile = (long)tm * 128;
  long colTile = (long)tn * BN;
  const u16* Ap = A + rowTile * K;
  const u16* Bp = Bt + colTile * K;
  int srow = t >> 3;
  int sck = ((t & 7) ^ (srow & 7)) * 8;

  auto stage = [&](int buf, int k0) {
#pragma unroll
    for (int i = 0; i < 4; ++i)
      gload_lds16(Ap + (long)(i * 32 + srow) * K + k0 + sck, &As[buf][(i * 256 + t) * 8]);
#pragma unroll
    for (int i = 0; i < BN / 32; ++i)
      gload_lds16(Bp + (long)(i * 32 + srow) * K + k0 + sck, &Bs[buf][(i * 256 + t) * 8]);
  };

  const int ntk = K >> 6;
  stage(0, 0);
  if (ntk > 1) stage(1, 64);

  f32x4 acc[4][NT] = {};
  int cur = 0;
  for (int i = 0; i < ntk; ++i) {
    if (i + 1 < ntk) {
      asm volatile("s_waitcnt vmcnt(%0)" ::"i"(LOADS) : "memory");
    } else {
      asm volatile("s_waitcnt vmcnt(0)" ::: "memory");
    }
    __builtin_amdgcn_s_barrier();
    const u16* Ac = As[cur];
    const u16* Bc = Bs[cur];
    short8 af[2][4], bfr[2][NT];
#pragma unroll
    for (int kk = 0; kk < 2; ++kk) {
#pragma unroll
      for (int m2 = 0; m2 < 4; ++m2)
        af[kk][m2] =
            *(const short8*)&Ac[(wr * 64 + m2 * 16 + ll) * 64 + (((kk * 4 + lg) ^ rx) << 3)];
#pragma unroll
      for (int n2 = 0; n2 < NT; ++n2)
        bfr[kk][n2] =
            *(const short8*)&Bc[(wc * WC + n2 * 16 + ll) * 64 + (((kk * 4 + lg) ^ rx) << 3)];
    }
    asm volatile("s_waitcnt lgkmcnt(0)" ::: "memory");
    __builtin_amdgcn_sched_barrier(0);
    __builtin_amdgcn_s_barrier();
    if (i + 2 < ntk) stage(cur, (i + 2) * 64);
    __builtin_amdgcn_s_setprio(1);
#pragma unroll
    for (int kk = 0; kk < 2; ++kk)
#pragma unroll
      for (int m2 = 0; m2 < 4; ++m2)
#pragma unroll
        for (int n2 = 0; n2 < NT; ++n2)
          acc[m2][n2] = __builtin_amdgcn_mfma_f32_16x16x32_bf16(af[kk][m2], bfr[kk][n2],
                                                                acc[m2][n2], 0, 0, 0);
    __builtin_amdgcn_s_setprio(0);
    cur ^= 1;
  }

  if (NORM == 1 && tn >= normLo && tn < normHi) {
    // per-64-col head RMS-norm (BN=128: wave wc owns one full head)
    float bv[NT], wnv[NT];
#pragma unroll
    for (int n2 = 0; n2 < NT; ++n2) {
      long cg = colTile + wc * WC + n2 * 16 + ll;
      bv[n2] = bias[cg];
      wnv[n2] = nw[n2 * 16 + ll];
    }
#pragma unroll
    for (int m2 = 0; m2 < 4; ++m2) {
#pragma unroll
      for (int r = 0; r < 4; ++r) {
        float vals[NT];
        float ss = 0.f;
#pragma unroll
        for (int n2 = 0; n2 < NT; ++n2) {
          vals[n2] = acc[m2][n2][r] + bv[n2];
          ss += vals[n2] * vals[n2];
        }
        ss += __shfl_xor(ss, 1);
        ss += __shfl_xor(ss, 2);
        ss += __shfl_xor(ss, 4);
        ss += __shfl_xor(ss, 8);
        float inv = rsqrtf(ss * (1.f / 64) + 1e-6f) * nscale;
        long rg = rowTile + wr * 64 + m2 * 16 + lg * 4 + r;
#pragma unroll
        for (int n2 = 0; n2 < NT; ++n2) {
          long cg = colTile + wc * WC + n2 * 16 + ll;
          outb[rg * ldc + cg] = f2bf(vals[n2] * inv * wnv[n2]);
        }
      }
    }
    return;
  }

#pragma unroll
  for (int n2 = 0; n2 < NT; ++n2) {
    long cg = colTile + wc * WC + n2 * 16 + ll;
    float bv = (cg < biasN) ? bias[cg] : 0.f;
#pragma unroll
    for (int m2 = 0; m2 < 4; ++m2) {
#pragma unroll
      for (int r = 0; r < 4; ++r) {
        long rg = rowTile + wr * 64 + m2 * 16 + lg * 4 + r;
        float v = acc[m2][n2][r] + bv;
        long idx = rg * ldc + cg;
        if (MODE == 0) {
          outb[idx] = f2bf(v);
        } else {
          int bb = (int)(rg >> 10);
          outf[idx] = xin[idx] + mods[(long)bb * MODS_LD + gateOff + cg] * v;
        }
      }
    }
  }
}

// ---------------- dual GEMM + swiglu: h = silu(A@B1+b1)*(A@B2+b2) ---------
__global__ __launch_bounds__(256, 2) void gemm_dual_swiglu(
    const u16* __restrict__ A, const u16* __restrict__ B1t, const u16* __restrict__ B2t,
    int K, int ldc, const float* __restrict__ b1, const float* __restrict__ b2, int biasN,
    u16* __restrict__ outb, int ncolChunks, int cr, int cc) {
  constexpr int BN = 64, WC = 32, NT = 2;
  __shared__ u16 As[2][128 * 64];
  __shared__ u16 B1s[2][BN * 64];
  __shared__ u16 B2s[2][BN * 64];
  int t = threadIdx.x;
  int l = t & 63, w = t >> 6;
  int wr = w >> 1, wc = w & 1;
  int lg = l >> 4, ll = l & 15;
  int rx = ll & 7;
  int tm, tn;
  xcd_tile(ncolChunks, cr, cc, tm, tn);
  long rowTile = (long)tm * 128;
  long colTile = (long)tn * BN;
  const u16* Ap = A + rowTile * K;
  const u16* B1p = B1t + colTile * K;
  const u16* B2p = B2t + colTile * K;
  int srow = t >> 3;
  int sck = ((t & 7) ^ (srow & 7)) * 8;

  auto stage = [&](int buf, int k0) {
#pragma unroll
    for (int i = 0; i < 4; ++i)
      gload_lds16(Ap + (long)(i * 32 + srow) * K + k0 + sck, &As[buf][(i * 256 + t) * 8]);
#pragma unroll
    for (int i = 0; i < 2; ++i) {
      gload_lds16(B1p + (long)(i * 32 + srow) * K + k0 + sck, &B1s[buf][(i * 256 + t) * 8]);
      gload_lds16(B2p + (long)(i * 32 + srow) * K + k0 + sck, &B2s[buf][(i * 256 + t) * 8]);
    }
  };

  const int ntk = K >> 6;
  stage(0, 0);
  if (ntk > 1) stage(1, 64);

  f32x4 acc1[4][NT] = {}, acc2[4][NT] = {};
  int cur = 0;
  for (int i = 0; i < ntk; ++i) {
    if (i + 1 < ntk) {
      asm volatile("s_waitcnt vmcnt(8)" ::: "memory");
    } else {
      asm volatile("s_waitcnt vmcnt(0)" ::: "memory");
    }
    __builtin_amdgcn_s_barrier();
    const u16* Ac = As[cur];
    const u16* B1c = B1s[cur];
    const u16* B2c = B2s[cur];
    short8 af[2][4], b1f[2][NT], b2f[2][NT];
#pragma unroll
    for (int kk = 0; kk < 2; ++kk) {
#pragma unroll
      for (int m2 = 0; m2 < 4; ++m2)
        af[kk][m2] =
            *(const short8*)&Ac[(wr * 64 + m2 * 16 + ll) * 64 + (((kk * 4 + lg) ^ rx) << 3)];
#pragma unroll
      for (int n2 = 0; n2 < NT; ++n2) {
        int off = (wc * WC + n2 * 16 + ll) * 64 + (((kk * 4 + lg) ^ rx) << 3);
        b1f[kk][n2] = *(const short8*)&B1c[off];
        b2f[kk][n2] = *(const short8*)&B2c[off];
      }
    }
    asm volatile("s_waitcnt lgkmcnt(0)" ::: "memory");
    __builtin_amdgcn_sched_barrier(0);
    __builtin_amdgcn_s_barrier();
    if (i + 2 < ntk) stage(cur, (i + 2) * 64);
    __builtin_amdgcn_s_setprio(1);
#pragma unroll
    for (int kk = 0; kk < 2; ++kk)
#pragma unroll
      for (int m2 = 0; m2 < 4; ++m2)
#pragma unroll
        for (int n2 = 0; n2 < NT; ++n2) {
          acc1[m2][n2] = __builtin_amdgcn_mfma_f32_16x16x32_bf16(af[kk][m2], b1f[kk][n2],
                                                                 acc1[m2][n2], 0, 0, 0);
          acc2[m2][n2] = __builtin_amdgcn_mfma_f32_16x16x32_bf16(af[kk][m2], b2f[kk][n2],
                                                                 acc2[m2][n2], 0, 0, 0);
        }
    __builtin_amdgcn_s_setprio(0);
    cur ^= 1;
  }
#pragma unroll
  for (int n2 = 0; n2 < NT; ++n2) {
    long cg = colTile + wc * WC + n2 * 16 + ll;
    float bv1 = (cg < biasN) ? b1[cg] : 0.f;
    float bv2 = (cg < biasN) ? b2[cg] : 0.f;
#pragma unroll
    for (int m2 = 0; m2 < 4; ++m2) {
#pragma unroll
      for (int r = 0; r < 4; ++r) {
        long rg = rowTile + wr * 64 + m2 * 16 + lg * 4 + r;
        float v1 = acc1[m2][n2][r] + bv1;
        float v2 = acc2[m2][n2][r] + bv2;
        float sg = v1 / (1.f + __expf(-v1));
        outb[rg * ldc + cg] = f2bf(sg * v2);
      }
    }
  }
}

// ---------------- flash attention v5: Q-norm prologue, counted-vmcnt ------
__global__ __launch_bounds__(256, 3) void attn_kernel(
    const u16* __restrict__ qb, int qStride, const u16* __restrict__ kb, int kvStride,
    const u16* __restrict__ vt, const float* __restrict__ qn, u16* __restrict__ outp,
    int Nk, int Mpb) {
  __shared__ u16 Qs[64 * 64];
  __shared__ u16 Ks[2][64 * 64];
  __shared__ u16 Vs[2][64 * 64];
  __shared__ u16 Ps[4][16 * 64];
  int t = threadIdx.x, w = t >> 6, l = t & 63;
  int h = blockIdx.x, b = blockIdx.y, qt = blockIdx.z;
  int lg = l >> 4, ll = l & 15;
  int rx = ll & 7;

  const u16* Qbase = qb + ((long)(b * NN + qt * 64)) * qStride + h * 64;
  const u16* Kbase = kb + ((long)b * Mpb) * kvStride + h * 64;
  const u16* Vbase = vt + ((long)(b * 16 + h) * 64) * 1024;

  int srow = t >> 3;
  int schunk = t & 7;

#pragma unroll
  for (int sh = 0; sh < 2; ++sh) {
    int row = sh * 32 + srow;
    int ck = schunk ^ (row & 7);
    gload_lds16(Qbase + (long)row * qStride + ck * 8, &Qs[sh * 2048 + t * 8]);
  }
  auto stageKV = [&](int buf, int kt) {
    const u16* kn = Kbase + (long)kt * 64 * kvStride;
    const u16* vn = Vbase + kt * 64;
#pragma unroll
    for (int sh = 0; sh < 2; ++sh) {
      int row = sh * 32 + srow;
      int ck = schunk ^ (row & 7);
      gload_lds16(kn + (long)row * kvStride + ck * 8, &Ks[buf][sh * 2048 + t * 8]);
      gload_lds16(vn + (long)row * 1024 + ck * 8, &Vs[buf][sh * 2048 + t * 8]);
    }
  };
  const int ntk = Nk >> 6;
  stageKV(0, 0);
  if (ntk > 1) stageKV(1, 1);

  short8 qf0, qf1;
  float mrun = -1e30f, ssum = 0.f;
  f32x4 o[4] = {};

  int cur = 0;
  for (int kt = 0; kt < ntk; ++kt) {
    if (kt + 1 < ntk) {
      asm volatile("s_waitcnt vmcnt(4)" ::: "memory");
    } else {
      asm volatile("s_waitcnt vmcnt(0)" ::: "memory");
    }
    __builtin_amdgcn_s_barrier();
    if (kt == 0) {
      qf0 = *(const short8*)&Qs[(w * 16 + ll) * 64 + ((lg ^ rx) << 3)];
      qf1 = *(const short8*)&Qs[(w * 16 + ll) * 64 + (((4 + lg) ^ rx) << 3)];
      // fused q RMS-norm: 4 lanes (lg=0..3, same ll) co-own row w*16+ll
      float qv0[8], qv1[8], ss = 0.f;
#pragma unroll
      for (int j = 0; j < 8; ++j) {
        qv0[j] = bf2f((u16)qf0[j]);
        qv1[j] = bf2f((u16)qf1[j]);
        ss += qv0[j] * qv0[j] + qv1[j] * qv1[j];
      }
      ss += __shfl_xor(ss, 16);
      ss += __shfl_xor(ss, 32);
      float inv = rsqrtf(ss * (1.f / 64) + 1e-6f) * 0.125f;
      int d0 = (lg ^ rx) << 3, d1 = ((4 + lg) ^ rx) << 3;
      u16 t0[8], t1[8];
#pragma unroll
      for (int j = 0; j < 8; ++j) {
        t0[j] = f2bf(qv0[j] * inv * qn[d0 + j]);
        t1[j] = f2bf(qv1[j] * inv * qn[d1 + j]);
      }
      qf0 = *(short8*)t0;
      qf1 = *(short8*)t1;
    }
    const u16* Kc = Ks[cur];
    f32x4 s[4] = {};
#pragma unroll
    for (int n = 0; n < 4; ++n) {
      short8 kf0 = *(const short8*)&Kc[(n * 16 + ll) * 64 + ((lg ^ rx) << 3)];
      short8 kf1 = *(const short8*)&Kc[(n * 16 + ll) * 64 + (((4 + lg) ^ rx) << 3)];
      s[n] = __builtin_amdgcn_mfma_f32_16x16x32_bf16(kf0, qf0, s[n], 0, 0, 0);
      s[n] = __builtin_amdgcn_mfma_f32_16x16x32_bf16(kf1, qf1, s[n], 0, 0, 0);
    }
    float t0 = fmaxf(fmaxf(s[0][0], s[0][1]), fmaxf(s[0][2], s[0][3]));
    float t1 = fmaxf(fmaxf(s[1][0], s[1][1]), fmaxf(s[1][2], s[1][3]));
    float t2 = fmaxf(fmaxf(s[2][0], s[2][1]), fmaxf(s[2][2], s[2][3]));
    float t3 = fmaxf(fmaxf(s[3][0], s[3][1]), fmaxf(s[3][2], s[3][3]));
    float pm = fmaxf(fmaxf(t0, t1), fmaxf(t2, t3));
    pm = fmaxf(pm, __shfl_xor(pm, 16));
    pm = fmaxf(pm, __shfl_xor(pm, 32));
    float nm = fmaxf(mrun, pm);
    float alpha = __expf(mrun - nm);
    float pn[4][4];
#pragma unroll
    for (int n = 0; n < 4; ++n)
#pragma unroll
      for (int r = 0; r < 4; ++r) pn[n][r] = __expf(s[n][r] - nm);
    float r0 = (pn[0][0] + pn[0][1]) + (pn[0][2] + pn[0][3]);
    float r1 = (pn[1][0] + pn[1][1]) + (pn[1][2] + pn[1][3]);
    float r2 = (pn[2][0] + pn[2][1]) + (pn[2][2] + pn[2][3]);
    float r3 = (pn[3][0] + pn[3][1]) + (pn[3][2] + pn[3][3]);
    float rs = (r0 + r1) + (r2 + r3);
    rs += __shfl_xor(rs, 16);
    rs += __shfl_xor(rs, 32);
    ssum = ssum * alpha + rs;
    mrun = nm;
#pragma unroll
    for (int n = 0; n < 4; ++n) {
      uint2 pkd;
      pkd.x = cvtpk_bf16(pn[n][0], pn[n][1]);
      pkd.y = cvtpk_bf16(pn[n][2], pn[n][3]);
      int gran = n * 2 + (lg >> 1);
      int perm = gran ^ rx;
      *(uint2*)&Ps[w][ll * 64 + perm * 8 + (lg & 1) * 4] = pkd;
    }
    float a0 = __shfl(alpha, lg * 4 + 0);
    float a1 = __shfl(alpha, lg * 4 + 1);
    float a2 = __shfl(alpha, lg * 4 + 2);
    float a3 = __shfl(alpha, lg * 4 + 3);
#pragma unroll
    for (int n = 0; n < 4; ++n) {
      o[n][0] *= a0;
      o[n][1] *= a1;
      o[n][2] *= a2;
      o[n][3] *= a3;
    }
    short8 pf0 = *(const short8*)&Ps[w][ll * 64 + ((lg ^ rx) << 3)];
    short8 pf1 = *(const short8*)&Ps[w][ll * 64 + (((4 + lg) ^ rx) << 3)];
    const u16* Vc = Vs[cur];
    short8 vfr[4][2];
#pragma unroll
    for (int n = 0; n < 4; ++n) {
      vfr[n][0] = *(const short8*)&Vc[(n * 16 + ll) * 64 + ((lg ^ rx) << 3)];
      vfr[n][1] = *(const short8*)&Vc[(n * 16 + ll) * 64 + (((4 + lg) ^ rx) << 3)];
    }
    asm volatile("s_waitcnt lgkmcnt(0)" ::: "memory");
    __builtin_amdgcn_sched_barrier(0);
    __builtin_amdgcn_s_barrier();
    if (kt + 2 < ntk) stageKV(cur, kt + 2);
    __builtin_amdgcn_s_setprio(1);
#pragma unroll
    for (int n = 0; n < 4; ++n) {
      o[n] = __builtin_amdgcn_mfma_f32_16x16x32_bf16(pf0, vfr[n][0], o[n], 0, 0, 0);
      o[n] = __builtin_amdgcn_mfma_f32_16x16x32_bf16(pf1, vfr[n][1], o[n], 0, 0, 0);
    }
    __builtin_amdgcn_s_setprio(0);
    cur ^= 1;
  }
  float s0 = __shfl(ssum, lg * 4 + 0);
  float s1 = __shfl(ssum, lg * 4 + 1);
  float s2 = __shfl(ssum, lg * 4 + 2);
  float s3 = __shfl(ssum, lg * 4 + 3);
  float i0 = 1.f / s0, i1 = 1.f / s1, i2 = 1.f / s2, i3 = 1.f / s3;
#pragma unroll
  for (int n = 0; n < 4; ++n) {
    float ir[4] = {i0, i1, i2, i3};
#pragma unroll
    for (int r = 0; r < 4; ++r) {
      long row = (long)b * NN + qt * 64 + w * 16 + lg * 4 + r;
      int col = h * 64 + n * 16 + ll;
      outp[row * DD + col] = f2bf(o[n][r] * ir[r]);
    }
  }
}

extern "C" void kernel_launch(void* const* d_in, const int* in_sizes, int n_in,
                              void* d_out, int out_size, void* d_ws, size_t ws_size,
                              hipStream_t stream) {
  const float* x = (const float*)d_in[0];
  const float* src = (const float*)d_in[1];
  const float* c = (const float*)d_in[2];
  const float* ada_w = (const float*)d_in[3];
  const float* ada_b = (const float*)d_in[4];
  const float* n1_w = (const float*)d_in[5];
  const float* nc_w = (const float*)d_in[6];
  const float* n2_w = (const float*)d_in[7];
  const float* sa_qkv_w = (const float*)d_in[8];
  const float* sa_qkv_b = (const float*)d_in[9];
  const float* sa_qn_w = (const float*)d_in[10];
  const float* sa_kn_w = (const float*)d_in[11];
  const float* sa_o_w = (const float*)d_in[12];
  const float* sa_o_b = (const float*)d_in[13];
  const float* ca_q_w = (const float*)d_in[14];
  const float* ca_q_b = (const float*)d_in[15];
  const float* ca_kv_w = (const float*)d_in[16];
  const float* ca_kv_b = (const float*)d_in[17];
  const float* ca_qn_w = (const float*)d_in[18];
  const float* ca_kn_w = (const float*)d_in[19];
  const float* ca_o_w = (const float*)d_in[20];
  const float* ca_o_b = (const float*)d_in[21];
  const float* mlp_w1 = (const float*)d_in[22];
  const float* mlp_b1 = (const float*)d_in[23];
  const float* mlp_w2 = (const float*)d_in[24];
  const float* mlp_b2 = (const float*)d_in[25];
  const float* mlp_w3 = (const float*)d_in[26];
  const float* mlp_b3 = (const float*)d_in[27];
  float* out = (float*)d_out;

  char* p = (char*)d_ws;
  auto alloc = [&](size_t bytes) {
    char* r = p;
    p += (bytes + 255) & ~(size_t)255;
    return r;
  };
  float* mods = (float*)alloc(4l * 9216 * 4);
  float* sc = (float*)alloc(4096l * 4);
  float* part = (float*)alloc((long)MODS_KS * 4 * 9216 * 4);
  u16* qkvT = (u16*)alloc(3072l * 1024 * 2);
  u16* saoT = (u16*)alloc(1024l * 1024 * 2);
  u16* caqT = (u16*)alloc(1024l * 1024 * 2);
  u16* cakvT = (u16*)alloc(2048l * 1024 * 2);
  u16* caoT = (u16*)alloc(1024l * 1024 * 2);
  u16* w1T = (u16*)alloc(2816l * 1024 * 2);
  u16* w2T = (u16*)alloc(2816l * 1024 * 2);
  u16* w3T = (u16*)alloc(1024l * 2816 * 2);
  u16* xnb = (u16*)alloc(4096l * 1024 * 2);
  u16* srcb = (u16*)alloc(4096l * 1024 * 2);
  u16* bufA = (u16*)alloc(4096l * 3072 * 2);
  u16* bufB = (u16*)alloc(4096l * 2816 * 2);
  u16* attO = (u16*)alloc(4096l * 1024 * 2);
  u16* vtb = xnb;  // alias: xnb dead during attention

  dim3 tb(32, 8);
  transpose_convert<<<dim3(32, 96), tb, 0, stream>>>(sa_qkv_w, qkvT, 1024, 3072, 1024, 3072);
  transpose_convert<<<dim3(32, 32), tb, 0, stream>>>(sa_o_w, saoT, 1024, 1024, 1024, 1024);
  transpose_convert<<<dim3(32, 32), tb, 0, stream>>>(ca_q_w, caqT, 1024, 1024, 1024, 1024);
  transpose_convert<<<dim3(32, 64), tb, 0, stream>>>(ca_kv_w, cakvT, 1024, 2048, 1024, 2048);
  transpose_convert<<<dim3(32, 32), tb, 0, stream>>>(ca_o_w, caoT, 1024, 1024, 1024, 1024);
  transpose_convert<<<dim3(32, 88), tb, 0, stream>>>(mlp_w1, w1T, 1024, 2730, 1024, 2816);
  transpose_convert<<<dim3(32, 88), tb, 0, stream>>>(mlp_w2, w2T, 1024, 2730, 1024, 2816);
  transpose_convert<<<dim3(88, 32), tb, 0, stream>>>(mlp_w3, w3T, 2730, 1024, 2816, 1024);
  cvt_bf16_kernel<<<4096, 256, 0, stream>>>(src, srcb, 4096l * 1024 / 4);
  silu_kernel<<<16, 256, 0, stream>>>(c, sc);
  mods_partial<<<dim3(36, MODS_KS), 256, 0, stream>>>(sc, ada_w, part);
  mods_reduce<<<dim3(36, 4), 256, 0, stream>>>(part, ada_b, mods);

  // ---- self-attention sublayer (k-norm fused into qkv epilogue; q-norm in attn)
  rmsmod_kernel<<<4096, 256, 0, stream>>>(x, n1_w, mods, 0, 1024, xnb);
  gemm_bf16<0, 128, 2, 1><<<768, 256, 0, stream>>>(xnb, qkvT, 1024, 3072, sa_qkv_b, 3072, bufA,
                                                   nullptr, nullptr, nullptr, 0, 4, 16, 6,
                                                   sa_kn_w, 8, 16, 1.0f);
  vtrans_kernel<<<dim3(16, 16, 4), 256, 0, stream>>>(bufA + 2048, 3072, 1024, vtb);
  attn_kernel<<<dim3(16, 4, 16), 256, 0, stream>>>(bufA, 3072, bufA + 1024, 3072, vtb, sa_qn_w,
                                                   attO, 1024, 1024);
  gemm_bf16<1, 64, 3, 0><<<512, 256, 0, stream>>>(attO, saoT, 1024, 1024, sa_o_b, 1024, nullptr,
                                                  out, x, mods, 2048, 2, 8, 8, nullptr, 0, 0,
                                                  0.f);

  // ---- cross-attention sublayer (k-norm fused into cakv; q-norm in attn)
  rmsmod_kernel<<<4096, 256, 0, stream>>>(out, nc_w, mods, 3072, 4096, xnb);
  gemm_bf16<0, 64, 3, 0><<<512, 256, 0, stream>>>(xnb, caqT, 1024, 1024, ca_q_b, 1024, bufA,
                                                  nullptr, nullptr, nullptr, 0, 2, 8, 8,
                                                  nullptr, 0, 0, 0.f);
  gemm_bf16<0, 128, 2, 1><<<512, 256, 0, stream>>>(srcb, cakvT, 1024, 2048, ca_kv_b, 2048, bufB,
                                                   nullptr, nullptr, nullptr, 0, 2, 8, 8,
                                                   ca_kn_w, 0, 8, 1.0f);
  vtrans_kernel<<<dim3(16, 16, 4), 256, 0, stream>>>(bufB + 1024, 2048, 1024, vtb);
  attn_kernel<<<dim3(16, 4, 16), 256, 0, stream>>>(bufA, 1024, bufB, 2048, vtb, ca_qn_w, attO,
                                                   1024, 1024);
  gemm_bf16<1, 64, 3, 0><<<512, 256, 0, stream>>>(attO, caoT, 1024, 1024, ca_o_b, 1024, nullptr,
                                                  out, out, mods, 5120, 2, 8, 8, nullptr, 0, 0,
                                                  0.f);

  // ---- SwiGLU FFN sublayer: fused dual GEMM, h1 never materialized
  rmsmod_kernel<<<4096, 256, 0, stream>>>(out, n2_w, mods, 6144, 7168, xnb);
  gemm_dual_swiglu<<<1408, 256, 0, stream>>>(xnb, w1T, w2T, 1024, 2816, mlp_b1, mlp_b2, 2730,
                                             bufA, 4, 16, 11);
  gemm_bf16<1, 64, 3, 0><<<512, 256, 0, stream>>>(bufA, w3T, 2816, 1024, mlp_b3, 1024, nullptr,
                                                  out, out, mods, 8192, 2, 8, 8, nullptr, 0, 0,
                                                  0.f);
}

// Round 12
// 362.341 us; speedup vs baseline: 1.5046x; 1.0273x over previous
//
#include <hip/hip_runtime.h>

typedef unsigned short u16;
typedef __attribute__((ext_vector_type(8))) short short8;
typedef __attribute__((ext_vector_type(4))) float f32x4;

#define DD 1024
#define NN 1024
#define MODS_LD 9216

__device__ __forceinline__ float bf2f(u16 v) {
  unsigned int u = ((unsigned int)v) << 16;
  return __builtin_bit_cast(float, u);
}
__device__ __forceinline__ u16 f2bf(float f) {
  unsigned int u = __builtin_bit_cast(unsigned int, f);
  unsigned int lsb = (u >> 16) & 1;
  u += 0x7fffu + lsb;
  return (u16)(u >> 16);
}
__device__ __forceinline__ unsigned cvtpk_bf16(float a, float b) {
  unsigned r;
  asm volatile("v_cvt_pk_bf16_f32 %0, %1, %2" : "=v"(r) : "v"(a), "v"(b));
  return r;
}
__device__ __forceinline__ float exp2x(float x) {
  float r;
  asm("v_exp_f32 %0, %1" : "=v"(r) : "v"(x));
  return r;
}

__device__ __forceinline__ void gload_lds16(const u16* g, u16* l) {
  __builtin_amdgcn_global_load_lds(
      (const __attribute__((address_space(1))) unsigned int*)g,
      (__attribute__((address_space(3))) unsigned int*)l, 16, 0, 0);
}

// XCD super-tile mapping: grid = 8*cr*cc blocks; XCD c gets a cr x cc tile rect.
__device__ __forceinline__ void xcd_tile(int ncolChunks, int cr, int cc, int& tm, int& tn) {
  int id = blockIdx.x;
  int c = id & 7, i = id >> 3;
  int chunkRow = c / ncolChunks, chunkCol = c % ncolChunks;
  tm = chunkRow * cr + (i % cr);
  tn = chunkCol * cc + (i / cr);
}

// ---------------- batched weight transpose + fp32->bf16 -------------------
struct TDesc {
  const float* s;
  u16* d;
  int R, C, R2, C2, gx, start;
};
struct TPack {
  TDesc t[8];
};

__global__ void transpose_all(TPack p) {
  __shared__ float tile[32][33];
  int id = blockIdx.x;
  int k = 0;
#pragma unroll
  for (int j = 1; j < 8; ++j)
    if (id >= p.t[j].start) k = j;
  const float* src = p.t[k].s;
  u16* dst = p.t[k].d;
  int R = p.t[k].R, C = p.t[k].C, R2 = p.t[k].R2, C2 = p.t[k].C2;
  int rem = id - p.t[k].start;
  int gx = p.t[k].gx;
  int r0 = (rem % gx) * 32, c0 = (rem / gx) * 32;
  int tx = threadIdx.x, ty = threadIdx.y;
#pragma unroll
  for (int i = 0; i < 4; ++i) {
    int r = r0 + ty + i * 8, c = c0 + tx;
    tile[ty + i * 8][tx] = (r < R && c < C) ? src[(long)r * C + c] : 0.f;
  }
  __syncthreads();
#pragma unroll
  for (int i = 0; i < 4; ++i) {
    int c = c0 + ty + i * 8, r = r0 + tx;
    if (c < C2 && r < R2) dst[(long)c * R2 + r] = f2bf(tile[tx][ty + i * 8]);
  }
}

// ---------------- fp32 -> bf16 (vector) ---------------------------------
__global__ void cvt_bf16_kernel(const float* __restrict__ in, u16* __restrict__ out, long n4) {
  long i = (long)blockIdx.x * 256 + threadIdx.x;
  if (i >= n4) return;
  float4 v = *(const float4*)&in[i * 4];
  ushort4 pk = {f2bf(v.x), f2bf(v.y), f2bf(v.z), f2bf(v.w)};
  *(ushort4*)&out[i * 4] = pk;
}

// ---------------- mods matvec (silu fused, k-split, deterministic) --------
#define MODS_KS 32
__global__ __launch_bounds__(256) void mods_partial(const float* __restrict__ c,
                                                    const float* __restrict__ aw,
                                                    float* __restrict__ part) {
  __shared__ float scs[4][32];
  int j = blockIdx.x * 256 + threadIdx.x;
  int ks = blockIdx.y;
  int d0 = ks * (DD / MODS_KS);
  int t = threadIdx.x;
  if (t < 32) {
#pragma unroll
    for (int b2 = 0; b2 < 4; ++b2) {
      float v = c[b2 * DD + d0 + t];
      scs[b2][t] = v / (1.f + __expf(-v));
    }
  }
  __syncthreads();
  float a0 = 0.f, a1 = 0.f, a2 = 0.f, a3 = 0.f;
#pragma unroll 8
  for (int d = 0; d < DD / MODS_KS; ++d) {
    float w = aw[(long)(d0 + d) * MODS_LD + j];
    a0 = fmaf(scs[0][d], w, a0);
    a1 = fmaf(scs[1][d], w, a1);
    a2 = fmaf(scs[2][d], w, a2);
    a3 = fmaf(scs[3][d], w, a3);
  }
  long base = (long)ks * 4 * MODS_LD + j;
  part[base] = a0;
  part[base + MODS_LD] = a1;
  part[base + 2 * MODS_LD] = a2;
  part[base + 3 * MODS_LD] = a3;
}

__global__ __launch_bounds__(256) void mods_reduce(const float* __restrict__ part,
                                                   const float* __restrict__ ab,
                                                   float* __restrict__ mods) {
  int j = blockIdx.x * 256 + threadIdx.x;
  int b = blockIdx.y;
  float acc = ab[j];
#pragma unroll
  for (int ks = 0; ks < MODS_KS; ++ks) acc += part[((long)ks * 4 + b) * MODS_LD + j];
  mods[(long)b * MODS_LD + j] = acc;
}

// ---------------- fused RMSNorm + modulate -> bf16 ------------------------
__global__ __launch_bounds__(256) void rmsmod_kernel(const float* __restrict__ x,
                                                     const float* __restrict__ w,
                                                     const float* __restrict__ mods,
                                                     int shiftOff, int scaleOff,
                                                     u16* __restrict__ out) {
  long row = blockIdx.x;
  int b = (int)(row >> 10);
  int t = threadIdx.x;
  const float* xr = x + row * DD;
  float4 v = *(const float4*)&xr[t * 4];
  float ss = v.x * v.x + v.y * v.y + v.z * v.z + v.w * v.w;
#pragma unroll
  for (int msk = 1; msk < 64; msk <<= 1) ss += __shfl_xor(ss, msk);
  __shared__ float red[4];
  if ((t & 63) == 0) red[t >> 6] = ss;
  __syncthreads();
  float tot = red[0] + red[1] + red[2] + red[3];
  float inv = rsqrtf(tot * (1.f / DD) + 1e-6f);
  const float* mrow = mods + (long)b * MODS_LD;
  float vv[4] = {v.x, v.y, v.z, v.w};
  u16 tmp[4];
#pragma unroll
  for (int j = 0; j < 4; ++j) {
    int c = t * 4 + j;
    float rr = vv[j] * inv * w[c] * (1.f + mrow[scaleOff + c]) + mrow[shiftOff + c];
    tmp[j] = f2bf(rr);
  }
  ushort4 pk = {tmp[0], tmp[1], tmp[2], tmp[3]};
  *(ushort4*)&out[row * DD + t * 4] = pk;
}

// ---------------- V pre-transpose: v[b, kv, (h,d)] -> vt[(b,h), d, kv] -----
__global__ void vtrans_kernel(const u16* __restrict__ vb, int kvStride, int Mpb,
                              u16* __restrict__ vt) {
  __shared__ u16 tile[64][66];
  int t = threadIdx.x;
  int kt = blockIdx.x, h = blockIdx.y, b = blockIdx.z;
  const u16* base = vb + ((long)(b * Mpb + kt * 64)) * kvStride + h * 64;
#pragma unroll
  for (int sh = 0; sh < 2; ++sh) {
    int r = sh * 32 + (t >> 3);
    int c0 = (t & 7) * 8;
    short8 vv = *(const short8*)(base + (long)r * kvStride + c0);
#pragma unroll
    for (int j = 0; j < 8; ++j) tile[c0 + j][r] = (u16)vv[j];
  }
  __syncthreads();
  u16* obase = vt + ((long)(b * 16 + h) * 64) * 1024 + kt * 64;
#pragma unroll
  for (int sh = 0; sh < 2; ++sh) {
    int d = sh * 32 + (t >> 3);
    int c0 = (t & 7) * 8;
    u16 tmp[8];
#pragma unroll
    for (int j = 0; j < 8; ++j) tmp[j] = tile[d][c0 + j];
    *(short8*)(obase + (long)d * 1024 + c0) = *(short8*)tmp;
  }
}

// ---------------- GEMM: 128 x BN tiles, counted-vmcnt + T2 swizzle --------
// MODE 0: outb = bf16(acc+bias)
// MODE 1: outf = xin + gate*(acc+bias)
// NORM 1 (BN=128 only): tiles tn in [normLo,normHi) get per-64-head RMS-norm
template <int MODE, int BN, int MINW, int NORM>
__global__ __launch_bounds__(256, MINW) void gemm_bf16(
    const u16* __restrict__ A, const u16* __restrict__ Bt, int K, int ldc,
    const float* __restrict__ bias, int biasN, u16* __restrict__ outb,
    float* __restrict__ outf, const float* __restrict__ xin,
    const float* __restrict__ mods, int gateOff, int ncolChunks, int cr, int cc,
    const float* __restrict__ nw, int normLo, int normHi, float nscale) {
  constexpr int WC = BN / 2;
  constexpr int NT = WC / 16;
  constexpr int LOADS = 4 + BN / 32;
  __shared__ u16 As[2][128 * 64];
  __shared__ u16 Bs[2][BN * 64];
  int t = threadIdx.x;
  int l = t & 63, w = t >> 6;
  int wr = w >> 1, wc = w & 1;
  int lg = l >> 4, ll = l & 15;
  int rx = ll & 7;
  int tm, tn;
  xcd_tile(ncolChunks, cr, cc, tm, tn);
  long rowTile = (long)tm * 128;
  long colTile = (long)tn * BN;
  const u16* Ap = A + rowTile * K;
  const u16* Bp = Bt + colTile * K;
  int srow = t >> 3;
  int sck = ((t & 7) ^ (srow & 7)) * 8;

  auto stage = [&](int buf, int k0) {
#pragma unroll
    for (int i = 0; i < 4; ++i)
      gload_lds16(Ap + (long)(i * 32 + srow) * K + k0 + sck, &As[buf][(i * 256 + t) * 8]);
#pragma unroll
    for (int i = 0; i < BN / 32; ++i)
      gload_lds16(Bp + (long)(i * 32 + srow) * K + k0 + sck, &Bs[buf][(i * 256 + t) * 8]);
  };

  const int ntk = K >> 6;
  stage(0, 0);
  if (ntk > 1) stage(1, 64);

  f32x4 acc[4][NT] = {};
  int cur = 0;
  for (int i = 0; i < ntk; ++i) {
    if (i + 1 < ntk) {
      asm volatile("s_waitcnt vmcnt(%0)" ::"i"(LOADS) : "memory");
    } else {
      asm volatile("s_waitcnt vmcnt(0)" ::: "memory");
    }
    __builtin_amdgcn_s_barrier();
    const u16* Ac = As[cur];
    const u16* Bc = Bs[cur];
    short8 af[2][4], bfr[2][NT];
#pragma unroll
    for (int kk = 0; kk < 2; ++kk) {
#pragma unroll
      for (int m2 = 0; m2 < 4; ++m2)
        af[kk][m2] =
            *(const short8*)&Ac[(wr * 64 + m2 * 16 + ll) * 64 + (((kk * 4 + lg) ^ rx) << 3)];
#pragma unroll
      for (int n2 = 0; n2 < NT; ++n2)
        bfr[kk][n2] =
            *(const short8*)&Bc[(wc * WC + n2 * 16 + ll) * 64 + (((kk * 4 + lg) ^ rx) << 3)];
    }
    asm volatile("s_waitcnt lgkmcnt(0)" ::: "memory");
    __builtin_amdgcn_sched_barrier(0);
    __builtin_amdgcn_s_barrier();
    if (i + 2 < ntk) stage(cur, (i + 2) * 64);
    __builtin_amdgcn_s_setprio(1);
#pragma unroll
    for (int kk = 0; kk < 2; ++kk)
#pragma unroll
      for (int m2 = 0; m2 < 4; ++m2)
#pragma unroll
        for (int n2 = 0; n2 < NT; ++n2)
          acc[m2][n2] = __builtin_amdgcn_mfma_f32_16x16x32_bf16(af[kk][m2], bfr[kk][n2],
                                                                acc[m2][n2], 0, 0, 0);
    __builtin_amdgcn_s_setprio(0);
    cur ^= 1;
  }

  if (NORM == 1 && tn >= normLo && tn < normHi) {
    float bv[NT], wnv[NT];
#pragma unroll
    for (int n2 = 0; n2 < NT; ++n2) {
      long cg = colTile + wc * WC + n2 * 16 + ll;
      bv[n2] = bias[cg];
      wnv[n2] = nw[n2 * 16 + ll];
    }
#pragma unroll
    for (int m2 = 0; m2 < 4; ++m2) {
#pragma unroll
      for (int r = 0; r < 4; ++r) {
        float vals[NT];
        float ss = 0.f;
#pragma unroll
        for (int n2 = 0; n2 < NT; ++n2) {
          vals[n2] = acc[m2][n2][r] + bv[n2];
          ss += vals[n2] * vals[n2];
        }
        ss += __shfl_xor(ss, 1);
        ss += __shfl_xor(ss, 2);
        ss += __shfl_xor(ss, 4);
        ss += __shfl_xor(ss, 8);
        float inv = rsqrtf(ss * (1.f / 64) + 1e-6f) * nscale;
        long rg = rowTile + wr * 64 + m2 * 16 + lg * 4 + r;
#pragma unroll
        for (int n2 = 0; n2 < NT; ++n2) {
          long cg = colTile + wc * WC + n2 * 16 + ll;
          outb[rg * ldc + cg] = f2bf(vals[n2] * inv * wnv[n2]);
        }
      }
    }
    return;
  }

#pragma unroll
  for (int n2 = 0; n2 < NT; ++n2) {
    long cg = colTile + wc * WC + n2 * 16 + ll;
    float bv = (cg < biasN) ? bias[cg] : 0.f;
#pragma unroll
    for (int m2 = 0; m2 < 4; ++m2) {
#pragma unroll
      for (int r = 0; r < 4; ++r) {
        long rg = rowTile + wr * 64 + m2 * 16 + lg * 4 + r;
        float v = acc[m2][n2][r] + bv;
        long idx = rg * ldc + cg;
        if (MODE == 0) {
          outb[idx] = f2bf(v);
        } else {
          int bb = (int)(rg >> 10);
          outf[idx] = xin[idx] + mods[(long)bb * MODS_LD + gateOff + cg] * v;
        }
      }
    }
  }
}

// ---------------- dual GEMM + swiglu: h = silu(A@B1+b1)*(A@B2+b2) ---------
__global__ __launch_bounds__(256, 2) void gemm_dual_swiglu(
    const u16* __restrict__ A, const u16* __restrict__ B1t, const u16* __restrict__ B2t,
    int K, int ldc, const float* __restrict__ b1, const float* __restrict__ b2, int biasN,
    u16* __restrict__ outb, int ncolChunks, int cr, int cc) {
  constexpr int BN = 64, WC = 32, NT = 2;
  __shared__ u16 As[2][128 * 64];
  __shared__ u16 B1s[2][BN * 64];
  __shared__ u16 B2s[2][BN * 64];
  int t = threadIdx.x;
  int l = t & 63, w = t >> 6;
  int wr = w >> 1, wc = w & 1;
  int lg = l >> 4, ll = l & 15;
  int rx = ll & 7;
  int tm, tn;
  xcd_tile(ncolChunks, cr, cc, tm, tn);
  long rowTile = (long)tm * 128;
  long colTile = (long)tn * BN;
  const u16* Ap = A + rowTile * K;
  const u16* B1p = B1t + colTile * K;
  const u16* B2p = B2t + colTile * K;
  int srow = t >> 3;
  int sck = ((t & 7) ^ (srow & 7)) * 8;

  auto stage = [&](int buf, int k0) {
#pragma unroll
    for (int i = 0; i < 4; ++i)
      gload_lds16(Ap + (long)(i * 32 + srow) * K + k0 + sck, &As[buf][(i * 256 + t) * 8]);
#pragma unroll
    for (int i = 0; i < 2; ++i) {
      gload_lds16(B1p + (long)(i * 32 + srow) * K + k0 + sck, &B1s[buf][(i * 256 + t) * 8]);
      gload_lds16(B2p + (long)(i * 32 + srow) * K + k0 + sck, &B2s[buf][(i * 256 + t) * 8]);
    }
  };

  const int ntk = K >> 6;
  stage(0, 0);
  if (ntk > 1) stage(1, 64);

  f32x4 acc1[4][NT] = {}, acc2[4][NT] = {};
  int cur = 0;
  for (int i = 0; i < ntk; ++i) {
    if (i + 1 < ntk) {
      asm volatile("s_waitcnt vmcnt(8)" ::: "memory");
    } else {
      asm volatile("s_waitcnt vmcnt(0)" ::: "memory");
    }
    __builtin_amdgcn_s_barrier();
    const u16* Ac = As[cur];
    const u16* B1c = B1s[cur];
    const u16* B2c = B2s[cur];
    short8 af[2][4], b1f[2][NT], b2f[2][NT];
#pragma unroll
    for (int kk = 0; kk < 2; ++kk) {
#pragma unroll
      for (int m2 = 0; m2 < 4; ++m2)
        af[kk][m2] =
            *(const short8*)&Ac[(wr * 64 + m2 * 16 + ll) * 64 + (((kk * 4 + lg) ^ rx) << 3)];
#pragma unroll
      for (int n2 = 0; n2 < NT; ++n2) {
        int off = (wc * WC + n2 * 16 + ll) * 64 + (((kk * 4 + lg) ^ rx) << 3);
        b1f[kk][n2] = *(const short8*)&B1c[off];
        b2f[kk][n2] = *(const short8*)&B2c[off];
      }
    }
    asm volatile("s_waitcnt lgkmcnt(0)" ::: "memory");
    __builtin_amdgcn_sched_barrier(0);
    __builtin_amdgcn_s_barrier();
    if (i + 2 < ntk) stage(cur, (i + 2) * 64);
    __builtin_amdgcn_s_setprio(1);
#pragma unroll
    for (int kk = 0; kk < 2; ++kk)
#pragma unroll
      for (int m2 = 0; m2 < 4; ++m2)
#pragma unroll
        for (int n2 = 0; n2 < NT; ++n2) {
          acc1[m2][n2] = __builtin_amdgcn_mfma_f32_16x16x32_bf16(af[kk][m2], b1f[kk][n2],
                                                                 acc1[m2][n2], 0, 0, 0);
          acc2[m2][n2] = __builtin_amdgcn_mfma_f32_16x16x32_bf16(af[kk][m2], b2f[kk][n2],
                                                                 acc2[m2][n2], 0, 0, 0);
        }
    __builtin_amdgcn_s_setprio(0);
    cur ^= 1;
  }
#pragma unroll
  for (int n2 = 0; n2 < NT; ++n2) {
    long cg = colTile + wc * WC + n2 * 16 + ll;
    float bv1 = (cg < biasN) ? b1[cg] : 0.f;
    float bv2 = (cg < biasN) ? b2[cg] : 0.f;
#pragma unroll
    for (int m2 = 0; m2 < 4; ++m2) {
#pragma unroll
      for (int r = 0; r < 4; ++r) {
        long rg = rowTile + wr * 64 + m2 * 16 + lg * 4 + r;
        float v1 = acc1[m2][n2][r] + bv1;
        float v2 = acc2[m2][n2][r] + bv2;
        float sg = v1 / (1.f + __expf(-v1));
        outb[rg * ldc + cg] = f2bf(sg * v2);
      }
    }
  }
}

// ---------------- flash attention v6: log2-domain softmax + defer-max -----
__global__ __launch_bounds__(256, 3) void attn_kernel(
    const u16* __restrict__ qb, int qStride, const u16* __restrict__ kb, int kvStride,
    const u16* __restrict__ vt, const float* __restrict__ qn, u16* __restrict__ outp,
    int Nk, int Mpb) {
  __shared__ u16 Qs[64 * 64];
  __shared__ u16 Ks[2][64 * 64];
  __shared__ u16 Vs[2][64 * 64];
  __shared__ u16 Ps[4][16 * 64];
  int t = threadIdx.x, w = t >> 6, l = t & 63;
  int h = blockIdx.x, b = blockIdx.y, qt = blockIdx.z;
  int lg = l >> 4, ll = l & 15;
  int rx = ll & 7;

  const u16* Qbase = qb + ((long)(b * NN + qt * 64)) * qStride + h * 64;
  const u16* Kbase = kb + ((long)b * Mpb) * kvStride + h * 64;
  const u16* Vbase = vt + ((long)(b * 16 + h) * 64) * 1024;

  int srow = t >> 3;
  int schunk = t & 7;

#pragma unroll
  for (int sh = 0; sh < 2; ++sh) {
    int row = sh * 32 + srow;
    int ck = schunk ^ (row & 7);
    gload_lds16(Qbase + (long)row * qStride + ck * 8, &Qs[sh * 2048 + t * 8]);
  }
  auto stageKV = [&](int buf, int kt) {
    const u16* kn = Kbase + (long)kt * 64 * kvStride;
    const u16* vn = Vbase + kt * 64;
#pragma unroll
    for (int sh = 0; sh < 2; ++sh) {
      int row = sh * 32 + srow;
      int ck = schunk ^ (row & 7);
      gload_lds16(kn + (long)row * kvStride + ck * 8, &Ks[buf][sh * 2048 + t * 8]);
      gload_lds16(vn + (long)row * 1024 + ck * 8, &Vs[buf][sh * 2048 + t * 8]);
    }
  };
  const int ntk = Nk >> 6;
  stageKV(0, 0);
  if (ntk > 1) stageKV(1, 1);

  short8 qf0, qf1;
  float mrun = -1e30f, ssum = 0.f;
  f32x4 o[4] = {};

  int cur = 0;
  for (int kt = 0; kt < ntk; ++kt) {
    if (kt + 1 < ntk) {
      asm volatile("s_waitcnt vmcnt(4)" ::: "memory");
    } else {
      asm volatile("s_waitcnt vmcnt(0)" ::: "memory");
    }
    __builtin_amdgcn_s_barrier();
    if (kt == 0) {
      qf0 = *(const short8*)&Qs[(w * 16 + ll) * 64 + ((lg ^ rx) << 3)];
      qf1 = *(const short8*)&Qs[(w * 16 + ll) * 64 + (((4 + lg) ^ rx) << 3)];
      // fused q RMS-norm; fold softmax scale AND log2(e) so scores are log2-domain
      float qv0[8], qv1[8], ss = 0.f;
#pragma unroll
      for (int j = 0; j < 8; ++j) {
        qv0[j] = bf2f((u16)qf0[j]);
        qv1[j] = bf2f((u16)qf1[j]);
        ss += qv0[j] * qv0[j] + qv1[j] * qv1[j];
      }
      ss += __shfl_xor(ss, 16);
      ss += __shfl_xor(ss, 32);
      float inv = rsqrtf(ss * (1.f / 64) + 1e-6f) * (0.125f * 1.44269504f);
      int d0 = (lg ^ rx) << 3, d1 = ((4 + lg) ^ rx) << 3;
      u16 t0[8], t1[8];
#pragma unroll
      for (int j = 0; j < 8; ++j) {
        t0[j] = f2bf(qv0[j] * inv * qn[d0 + j]);
        t1[j] = f2bf(qv1[j] * inv * qn[d1 + j]);
      }
      qf0 = *(short8*)t0;
      qf1 = *(short8*)t1;
    }
    const u16* Kc = Ks[cur];
    f32x4 s[4] = {};
#pragma unroll
    for (int n = 0; n < 4; ++n) {
      short8 kf0 = *(const short8*)&Kc[(n * 16 + ll) * 64 + ((lg ^ rx) << 3)];
      short8 kf1 = *(const short8*)&Kc[(n * 16 + ll) * 64 + (((4 + lg) ^ rx) << 3)];
      s[n] = __builtin_amdgcn_mfma_f32_16x16x32_bf16(kf0, qf0, s[n], 0, 0, 0);
      s[n] = __builtin_amdgcn_mfma_f32_16x16x32_bf16(kf1, qf1, s[n], 0, 0, 0);
    }
    float t0 = fmaxf(fmaxf(s[0][0], s[0][1]), fmaxf(s[0][2], s[0][3]));
    float t1 = fmaxf(fmaxf(s[1][0], s[1][1]), fmaxf(s[1][2], s[1][3]));
    float t2 = fmaxf(fmaxf(s[2][0], s[2][1]), fmaxf(s[2][2], s[2][3]));
    float t3 = fmaxf(fmaxf(s[3][0], s[3][1]), fmaxf(s[3][2], s[3][3]));
    float pm = fmaxf(fmaxf(t0, t1), fmaxf(t2, t3));
    pm = fmaxf(pm, __shfl_xor(pm, 16));
    pm = fmaxf(pm, __shfl_xor(pm, 32));
    // defer-max (T13): skip rescale when all rows grew by <= 8 (log2 units)
    bool resc = !__all(pm - mrun <= 8.f);
    float nm = resc ? fmaxf(mrun, pm) : mrun;
    float pn[4][4];
#pragma unroll
    for (int n = 0; n < 4; ++n)
#pragma unroll
      for (int r = 0; r < 4; ++r) pn[n][r] = exp2x(s[n][r] - nm);
    float r0 = (pn[0][0] + pn[0][1]) + (pn[0][2] + pn[0][3]);
    float r1 = (pn[1][0] + pn[1][1]) + (pn[1][2] + pn[1][3]);
    float r2 = (pn[2][0] + pn[2][1]) + (pn[2][2] + pn[2][3]);
    float r3 = (pn[3][0] + pn[3][1]) + (pn[3][2] + pn[3][3]);
    float rs = (r0 + r1) + (r2 + r3);
    rs += __shfl_xor(rs, 16);
    rs += __shfl_xor(rs, 32);
    if (resc) {
      float alpha = exp2x(mrun - nm);
      ssum = ssum * alpha + rs;
      float a0 = __shfl(alpha, lg * 4 + 0);
      float a1 = __shfl(alpha, lg * 4 + 1);
      float a2 = __shfl(alpha, lg * 4 + 2);
      float a3 = __shfl(alpha, lg * 4 + 3);
#pragma unroll
      for (int n = 0; n < 4; ++n) {
        o[n][0] *= a0;
        o[n][1] *= a1;
        o[n][2] *= a2;
        o[n][3] *= a3;
      }
    } else {
      ssum += rs;
    }
    mrun = nm;
#pragma unroll
    for (int n = 0; n < 4; ++n) {
      uint2 pkd;
      pkd.x = cvtpk_bf16(pn[n][0], pn[n][1]);
      pkd.y = cvtpk_bf16(pn[n][2], pn[n][3]);
      int gran = n * 2 + (lg >> 1);
      int perm = gran ^ rx;
      *(uint2*)&Ps[w][ll * 64 + perm * 8 + (lg & 1) * 4] = pkd;
    }
    short8 pf0 = *(const short8*)&Ps[w][ll * 64 + ((lg ^ rx) << 3)];
    short8 pf1 = *(const short8*)&Ps[w][ll * 64 + (((4 + lg) ^ rx) << 3)];
    const u16* Vc = Vs[cur];
    short8 vfr[4][2];
#pragma unroll
    for (int n = 0; n < 4; ++n) {
      vfr[n][0] = *(const short8*)&Vc[(n * 16 + ll) * 64 + ((lg ^ rx) << 3)];
      vfr[n][1] = *(const short8*)&Vc[(n * 16 + ll) * 64 + (((4 + lg) ^ rx) << 3)];
    }
    asm volatile("s_waitcnt lgkmcnt(0)" ::: "memory");
    __builtin_amdgcn_sched_barrier(0);
    __builtin_amdgcn_s_barrier();
    if (kt + 2 < ntk) stageKV(cur, kt + 2);
    __builtin_amdgcn_s_setprio(1);
#pragma unroll
    for (int n = 0; n < 4; ++n) {
      o[n] = __builtin_amdgcn_mfma_f32_16x16x32_bf16(pf0, vfr[n][0], o[n], 0, 0, 0);
      o[n] = __builtin_amdgcn_mfma_f32_16x16x32_bf16(pf1, vfr[n][1], o[n], 0, 0, 0);
    }
    __builtin_amdgcn_s_setprio(0);
    cur ^= 1;
  }
  float s0 = __shfl(ssum, lg * 4 + 0);
  float s1 = __shfl(ssum, lg * 4 + 1);
  float s2 = __shfl(ssum, lg * 4 + 2);
  float s3 = __shfl(ssum, lg * 4 + 3);
  float i0 = 1.f / s0, i1 = 1.f / s1, i2 = 1.f / s2, i3 = 1.f / s3;
#pragma unroll
  for (int n = 0; n < 4; ++n) {
    float ir[4] = {i0, i1, i2, i3};
#pragma unroll
    for (int r = 0; r < 4; ++r) {
      long row = (long)b * NN + qt * 64 + w * 16 + lg * 4 + r;
      int col = h * 64 + n * 16 + ll;
      outp[row * DD + col] = f2bf(o[n][r] * ir[r]);
    }
  }
}

extern "C" void kernel_launch(void* const* d_in, const int* in_sizes, int n_in,
                              void* d_out, int out_size, void* d_ws, size_t ws_size,
                              hipStream_t stream) {
  const float* x = (const float*)d_in[0];
  const float* src = (const float*)d_in[1];
  const float* c = (const float*)d_in[2];
  const float* ada_w = (const float*)d_in[3];
  const float* ada_b = (const float*)d_in[4];
  const float* n1_w = (const float*)d_in[5];
  const float* nc_w = (const float*)d_in[6];
  const float* n2_w = (const float*)d_in[7];
  const float* sa_qkv_w = (const float*)d_in[8];
  const float* sa_qkv_b = (const float*)d_in[9];
  const float* sa_qn_w = (const float*)d_in[10];
  const float* sa_kn_w = (const float*)d_in[11];
  const float* sa_o_w = (const float*)d_in[12];
  const float* sa_o_b = (const float*)d_in[13];
  const float* ca_q_w = (const float*)d_in[14];
  const float* ca_q_b = (const float*)d_in[15];
  const float* ca_kv_w = (const float*)d_in[16];
  const float* ca_kv_b = (const float*)d_in[17];
  const float* ca_qn_w = (const float*)d_in[18];
  const float* ca_kn_w = (const float*)d_in[19];
  const float* ca_o_w = (const float*)d_in[20];
  const float* ca_o_b = (const float*)d_in[21];
  const float* mlp_w1 = (const float*)d_in[22];
  const float* mlp_b1 = (const float*)d_in[23];
  const float* mlp_w2 = (const float*)d_in[24];
  const float* mlp_b2 = (const float*)d_in[25];
  const float* mlp_w3 = (const float*)d_in[26];
  const float* mlp_b3 = (const float*)d_in[27];
  float* out = (float*)d_out;

  char* p = (char*)d_ws;
  auto alloc = [&](size_t bytes) {
    char* r = p;
    p += (bytes + 255) & ~(size_t)255;
    return r;
  };
  float* mods = (float*)alloc(4l * 9216 * 4);
  float* part = (float*)alloc((long)MODS_KS * 4 * 9216 * 4);
  u16* qkvT = (u16*)alloc(3072l * 1024 * 2);
  u16* saoT = (u16*)alloc(1024l * 1024 * 2);
  u16* caqT = (u16*)alloc(1024l * 1024 * 2);
  u16* cakvT = (u16*)alloc(2048l * 1024 * 2);
  u16* caoT = (u16*)alloc(1024l * 1024 * 2);
  u16* w1T = (u16*)alloc(2816l * 1024 * 2);
  u16* w2T = (u16*)alloc(2816l * 1024 * 2);
  u16* w3T = (u16*)alloc(1024l * 2816 * 2);
  u16* xnb = (u16*)alloc(4096l * 1024 * 2);
  u16* srcb = (u16*)alloc(4096l * 1024 * 2);
  u16* bufA = (u16*)alloc(4096l * 3072 * 2);
  u16* bufB = (u16*)alloc(4096l * 2816 * 2);
  u16* attO = (u16*)alloc(4096l * 1024 * 2);
  u16* vtb = xnb;  // alias: xnb dead during attention

  TPack tp;
  tp.t[0] = {sa_qkv_w, qkvT, 1024, 3072, 1024, 3072, 32, 0};
  tp.t[1] = {sa_o_w, saoT, 1024, 1024, 1024, 1024, 32, 3072};
  tp.t[2] = {ca_q_w, caqT, 1024, 1024, 1024, 1024, 32, 4096};
  tp.t[3] = {ca_kv_w, cakvT, 1024, 2048, 1024, 2048, 32, 5120};
  tp.t[4] = {ca_o_w, caoT, 1024, 1024, 1024, 1024, 32, 7168};
  tp.t[5] = {mlp_w1, w1T, 1024, 2730, 1024, 2816, 32, 8192};
  tp.t[6] = {mlp_w2, w2T, 1024, 2730, 1024, 2816, 32, 11008};
  tp.t[7] = {mlp_w3, w3T, 2730, 1024, 2816, 1024, 88, 13824};
  transpose_all<<<16640, dim3(32, 8), 0, stream>>>(tp);
  cvt_bf16_kernel<<<4096, 256, 0, stream>>>(src, srcb, 4096l * 1024 / 4);
  mods_partial<<<dim3(36, MODS_KS), 256, 0, stream>>>(c, ada_w, part);
  mods_reduce<<<dim3(36, 4), 256, 0, stream>>>(part, ada_b, mods);

  // ---- self-attention sublayer (k-norm fused into qkv epilogue; q-norm in attn)
  rmsmod_kernel<<<4096, 256, 0, stream>>>(x, n1_w, mods, 0, 1024, xnb);
  gemm_bf16<0, 128, 2, 1><<<768, 256, 0, stream>>>(xnb, qkvT, 1024, 3072, sa_qkv_b, 3072, bufA,
                                                   nullptr, nullptr, nullptr, 0, 4, 16, 6,
                                                   sa_kn_w, 8, 16, 1.0f);
  vtrans_kernel<<<dim3(16, 16, 4), 256, 0, stream>>>(bufA + 2048, 3072, 1024, vtb);
  attn_kernel<<<dim3(16, 4, 16), 256, 0, stream>>>(bufA, 3072, bufA + 1024, 3072, vtb, sa_qn_w,
                                                   attO, 1024, 1024);
  gemm_bf16<1, 64, 3, 0><<<512, 256, 0, stream>>>(attO, saoT, 1024, 1024, sa_o_b, 1024, nullptr,
                                                  out, x, mods, 2048, 2, 8, 8, nullptr, 0, 0,
                                                  0.f);

  // ---- cross-attention sublayer (k-norm fused into cakv; q-norm in attn)
  rmsmod_kernel<<<4096, 256, 0, stream>>>(out, nc_w, mods, 3072, 4096, xnb);
  gemm_bf16<0, 64, 3, 0><<<512, 256, 0, stream>>>(xnb, caqT, 1024, 1024, ca_q_b, 1024, bufA,
                                                  nullptr, nullptr, nullptr, 0, 2, 8, 8,
                                                  nullptr, 0, 0, 0.f);
  gemm_bf16<0, 128, 2, 1><<<512, 256, 0, stream>>>(srcb, cakvT, 1024, 2048, ca_kv_b, 2048, bufB,
                                                   nullptr, nullptr, nullptr, 0, 2, 8, 8,
                                                   ca_kn_w, 0, 8, 1.0f);
  vtrans_kernel<<<dim3(16, 16, 4), 256, 0, stream>>>(bufB + 1024, 2048, 1024, vtb);
  attn_kernel<<<dim3(16, 4, 16), 256, 0, stream>>>(bufA, 1024, bufB, 2048, vtb, ca_qn_w, attO,
                                                   1024, 1024);
  gemm_bf16<1, 64, 3, 0><<<512, 256, 0, stream>>>(attO, caoT, 1024, 1024, ca_o_b, 1024, nullptr,
                                                  out, out, mods, 5120, 2, 8, 8, nullptr, 0, 0,
                                                  0.f);

  // ---- SwiGLU FFN sublayer: fused dual GEMM, h1 never materialized
  rmsmod_kernel<<<4096, 256, 0, stream>>>(out, n2_w, mods, 6144, 7168, xnb);
  gemm_dual_swiglu<<<1408, 256, 0, stream>>>(xnb, w1T, w2T, 1024, 2816, mlp_b1, mlp_b2, 2730,
                                             bufA, 4, 16, 11);
  gemm_bf16<1, 64, 3, 0><<<512, 256, 0, stream>>>(bufA, w3T, 2816, 1024, mlp_b3, 1024, nullptr,
                                                  out, out, mods, 8192, 2, 8, 8, nullptr, 0, 0,
                                                  0.f);
}

// Round 13
// 334.742 us; speedup vs baseline: 1.6286x; 1.0824x over previous
//
#include <hip/hip_runtime.h>

typedef unsigned short u16;
typedef __attribute__((ext_vector_type(8))) short short8;
typedef __attribute__((ext_vector_type(4))) float f32x4;

#define DD 1024
#define NN 1024
#define MODS_LD 9216

__device__ __forceinline__ float bf2f(u16 v) {
  unsigned int u = ((unsigned int)v) << 16;
  return __builtin_bit_cast(float, u);
}
__device__ __forceinline__ u16 f2bf(float f) {
  unsigned int u = __builtin_bit_cast(unsigned int, f);
  unsigned int lsb = (u >> 16) & 1;
  u += 0x7fffu + lsb;
  return (u16)(u >> 16);
}
__device__ __forceinline__ unsigned cvtpk_bf16(float a, float b) {
  unsigned r;
  asm volatile("v_cvt_pk_bf16_f32 %0, %1, %2" : "=v"(r) : "v"(a), "v"(b));
  return r;
}
__device__ __forceinline__ float exp2x(float x) {
  float r;
  asm("v_exp_f32 %0, %1" : "=v"(r) : "v"(x));
  return r;
}

__device__ __forceinline__ void gload_lds16(const u16* g, u16* l) {
  __builtin_amdgcn_global_load_lds(
      (const __attribute__((address_space(1))) unsigned int*)g,
      (__attribute__((address_space(3))) unsigned int*)l, 16, 0, 0);
}

// XCD super-tile mapping: grid = 8*cr*cc blocks; XCD c gets a cr x cc tile rect.
__device__ __forceinline__ void xcd_tile(int ncolChunks, int cr, int cc, int& tm, int& tn) {
  int id = blockIdx.x;
  int c = id & 7, i = id >> 3;
  int chunkRow = c / ncolChunks, chunkCol = c % ncolChunks;
  tm = chunkRow * cr + (i % cr);
  tn = chunkCol * cc + (i / cr);
}

// ---------------- batched weight transpose + fp32->bf16 -------------------
struct TDesc {
  const float* s;
  u16* d;
  int R, C, R2, C2, gx, start;
};
struct TPack {
  TDesc t[8];
};

__global__ void transpose_all(TPack p) {
  __shared__ float tile[32][33];
  int id = blockIdx.x;
  int k = 0;
#pragma unroll
  for (int j = 1; j < 8; ++j)
    if (id >= p.t[j].start) k = j;
  const float* src = p.t[k].s;
  u16* dst = p.t[k].d;
  int R = p.t[k].R, C = p.t[k].C, R2 = p.t[k].R2, C2 = p.t[k].C2;
  int rem = id - p.t[k].start;
  int gx = p.t[k].gx;
  int r0 = (rem % gx) * 32, c0 = (rem / gx) * 32;
  int tx = threadIdx.x, ty = threadIdx.y;
#pragma unroll
  for (int i = 0; i < 4; ++i) {
    int r = r0 + ty + i * 8, c = c0 + tx;
    tile[ty + i * 8][tx] = (r < R && c < C) ? src[(long)r * C + c] : 0.f;
  }
  __syncthreads();
#pragma unroll
  for (int i = 0; i < 4; ++i) {
    int c = c0 + ty + i * 8, r = r0 + tx;
    if (c < C2 && r < R2) dst[(long)c * R2 + r] = f2bf(tile[tx][ty + i * 8]);
  }
}

// ---------------- fp32 -> bf16 (vector) ---------------------------------
__global__ void cvt_bf16_kernel(const float* __restrict__ in, u16* __restrict__ out, long n4) {
  long i = (long)blockIdx.x * 256 + threadIdx.x;
  if (i >= n4) return;
  float4 v = *(const float4*)&in[i * 4];
  ushort4 pk = {f2bf(v.x), f2bf(v.y), f2bf(v.z), f2bf(v.w)};
  *(ushort4*)&out[i * 4] = pk;
}

// ---------------- mods matvec (silu fused, k-split, deterministic) --------
#define MODS_KS 32
__global__ __launch_bounds__(256) void mods_partial(const float* __restrict__ c,
                                                    const float* __restrict__ aw,
                                                    float* __restrict__ part) {
  __shared__ float scs[4][32];
  int j = blockIdx.x * 256 + threadIdx.x;
  int ks = blockIdx.y;
  int d0 = ks * (DD / MODS_KS);
  int t = threadIdx.x;
  if (t < 32) {
#pragma unroll
    for (int b2 = 0; b2 < 4; ++b2) {
      float v = c[b2 * DD + d0 + t];
      scs[b2][t] = v / (1.f + __expf(-v));
    }
  }
  __syncthreads();
  float a0 = 0.f, a1 = 0.f, a2 = 0.f, a3 = 0.f;
#pragma unroll 8
  for (int d = 0; d < DD / MODS_KS; ++d) {
    float w = aw[(long)(d0 + d) * MODS_LD + j];
    a0 = fmaf(scs[0][d], w, a0);
    a1 = fmaf(scs[1][d], w, a1);
    a2 = fmaf(scs[2][d], w, a2);
    a3 = fmaf(scs[3][d], w, a3);
  }
  long base = (long)ks * 4 * MODS_LD + j;
  part[base] = a0;
  part[base + MODS_LD] = a1;
  part[base + 2 * MODS_LD] = a2;
  part[base + 3 * MODS_LD] = a3;
}

__global__ __launch_bounds__(256) void mods_reduce(const float* __restrict__ part,
                                                   const float* __restrict__ ab,
                                                   float* __restrict__ mods) {
  int j = blockIdx.x * 256 + threadIdx.x;
  int b = blockIdx.y;
  float acc = ab[j];
#pragma unroll
  for (int ks = 0; ks < MODS_KS; ++ks) acc += part[((long)ks * 4 + b) * MODS_LD + j];
  mods[(long)b * MODS_LD + j] = acc;
}

// ---------------- fused RMSNorm + modulate -> bf16 ------------------------
__global__ __launch_bounds__(256) void rmsmod_kernel(const float* __restrict__ x,
                                                     const float* __restrict__ w,
                                                     const float* __restrict__ mods,
                                                     int shiftOff, int scaleOff,
                                                     u16* __restrict__ out) {
  long row = blockIdx.x;
  int b = (int)(row >> 10);
  int t = threadIdx.x;
  const float* xr = x + row * DD;
  float4 v = *(const float4*)&xr[t * 4];
  float ss = v.x * v.x + v.y * v.y + v.z * v.z + v.w * v.w;
#pragma unroll
  for (int msk = 1; msk < 64; msk <<= 1) ss += __shfl_xor(ss, msk);
  __shared__ float red[4];
  if ((t & 63) == 0) red[t >> 6] = ss;
  __syncthreads();
  float tot = red[0] + red[1] + red[2] + red[3];
  float inv = rsqrtf(tot * (1.f / DD) + 1e-6f);
  const float* mrow = mods + (long)b * MODS_LD;
  float vv[4] = {v.x, v.y, v.z, v.w};
  u16 tmp[4];
#pragma unroll
  for (int j = 0; j < 4; ++j) {
    int c = t * 4 + j;
    float rr = vv[j] * inv * w[c] * (1.f + mrow[scaleOff + c]) + mrow[shiftOff + c];
    tmp[j] = f2bf(rr);
  }
  ushort4 pk = {tmp[0], tmp[1], tmp[2], tmp[3]};
  *(ushort4*)&out[row * DD + t * 4] = pk;
}

// ---------------- V pre-transpose: v[b, kv, (h,d)] -> vt[(b,h), d, kv] -----
__global__ void vtrans_kernel(const u16* __restrict__ vb, int kvStride, int Mpb,
                              u16* __restrict__ vt) {
  __shared__ u16 tile[64][66];
  int t = threadIdx.x;
  int kt = blockIdx.x, h = blockIdx.y, b = blockIdx.z;
  const u16* base = vb + ((long)(b * Mpb + kt * 64)) * kvStride + h * 64;
#pragma unroll
  for (int sh = 0; sh < 2; ++sh) {
    int r = sh * 32 + (t >> 3);
    int c0 = (t & 7) * 8;
    short8 vv = *(const short8*)(base + (long)r * kvStride + c0);
#pragma unroll
    for (int j = 0; j < 8; ++j) tile[c0 + j][r] = (u16)vv[j];
  }
  __syncthreads();
  u16* obase = vt + ((long)(b * 16 + h) * 64) * 1024 + kt * 64;
#pragma unroll
  for (int sh = 0; sh < 2; ++sh) {
    int d = sh * 32 + (t >> 3);
    int c0 = (t & 7) * 8;
    u16 tmp[8];
#pragma unroll
    for (int j = 0; j < 8; ++j) tmp[j] = tile[d][c0 + j];
    *(short8*)(obase + (long)d * 1024 + c0) = *(short8*)tmp;
  }
}

// ---------------- GEMM: 128 x BN tiles, counted-vmcnt + T2 swizzle --------
// MODE 0: outb = bf16(acc+bias)
// MODE 1: outf = xin + gate*(acc+bias)
// NORM 1 (BN=128 only): tiles tn in [normLo,normHi) get per-64-head RMS-norm
template <int MODE, int BN, int MINW, int NORM>
__global__ __launch_bounds__(256, MINW) void gemm_bf16(
    const u16* __restrict__ A, const u16* __restrict__ Bt, int K, int ldc,
    const float* __restrict__ bias, int biasN, u16* __restrict__ outb,
    float* __restrict__ outf, const float* __restrict__ xin,
    const float* __restrict__ mods, int gateOff, int ncolChunks, int cr, int cc,
    const float* __restrict__ nw, int normLo, int normHi, float nscale) {
  constexpr int WC = BN / 2;
  constexpr int NT = WC / 16;
  constexpr int LOADS = 4 + BN / 32;
  __shared__ u16 As[2][128 * 64];
  __shared__ u16 Bs[2][BN * 64];
  int t = threadIdx.x;
  int l = t & 63, w = t >> 6;
  int wr = w >> 1, wc = w & 1;
  int lg = l >> 4, ll = l & 15;
  int rx = ll & 7;
  int tm, tn;
  xcd_tile(ncolChunks, cr, cc, tm, tn);
  long rowTile = (long)tm * 128;
  long colTile = (long)tn * BN;
  const u16* Ap = A + rowTile * K;
  const u16* Bp = Bt + colTile * K;
  int srow = t >> 3;
  int sck = ((t & 7) ^ (srow & 7)) * 8;

  auto stage = [&](int buf, int k0) {
#pragma unroll
    for (int i = 0; i < 4; ++i)
      gload_lds16(Ap + (long)(i * 32 + srow) * K + k0 + sck, &As[buf][(i * 256 + t) * 8]);
#pragma unroll
    for (int i = 0; i < BN / 32; ++i)
      gload_lds16(Bp + (long)(i * 32 + srow) * K + k0 + sck, &Bs[buf][(i * 256 + t) * 8]);
  };

  const int ntk = K >> 6;
  stage(0, 0);
  if (ntk > 1) stage(1, 64);

  f32x4 acc[4][NT] = {};
  int cur = 0;
  for (int i = 0; i < ntk; ++i) {
    if (i + 1 < ntk) {
      asm volatile("s_waitcnt vmcnt(%0)" ::"i"(LOADS) : "memory");
    } else {
      asm volatile("s_waitcnt vmcnt(0)" ::: "memory");
    }
    __builtin_amdgcn_s_barrier();
    const u16* Ac = As[cur];
    const u16* Bc = Bs[cur];
    short8 af[2][4], bfr[2][NT];
#pragma unroll
    for (int kk = 0; kk < 2; ++kk) {
#pragma unroll
      for (int m2 = 0; m2 < 4; ++m2)
        af[kk][m2] =
            *(const short8*)&Ac[(wr * 64 + m2 * 16 + ll) * 64 + (((kk * 4 + lg) ^ rx) << 3)];
#pragma unroll
      for (int n2 = 0; n2 < NT; ++n2)
        bfr[kk][n2] =
            *(const short8*)&Bc[(wc * WC + n2 * 16 + ll) * 64 + (((kk * 4 + lg) ^ rx) << 3)];
    }
    asm volatile("s_waitcnt lgkmcnt(0)" ::: "memory");
    __builtin_amdgcn_sched_barrier(0);
    __builtin_amdgcn_s_barrier();
    if (i + 2 < ntk) stage(cur, (i + 2) * 64);
    __builtin_amdgcn_s_setprio(1);
#pragma unroll
    for (int kk = 0; kk < 2; ++kk)
#pragma unroll
      for (int m2 = 0; m2 < 4; ++m2)
#pragma unroll
        for (int n2 = 0; n2 < NT; ++n2)
          acc[m2][n2] = __builtin_amdgcn_mfma_f32_16x16x32_bf16(af[kk][m2], bfr[kk][n2],
                                                                acc[m2][n2], 0, 0, 0);
    __builtin_amdgcn_s_setprio(0);
    cur ^= 1;
  }

  if (NORM == 1 && tn >= normLo && tn < normHi) {
    float bv[NT], wnv[NT];
#pragma unroll
    for (int n2 = 0; n2 < NT; ++n2) {
      long cg = colTile + wc * WC + n2 * 16 + ll;
      bv[n2] = bias[cg];
      wnv[n2] = nw[n2 * 16 + ll];
    }
#pragma unroll
    for (int m2 = 0; m2 < 4; ++m2) {
#pragma unroll
      for (int r = 0; r < 4; ++r) {
        float vals[NT];
        float ss = 0.f;
#pragma unroll
        for (int n2 = 0; n2 < NT; ++n2) {
          vals[n2] = acc[m2][n2][r] + bv[n2];
          ss += vals[n2] * vals[n2];
        }
        ss += __shfl_xor(ss, 1);
        ss += __shfl_xor(ss, 2);
        ss += __shfl_xor(ss, 4);
        ss += __shfl_xor(ss, 8);
        float inv = rsqrtf(ss * (1.f / 64) + 1e-6f) * nscale;
        long rg = rowTile + wr * 64 + m2 * 16 + lg * 4 + r;
#pragma unroll
        for (int n2 = 0; n2 < NT; ++n2) {
          long cg = colTile + wc * WC + n2 * 16 + ll;
          outb[rg * ldc + cg] = f2bf(vals[n2] * inv * wnv[n2]);
        }
      }
    }
    return;
  }

#pragma unroll
  for (int n2 = 0; n2 < NT; ++n2) {
    long cg = colTile + wc * WC + n2 * 16 + ll;
    float bv = (cg < biasN) ? bias[cg] : 0.f;
#pragma unroll
    for (int m2 = 0; m2 < 4; ++m2) {
#pragma unroll
      for (int r = 0; r < 4; ++r) {
        long rg = rowTile + wr * 64 + m2 * 16 + lg * 4 + r;
        float v = acc[m2][n2][r] + bv;
        long idx = rg * ldc + cg;
        if (MODE == 0) {
          outb[idx] = f2bf(v);
        } else {
          int bb = (int)(rg >> 10);
          outf[idx] = xin[idx] + mods[(long)bb * MODS_LD + gateOff + cg] * v;
        }
      }
    }
  }
}

// ---------------- dual GEMM + swiglu: h = silu(A@B1+b1)*(A@B2+b2) ---------
__global__ __launch_bounds__(256, 2) void gemm_dual_swiglu(
    const u16* __restrict__ A, const u16* __restrict__ B1t, const u16* __restrict__ B2t,
    int K, int ldc, const float* __restrict__ b1, const float* __restrict__ b2, int biasN,
    u16* __restrict__ outb, int ncolChunks, int cr, int cc) {
  constexpr int BN = 64, WC = 32, NT = 2;
  __shared__ u16 As[2][128 * 64];
  __shared__ u16 B1s[2][BN * 64];
  __shared__ u16 B2s[2][BN * 64];
  int t = threadIdx.x;
  int l = t & 63, w = t >> 6;
  int wr = w >> 1, wc = w & 1;
  int lg = l >> 4, ll = l & 15;
  int rx = ll & 7;
  int tm, tn;
  xcd_tile(ncolChunks, cr, cc, tm, tn);
  long rowTile = (long)tm * 128;
  long colTile = (long)tn * BN;
  const u16* Ap = A + rowTile * K;
  const u16* B1p = B1t + colTile * K;
  const u16* B2p = B2t + colTile * K;
  int srow = t >> 3;
  int sck = ((t & 7) ^ (srow & 7)) * 8;

  auto stage = [&](int buf, int k0) {
#pragma unroll
    for (int i = 0; i < 4; ++i)
      gload_lds16(Ap + (long)(i * 32 + srow) * K + k0 + sck, &As[buf][(i * 256 + t) * 8]);
#pragma unroll
    for (int i = 0; i < 2; ++i) {
      gload_lds16(B1p + (long)(i * 32 + srow) * K + k0 + sck, &B1s[buf][(i * 256 + t) * 8]);
      gload_lds16(B2p + (long)(i * 32 + srow) * K + k0 + sck, &B2s[buf][(i * 256 + t) * 8]);
    }
  };

  const int ntk = K >> 6;
  stage(0, 0);
  if (ntk > 1) stage(1, 64);

  f32x4 acc1[4][NT] = {}, acc2[4][NT] = {};
  int cur = 0;
  for (int i = 0; i < ntk; ++i) {
    if (i + 1 < ntk) {
      asm volatile("s_waitcnt vmcnt(8)" ::: "memory");
    } else {
      asm volatile("s_waitcnt vmcnt(0)" ::: "memory");
    }
    __builtin_amdgcn_s_barrier();
    const u16* Ac = As[cur];
    const u16* B1c = B1s[cur];
    const u16* B2c = B2s[cur];
    short8 af[2][4], b1f[2][NT], b2f[2][NT];
#pragma unroll
    for (int kk = 0; kk < 2; ++kk) {
#pragma unroll
      for (int m2 = 0; m2 < 4; ++m2)
        af[kk][m2] =
            *(const short8*)&Ac[(wr * 64 + m2 * 16 + ll) * 64 + (((kk * 4 + lg) ^ rx) << 3)];
#pragma unroll
      for (int n2 = 0; n2 < NT; ++n2) {
        int off = (wc * WC + n2 * 16 + ll) * 64 + (((kk * 4 + lg) ^ rx) << 3);
        b1f[kk][n2] = *(const short8*)&B1c[off];
        b2f[kk][n2] = *(const short8*)&B2c[off];
      }
    }
    asm volatile("s_waitcnt lgkmcnt(0)" ::: "memory");
    __builtin_amdgcn_sched_barrier(0);
    __builtin_amdgcn_s_barrier();
    if (i + 2 < ntk) stage(cur, (i + 2) * 64);
    __builtin_amdgcn_s_setprio(1);
#pragma unroll
    for (int kk = 0; kk < 2; ++kk)
#pragma unroll
      for (int m2 = 0; m2 < 4; ++m2)
#pragma unroll
        for (int n2 = 0; n2 < NT; ++n2) {
          acc1[m2][n2] = __builtin_amdgcn_mfma_f32_16x16x32_bf16(af[kk][m2], b1f[kk][n2],
                                                                 acc1[m2][n2], 0, 0, 0);
          acc2[m2][n2] = __builtin_amdgcn_mfma_f32_16x16x32_bf16(af[kk][m2], b2f[kk][n2],
                                                                 acc2[m2][n2], 0, 0, 0);
        }
    __builtin_amdgcn_s_setprio(0);
    cur ^= 1;
  }
#pragma unroll
  for (int n2 = 0; n2 < NT; ++n2) {
    long cg = colTile + wc * WC + n2 * 16 + ll;
    float bv1 = (cg < biasN) ? b1[cg] : 0.f;
    float bv2 = (cg < biasN) ? b2[cg] : 0.f;
#pragma unroll
    for (int m2 = 0; m2 < 4; ++m2) {
#pragma unroll
      for (int r = 0; r < 4; ++r) {
        long rg = rowTile + wr * 64 + m2 * 16 + lg * 4 + r;
        float v1 = acc1[m2][n2][r] + bv1;
        float v2 = acc2[m2][n2][r] + bv2;
        float sg = v1 / (1.f + __expf(-v1));
        outb[rg * ldc + cg] = f2bf(sg * v2);
      }
    }
  }
}

// ---------------- flash attention v7: 8-wave QBLK=128, log2 softmax --------
__global__ __launch_bounds__(512, 2) void attn_kernel(
    const u16* __restrict__ qb, int qStride, const u16* __restrict__ kb, int kvStride,
    const u16* __restrict__ vt, const float* __restrict__ qn, u16* __restrict__ outp,
    int Nk, int Mpb) {
  __shared__ u16 Qs[128 * 64];
  __shared__ u16 Ks[2][64 * 64];
  __shared__ u16 Vs[2][64 * 64];
  __shared__ u16 Ps[8][16 * 64];
  int t = threadIdx.x, w = t >> 6, l = t & 63;
  int h = blockIdx.x, b = blockIdx.y, qt = blockIdx.z;
  int lg = l >> 4, ll = l & 15;
  int rx = ll & 7;

  const u16* Qbase = qb + ((long)(b * NN + qt * 128)) * qStride + h * 64;
  const u16* Kbase = kb + ((long)b * Mpb) * kvStride + h * 64;
  const u16* Vbase = vt + ((long)(b * 16 + h) * 64) * 1024;

  int srow = t >> 3;       // 0..63
  int schunk = t & 7;

  // stage Q (128 rows, 2 sweeps of 64 rows)
#pragma unroll
  for (int sh = 0; sh < 2; ++sh) {
    int row = sh * 64 + srow;
    int ck = schunk ^ (row & 7);
    gload_lds16(Qbase + (long)row * qStride + ck * 8, &Qs[sh * 4096 + t * 8]);
  }
  auto stageKV = [&](int buf, int kt) {
    const u16* kn = Kbase + (long)kt * 64 * kvStride;
    const u16* vn = Vbase + kt * 64;
    int ck = schunk ^ (srow & 7);
    gload_lds16(kn + (long)srow * kvStride + ck * 8, &Ks[buf][t * 8]);
    gload_lds16(vn + (long)srow * 1024 + ck * 8, &Vs[buf][t * 8]);
  };
  const int ntk = Nk >> 6;
  stageKV(0, 0);
  if (ntk > 1) stageKV(1, 1);

  short8 qf0, qf1;
  float mrun = -1e30f, ssum = 0.f;
  f32x4 o[4] = {};

  int cur = 0;
  for (int kt = 0; kt < ntk; ++kt) {
    if (kt + 1 < ntk) {
      asm volatile("s_waitcnt vmcnt(2)" ::: "memory");
    } else {
      asm volatile("s_waitcnt vmcnt(0)" ::: "memory");
    }
    __builtin_amdgcn_s_barrier();
    if (kt == 0) {
      qf0 = *(const short8*)&Qs[(w * 16 + ll) * 64 + ((lg ^ rx) << 3)];
      qf1 = *(const short8*)&Qs[(w * 16 + ll) * 64 + (((4 + lg) ^ rx) << 3)];
      // fused q RMS-norm; fold softmax scale AND log2(e) so scores are log2-domain
      float qv0[8], qv1[8], ss = 0.f;
#pragma unroll
      for (int j = 0; j < 8; ++j) {
        qv0[j] = bf2f((u16)qf0[j]);
        qv1[j] = bf2f((u16)qf1[j]);
        ss += qv0[j] * qv0[j] + qv1[j] * qv1[j];
      }
      ss += __shfl_xor(ss, 16);
      ss += __shfl_xor(ss, 32);
      float inv = rsqrtf(ss * (1.f / 64) + 1e-6f) * (0.125f * 1.44269504f);
      int d0 = (lg ^ rx) << 3, d1 = ((4 + lg) ^ rx) << 3;
      u16 t0[8], t1[8];
#pragma unroll
      for (int j = 0; j < 8; ++j) {
        t0[j] = f2bf(qv0[j] * inv * qn[d0 + j]);
        t1[j] = f2bf(qv1[j] * inv * qn[d1 + j]);
      }
      qf0 = *(short8*)t0;
      qf1 = *(short8*)t1;
    }
    const u16* Kc = Ks[cur];
    f32x4 s[4] = {};
#pragma unroll
    for (int n = 0; n < 4; ++n) {
      short8 kf0 = *(const short8*)&Kc[(n * 16 + ll) * 64 + ((lg ^ rx) << 3)];
      short8 kf1 = *(const short8*)&Kc[(n * 16 + ll) * 64 + (((4 + lg) ^ rx) << 3)];
      s[n] = __builtin_amdgcn_mfma_f32_16x16x32_bf16(kf0, qf0, s[n], 0, 0, 0);
      s[n] = __builtin_amdgcn_mfma_f32_16x16x32_bf16(kf1, qf1, s[n], 0, 0, 0);
    }
    float t0 = fmaxf(fmaxf(s[0][0], s[0][1]), fmaxf(s[0][2], s[0][3]));
    float t1 = fmaxf(fmaxf(s[1][0], s[1][1]), fmaxf(s[1][2], s[1][3]));
    float t2 = fmaxf(fmaxf(s[2][0], s[2][1]), fmaxf(s[2][2], s[2][3]));
    float t3 = fmaxf(fmaxf(s[3][0], s[3][1]), fmaxf(s[3][2], s[3][3]));
    float pm = fmaxf(fmaxf(t0, t1), fmaxf(t2, t3));
    pm = fmaxf(pm, __shfl_xor(pm, 16));
    pm = fmaxf(pm, __shfl_xor(pm, 32));
    bool resc = !__all(pm - mrun <= 8.f);
    float nm = resc ? fmaxf(mrun, pm) : mrun;
    float pn[4][4];
#pragma unroll
    for (int n = 0; n < 4; ++n)
#pragma unroll
      for (int r = 0; r < 4; ++r) pn[n][r] = exp2x(s[n][r] - nm);
    float r0 = (pn[0][0] + pn[0][1]) + (pn[0][2] + pn[0][3]);
    float r1 = (pn[1][0] + pn[1][1]) + (pn[1][2] + pn[1][3]);
    float r2 = (pn[2][0] + pn[2][1]) + (pn[2][2] + pn[2][3]);
    float r3 = (pn[3][0] + pn[3][1]) + (pn[3][2] + pn[3][3]);
    float rs = (r0 + r1) + (r2 + r3);
    rs += __shfl_xor(rs, 16);
    rs += __shfl_xor(rs, 32);
    if (resc) {
      float alpha = exp2x(mrun - nm);
      ssum = ssum * alpha + rs;
      float a0 = __shfl(alpha, lg * 4 + 0);
      float a1 = __shfl(alpha, lg * 4 + 1);
      float a2 = __shfl(alpha, lg * 4 + 2);
      float a3 = __shfl(alpha, lg * 4 + 3);
#pragma unroll
      for (int n = 0; n < 4; ++n) {
        o[n][0] *= a0;
        o[n][1] *= a1;
        o[n][2] *= a2;
        o[n][3] *= a3;
      }
    } else {
      ssum += rs;
    }
    mrun = nm;
#pragma unroll
    for (int n = 0; n < 4; ++n) {
      uint2 pkd;
      pkd.x = cvtpk_bf16(pn[n][0], pn[n][1]);
      pkd.y = cvtpk_bf16(pn[n][2], pn[n][3]);
      int gran = n * 2 + (lg >> 1);
      int perm = gran ^ rx;
      *(uint2*)&Ps[w][ll * 64 + perm * 8 + (lg & 1) * 4] = pkd;
    }
    short8 pf0 = *(const short8*)&Ps[w][ll * 64 + ((lg ^ rx) << 3)];
    short8 pf1 = *(const short8*)&Ps[w][ll * 64 + (((4 + lg) ^ rx) << 3)];
    const u16* Vc = Vs[cur];
    short8 vfr[4][2];
#pragma unroll
    for (int n = 0; n < 4; ++n) {
      vfr[n][0] = *(const short8*)&Vc[(n * 16 + ll) * 64 + ((lg ^ rx) << 3)];
      vfr[n][1] = *(const short8*)&Vc[(n * 16 + ll) * 64 + (((4 + lg) ^ rx) << 3)];
    }
    asm volatile("s_waitcnt lgkmcnt(0)" ::: "memory");
    __builtin_amdgcn_sched_barrier(0);
    __builtin_amdgcn_s_barrier();
    if (kt + 2 < ntk) stageKV(cur, kt + 2);
    __builtin_amdgcn_s_setprio(1);
#pragma unroll
    for (int n = 0; n < 4; ++n) {
      o[n] = __builtin_amdgcn_mfma_f32_16x16x32_bf16(pf0, vfr[n][0], o[n], 0, 0, 0);
      o[n] = __builtin_amdgcn_mfma_f32_16x16x32_bf16(pf1, vfr[n][1], o[n], 0, 0, 0);
    }
    __builtin_amdgcn_s_setprio(0);
    cur ^= 1;
  }
  float s0 = __shfl(ssum, lg * 4 + 0);
  float s1 = __shfl(ssum, lg * 4 + 1);
  float s2 = __shfl(ssum, lg * 4 + 2);
  float s3 = __shfl(ssum, lg * 4 + 3);
  float i0 = 1.f / s0, i1 = 1.f / s1, i2 = 1.f / s2, i3 = 1.f / s3;
#pragma unroll
  for (int n = 0; n < 4; ++n) {
    float ir[4] = {i0, i1, i2, i3};
#pragma unroll
    for (int r = 0; r < 4; ++r) {
      long row = (long)b * NN + qt * 128 + w * 16 + lg * 4 + r;
      int col = h * 64 + n * 16 + ll;
      outp[row * DD + col] = f2bf(o[n][r] * ir[r]);
    }
  }
}

extern "C" void kernel_launch(void* const* d_in, const int* in_sizes, int n_in,
                              void* d_out, int out_size, void* d_ws, size_t ws_size,
                              hipStream_t stream) {
  const float* x = (const float*)d_in[0];
  const float* src = (const float*)d_in[1];
  const float* c = (const float*)d_in[2];
  const float* ada_w = (const float*)d_in[3];
  const float* ada_b = (const float*)d_in[4];
  const float* n1_w = (const float*)d_in[5];
  const float* nc_w = (const float*)d_in[6];
  const float* n2_w = (const float*)d_in[7];
  const float* sa_qkv_w = (const float*)d_in[8];
  const float* sa_qkv_b = (const float*)d_in[9];
  const float* sa_qn_w = (const float*)d_in[10];
  const float* sa_kn_w = (const float*)d_in[11];
  const float* sa_o_w = (const float*)d_in[12];
  const float* sa_o_b = (const float*)d_in[13];
  const float* ca_q_w = (const float*)d_in[14];
  const float* ca_q_b = (const float*)d_in[15];
  const float* ca_kv_w = (const float*)d_in[16];
  const float* ca_kv_b = (const float*)d_in[17];
  const float* ca_qn_w = (const float*)d_in[18];
  const float* ca_kn_w = (const float*)d_in[19];
  const float* ca_o_w = (const float*)d_in[20];
  const float* ca_o_b = (const float*)d_in[21];
  const float* mlp_w1 = (const float*)d_in[22];
  const float* mlp_b1 = (const float*)d_in[23];
  const float* mlp_w2 = (const float*)d_in[24];
  const float* mlp_b2 = (const float*)d_in[25];
  const float* mlp_w3 = (const float*)d_in[26];
  const float* mlp_b3 = (const float*)d_in[27];
  float* out = (float*)d_out;

  char* p = (char*)d_ws;
  auto alloc = [&](size_t bytes) {
    char* r = p;
    p += (bytes + 255) & ~(size_t)255;
    return r;
  };
  float* mods = (float*)alloc(4l * 9216 * 4);
  float* part = (float*)alloc((long)MODS_KS * 4 * 9216 * 4);
  u16* qkvT = (u16*)alloc(3072l * 1024 * 2);
  u16* saoT = (u16*)alloc(1024l * 1024 * 2);
  u16* caqT = (u16*)alloc(1024l * 1024 * 2);
  u16* cakvT = (u16*)alloc(2048l * 1024 * 2);
  u16* caoT = (u16*)alloc(1024l * 1024 * 2);
  u16* w1T = (u16*)alloc(2816l * 1024 * 2);
  u16* w2T = (u16*)alloc(2816l * 1024 * 2);
  u16* w3T = (u16*)alloc(1024l * 2816 * 2);
  u16* xnb = (u16*)alloc(4096l * 1024 * 2);
  u16* srcb = (u16*)alloc(4096l * 1024 * 2);
  u16* bufA = (u16*)alloc(4096l * 3072 * 2);
  u16* bufB = (u16*)alloc(4096l * 2816 * 2);
  u16* attO = (u16*)alloc(4096l * 1024 * 2);
  u16* vtb = xnb;  // alias: xnb dead during attention

  TPack tp;
  tp.t[0] = {sa_qkv_w, qkvT, 1024, 3072, 1024, 3072, 32, 0};
  tp.t[1] = {sa_o_w, saoT, 1024, 1024, 1024, 1024, 32, 3072};
  tp.t[2] = {ca_q_w, caqT, 1024, 1024, 1024, 1024, 32, 4096};
  tp.t[3] = {ca_kv_w, cakvT, 1024, 2048, 1024, 2048, 32, 5120};
  tp.t[4] = {ca_o_w, caoT, 1024, 1024, 1024, 1024, 32, 7168};
  tp.t[5] = {mlp_w1, w1T, 1024, 2730, 1024, 2816, 32, 8192};
  tp.t[6] = {mlp_w2, w2T, 1024, 2730, 1024, 2816, 32, 11008};
  tp.t[7] = {mlp_w3, w3T, 2730, 1024, 2816, 1024, 88, 13824};
  transpose_all<<<16640, dim3(32, 8), 0, stream>>>(tp);
  cvt_bf16_kernel<<<4096, 256, 0, stream>>>(src, srcb, 4096l * 1024 / 4);
  mods_partial<<<dim3(36, MODS_KS), 256, 0, stream>>>(c, ada_w, part);
  mods_reduce<<<dim3(36, 4), 256, 0, stream>>>(part, ada_b, mods);

  // ---- self-attention sublayer (k-norm fused into qkv epilogue; q-norm in attn)
  rmsmod_kernel<<<4096, 256, 0, stream>>>(x, n1_w, mods, 0, 1024, xnb);
  gemm_bf16<0, 128, 2, 1><<<768, 256, 0, stream>>>(xnb, qkvT, 1024, 3072, sa_qkv_b, 3072, bufA,
                                                   nullptr, nullptr, nullptr, 0, 4, 16, 6,
                                                   sa_kn_w, 8, 16, 1.0f);
  vtrans_kernel<<<dim3(16, 16, 4), 256, 0, stream>>>(bufA + 2048, 3072, 1024, vtb);
  attn_kernel<<<dim3(16, 4, 8), 512, 0, stream>>>(bufA, 3072, bufA + 1024, 3072, vtb, sa_qn_w,
                                                  attO, 1024, 1024);
  gemm_bf16<1, 64, 3, 0><<<512, 256, 0, stream>>>(attO, saoT, 1024, 1024, sa_o_b, 1024, nullptr,
                                                  out, x, mods, 2048, 2, 8, 8, nullptr, 0, 0,
                                                  0.f);

  // ---- cross-attention sublayer (k-norm fused into cakv; q-norm in attn)
  rmsmod_kernel<<<4096, 256, 0, stream>>>(out, nc_w, mods, 3072, 4096, xnb);
  gemm_bf16<0, 64, 3, 0><<<512, 256, 0, stream>>>(xnb, caqT, 1024, 1024, ca_q_b, 1024, bufA,
                                                  nullptr, nullptr, nullptr, 0, 2, 8, 8,
                                                  nullptr, 0, 0, 0.f);
  gemm_bf16<0, 128, 2, 1><<<512, 256, 0, stream>>>(srcb, cakvT, 1024, 2048, ca_kv_b, 2048, bufB,
                                                   nullptr, nullptr, nullptr, 0, 2, 8, 8,
                                                   ca_kn_w, 0, 8, 1.0f);
  vtrans_kernel<<<dim3(16, 16, 4), 256, 0, stream>>>(bufB + 1024, 2048, 1024, vtb);
  attn_kernel<<<dim3(16, 4, 8), 512, 0, stream>>>(bufA, 1024, bufB, 2048, vtb, ca_qn_w, attO,
                                                  1024, 1024);
  gemm_bf16<1, 64, 3, 0><<<512, 256, 0, stream>>>(attO, caoT, 1024, 1024, ca_o_b, 1024, nullptr,
                                                  out, out, mods, 5120, 2, 8, 8, nullptr, 0, 0,
                                                  0.f);

  // ---- SwiGLU FFN sublayer: fused dual GEMM, h1 never materialized
  rmsmod_kernel<<<4096, 256, 0, stream>>>(out, n2_w, mods, 6144, 7168, xnb);
  gemm_dual_swiglu<<<1408, 256, 0, stream>>>(xnb, w1T, w2T, 1024, 2816, mlp_b1, mlp_b2, 2730,
                                             bufA, 4, 16, 11);
  gemm_bf16<1, 64, 3, 0><<<512, 256, 0, stream>>>(bufA, w3T, 2816, 1024, mlp_b3, 1024, nullptr,
                                                  out, out, mods, 8192, 2, 8, 8, nullptr, 0, 0,
                                                  0.f);
}

// Round 14
// 320.750 us; speedup vs baseline: 1.6997x; 1.0436x over previous
//
#include <hip/hip_runtime.h>

typedef unsigned short u16;
typedef __attribute__((ext_vector_type(8))) short short8;
typedef __attribute__((ext_vector_type(4))) float f32x4;

#define DD 1024
#define NN 1024
#define MODS_LD 9216

__device__ __forceinline__ float bf2f(u16 v) {
  unsigned int u = ((unsigned int)v) << 16;
  return __builtin_bit_cast(float, u);
}
__device__ __forceinline__ u16 f2bf(float f) {
  unsigned int u = __builtin_bit_cast(unsigned int, f);
  unsigned int lsb = (u >> 16) & 1;
  u += 0x7fffu + lsb;
  return (u16)(u >> 16);
}
__device__ __forceinline__ unsigned cvtpk_bf16(float a, float b) {
  unsigned r;
  asm volatile("v_cvt_pk_bf16_f32 %0, %1, %2" : "=v"(r) : "v"(a), "v"(b));
  return r;
}
__device__ __forceinline__ float exp2x(float x) {
  float r;
  asm("v_exp_f32 %0, %1" : "=v"(r) : "v"(x));
  return r;
}

__device__ __forceinline__ void gload_lds16(const u16* g, u16* l) {
  __builtin_amdgcn_global_load_lds(
      (const __attribute__((address_space(1))) unsigned int*)g,
      (__attribute__((address_space(3))) unsigned int*)l, 16, 0, 0);
}

// XCD super-tile mapping: grid = 8*cr*cc blocks; XCD c gets a cr x cc tile rect.
__device__ __forceinline__ void xcd_tile(int ncolChunks, int cr, int cc, int& tm, int& tn) {
  int id = blockIdx.x;
  int c = id & 7, i = id >> 3;
  int chunkRow = c / ncolChunks, chunkCol = c % ncolChunks;
  tm = chunkRow * cr + (i % cr);
  tn = chunkCol * cc + (i / cr);
}

// ---------------- batched weight transpose + fp32->bf16 -------------------
struct TDesc {
  const float* s;
  u16* d;
  int R, C, R2, C2, gx, start;
};
struct TPack {
  TDesc t[8];
};

__global__ void transpose_all(TPack p) {
  __shared__ float tile[32][33];
  int id = blockIdx.x;
  int k = 0;
#pragma unroll
  for (int j = 1; j < 8; ++j)
    if (id >= p.t[j].start) k = j;
  const float* src = p.t[k].s;
  u16* dst = p.t[k].d;
  int R = p.t[k].R, C = p.t[k].C, R2 = p.t[k].R2, C2 = p.t[k].C2;
  int rem = id - p.t[k].start;
  int gx = p.t[k].gx;
  int r0 = (rem % gx) * 32, c0 = (rem / gx) * 32;
  int tx = threadIdx.x, ty = threadIdx.y;
#pragma unroll
  for (int i = 0; i < 4; ++i) {
    int r = r0 + ty + i * 8, c = c0 + tx;
    tile[ty + i * 8][tx] = (r < R && c < C) ? src[(long)r * C + c] : 0.f;
  }
  __syncthreads();
#pragma unroll
  for (int i = 0; i < 4; ++i) {
    int c = c0 + ty + i * 8, r = r0 + tx;
    if (c < C2 && r < R2) dst[(long)c * R2 + r] = f2bf(tile[tx][ty + i * 8]);
  }
}

// ---------------- fp32 -> bf16 (vector) ---------------------------------
__global__ void cvt_bf16_kernel(const float* __restrict__ in, u16* __restrict__ out, long n4) {
  long i = (long)blockIdx.x * 256 + threadIdx.x;
  if (i >= n4) return;
  float4 v = *(const float4*)&in[i * 4];
  ushort4 pk = {f2bf(v.x), f2bf(v.y), f2bf(v.z), f2bf(v.w)};
  *(ushort4*)&out[i * 4] = pk;
}

// ---------------- mods matvec (silu fused, k-split, deterministic) --------
#define MODS_KS 32
__global__ __launch_bounds__(256) void mods_partial(const float* __restrict__ c,
                                                    const float* __restrict__ aw,
                                                    float* __restrict__ part) {
  __shared__ float scs[4][32];
  int j = blockIdx.x * 256 + threadIdx.x;
  int ks = blockIdx.y;
  int d0 = ks * (DD / MODS_KS);
  int t = threadIdx.x;
  if (t < 32) {
#pragma unroll
    for (int b2 = 0; b2 < 4; ++b2) {
      float v = c[b2 * DD + d0 + t];
      scs[b2][t] = v / (1.f + __expf(-v));
    }
  }
  __syncthreads();
  float a0 = 0.f, a1 = 0.f, a2 = 0.f, a3 = 0.f;
#pragma unroll 8
  for (int d = 0; d < DD / MODS_KS; ++d) {
    float w = aw[(long)(d0 + d) * MODS_LD + j];
    a0 = fmaf(scs[0][d], w, a0);
    a1 = fmaf(scs[1][d], w, a1);
    a2 = fmaf(scs[2][d], w, a2);
    a3 = fmaf(scs[3][d], w, a3);
  }
  long base = (long)ks * 4 * MODS_LD + j;
  part[base] = a0;
  part[base + MODS_LD] = a1;
  part[base + 2 * MODS_LD] = a2;
  part[base + 3 * MODS_LD] = a3;
}

__global__ __launch_bounds__(256) void mods_reduce(const float* __restrict__ part,
                                                   const float* __restrict__ ab,
                                                   float* __restrict__ mods) {
  int j = blockIdx.x * 256 + threadIdx.x;
  int b = blockIdx.y;
  float acc = ab[j];
#pragma unroll
  for (int ks = 0; ks < MODS_KS; ++ks) acc += part[((long)ks * 4 + b) * MODS_LD + j];
  mods[(long)b * MODS_LD + j] = acc;
}

// ---------------- fused RMSNorm + modulate -> bf16 ------------------------
__global__ __launch_bounds__(256) void rmsmod_kernel(const float* __restrict__ x,
                                                     const float* __restrict__ w,
                                                     const float* __restrict__ mods,
                                                     int shiftOff, int scaleOff,
                                                     u16* __restrict__ out) {
  long row = blockIdx.x;
  int b = (int)(row >> 10);
  int t = threadIdx.x;
  const float* xr = x + row * DD;
  float4 v = *(const float4*)&xr[t * 4];
  float ss = v.x * v.x + v.y * v.y + v.z * v.z + v.w * v.w;
#pragma unroll
  for (int msk = 1; msk < 64; msk <<= 1) ss += __shfl_xor(ss, msk);
  __shared__ float red[4];
  if ((t & 63) == 0) red[t >> 6] = ss;
  __syncthreads();
  float tot = red[0] + red[1] + red[2] + red[3];
  float inv = rsqrtf(tot * (1.f / DD) + 1e-6f);
  const float* mrow = mods + (long)b * MODS_LD;
  float vv[4] = {v.x, v.y, v.z, v.w};
  u16 tmp[4];
#pragma unroll
  for (int j = 0; j < 4; ++j) {
    int c = t * 4 + j;
    float rr = vv[j] * inv * w[c] * (1.f + mrow[scaleOff + c]) + mrow[shiftOff + c];
    tmp[j] = f2bf(rr);
  }
  ushort4 pk = {tmp[0], tmp[1], tmp[2], tmp[3]};
  *(ushort4*)&out[row * DD + t * 4] = pk;
}

// ---------------- GEMM: 128 x BN tiles, counted-vmcnt + T2 swizzle --------
// MODE 0: outb = bf16(acc+bias)
// MODE 1: outf = xin + gate*(acc+bias)
// NORM 1 (BN=128): tiles tn in [normLo,normHi) get per-64-head RMS-norm
// VT 1   (BN=128): tiles tn in [vLo,vHi) write TRANSPOSED into vt[(b,h),d,tok]
template <int MODE, int BN, int MINW, int NORM, int VT>
__global__ __launch_bounds__(256, MINW) void gemm_bf16(
    const u16* __restrict__ A, const u16* __restrict__ Bt, int K, int ldc,
    const float* __restrict__ bias, int biasN, u16* __restrict__ outb,
    float* __restrict__ outf, const float* __restrict__ xin,
    const float* __restrict__ mods, int gateOff, int ncolChunks, int cr, int cc,
    const float* __restrict__ nw, int normLo, int normHi, float nscale,
    u16* __restrict__ vtOut, int vLo, int vHi, int vOff) {
  constexpr int WC = BN / 2;
  constexpr int NT = WC / 16;
  constexpr int LOADS = 4 + BN / 32;
  __shared__ u16 As[2][128 * 64];
  __shared__ u16 Bs[2][BN * 64];
  int t = threadIdx.x;
  int l = t & 63, w = t >> 6;
  int wr = w >> 1, wc = w & 1;
  int lg = l >> 4, ll = l & 15;
  int rx = ll & 7;
  int tm, tn;
  xcd_tile(ncolChunks, cr, cc, tm, tn);
  long rowTile = (long)tm * 128;
  long colTile = (long)tn * BN;
  const u16* Ap = A + rowTile * K;
  const u16* Bp = Bt + colTile * K;
  int srow = t >> 3;
  int sck = ((t & 7) ^ (srow & 7)) * 8;

  auto stage = [&](int buf, int k0) {
#pragma unroll
    for (int i = 0; i < 4; ++i)
      gload_lds16(Ap + (long)(i * 32 + srow) * K + k0 + sck, &As[buf][(i * 256 + t) * 8]);
#pragma unroll
    for (int i = 0; i < BN / 32; ++i)
      gload_lds16(Bp + (long)(i * 32 + srow) * K + k0 + sck, &Bs[buf][(i * 256 + t) * 8]);
  };

  const int ntk = K >> 6;
  stage(0, 0);
  if (ntk > 1) stage(1, 64);

  f32x4 acc[4][NT] = {};
  int cur = 0;
  for (int i = 0; i < ntk; ++i) {
    if (i + 1 < ntk) {
      asm volatile("s_waitcnt vmcnt(%0)" ::"i"(LOADS) : "memory");
    } else {
      asm volatile("s_waitcnt vmcnt(0)" ::: "memory");
    }
    __builtin_amdgcn_s_barrier();
    const u16* Ac = As[cur];
    const u16* Bc = Bs[cur];
    short8 af[2][4], bfr[2][NT];
#pragma unroll
    for (int kk = 0; kk < 2; ++kk) {
#pragma unroll
      for (int m2 = 0; m2 < 4; ++m2)
        af[kk][m2] =
            *(const short8*)&Ac[(wr * 64 + m2 * 16 + ll) * 64 + (((kk * 4 + lg) ^ rx) << 3)];
#pragma unroll
      for (int n2 = 0; n2 < NT; ++n2)
        bfr[kk][n2] =
            *(const short8*)&Bc[(wc * WC + n2 * 16 + ll) * 64 + (((kk * 4 + lg) ^ rx) << 3)];
    }
    asm volatile("s_waitcnt lgkmcnt(0)" ::: "memory");
    __builtin_amdgcn_sched_barrier(0);
    __builtin_amdgcn_s_barrier();
    if (i + 2 < ntk) stage(cur, (i + 2) * 64);
    __builtin_amdgcn_s_setprio(1);
#pragma unroll
    for (int kk = 0; kk < 2; ++kk)
#pragma unroll
      for (int m2 = 0; m2 < 4; ++m2)
#pragma unroll
        for (int n2 = 0; n2 < NT; ++n2)
          acc[m2][n2] = __builtin_amdgcn_mfma_f32_16x16x32_bf16(af[kk][m2], bfr[kk][n2],
                                                                acc[m2][n2], 0, 0, 0);
    __builtin_amdgcn_s_setprio(0);
    cur ^= 1;
  }

  if (NORM == 1 && tn >= normLo && tn < normHi) {
    float bv[NT], wnv[NT];
#pragma unroll
    for (int n2 = 0; n2 < NT; ++n2) {
      long cg = colTile + wc * WC + n2 * 16 + ll;
      bv[n2] = bias[cg];
      wnv[n2] = nw[n2 * 16 + ll];
    }
#pragma unroll
    for (int m2 = 0; m2 < 4; ++m2) {
#pragma unroll
      for (int r = 0; r < 4; ++r) {
        float vals[NT];
        float ss = 0.f;
#pragma unroll
        for (int n2 = 0; n2 < NT; ++n2) {
          vals[n2] = acc[m2][n2][r] + bv[n2];
          ss += vals[n2] * vals[n2];
        }
        ss += __shfl_xor(ss, 1);
        ss += __shfl_xor(ss, 2);
        ss += __shfl_xor(ss, 4);
        ss += __shfl_xor(ss, 8);
        float inv = rsqrtf(ss * (1.f / 64) + 1e-6f) * nscale;
        long rg = rowTile + wr * 64 + m2 * 16 + lg * 4 + r;
#pragma unroll
        for (int n2 = 0; n2 < NT; ++n2) {
          long cg = colTile + wc * WC + n2 * 16 + ll;
          outb[rg * ldc + cg] = f2bf(vals[n2] * inv * wnv[n2]);
        }
      }
    }
    return;
  }

  if (VT == 1 && tn >= vLo && tn < vHi) {
    // per-wave LDS transpose (As dead), coalesced store to vt[(b,h), d, tok]
    int bblk = (int)(rowTile >> 10);
    int tokBase = (int)(rowTile & 1023) + wr * 64;
    int hGlob = (int)((colTile + wc * WC - vOff) >> 6);
    long vBase = ((long)(bblk * 16 + hGlob) * 64) * 1024;
    u16* scr = &As[0][0] + w * 1152;  // 16 rows x 72 (pad) per wave
#pragma unroll
    for (int n2 = 0; n2 < NT; ++n2) {
      long cg = colTile + wc * WC + n2 * 16 + ll;
      float bv = bias[cg];
#pragma unroll
      for (int m2 = 0; m2 < 4; ++m2)
#pragma unroll
        for (int r = 0; r < 4; ++r)
          scr[ll * 72 + m2 * 16 + lg * 4 + r] = f2bf(acc[m2][n2][r] + bv);
      asm volatile("s_waitcnt lgkmcnt(0)" ::: "memory");
      __builtin_amdgcn_sched_barrier(0);
      int dloc = l >> 2, tko = (l & 3) * 16;
      short8 v0 = *(const short8*)&scr[dloc * 72 + tko];
      short8 v1 = *(const short8*)&scr[dloc * 72 + tko + 8];
      asm volatile("s_waitcnt lgkmcnt(0)" ::: "memory");
      __builtin_amdgcn_sched_barrier(0);
      u16* dst = vtOut + vBase + (long)(n2 * 16 + dloc) * 1024 + tokBase + tko;
      *(short8*)dst = v0;
      *(short8*)(dst + 8) = v1;
    }
    return;
  }

#pragma unroll
  for (int n2 = 0; n2 < NT; ++n2) {
    long cg = colTile + wc * WC + n2 * 16 + ll;
    float bv = (cg < biasN) ? bias[cg] : 0.f;
#pragma unroll
    for (int m2 = 0; m2 < 4; ++m2) {
#pragma unroll
      for (int r = 0; r < 4; ++r) {
        long rg = rowTile + wr * 64 + m2 * 16 + lg * 4 + r;
        float v = acc[m2][n2][r] + bv;
        long idx = rg * ldc + cg;
        if (MODE == 0) {
          outb[idx] = f2bf(v);
        } else {
          int bb = (int)(rg >> 10);
          outf[idx] = xin[idx] + mods[(long)bb * MODS_LD + gateOff + cg] * v;
        }
      }
    }
  }
}

// ---------------- dual GEMM + swiglu: h = silu(A@B1+b1)*(A@B2+b2) ---------
__global__ __launch_bounds__(256, 2) void gemm_dual_swiglu(
    const u16* __restrict__ A, const u16* __restrict__ B1t, const u16* __restrict__ B2t,
    int K, int ldc, const float* __restrict__ b1, const float* __restrict__ b2, int biasN,
    u16* __restrict__ outb, int ncolChunks, int cr, int cc) {
  constexpr int BN = 64, WC = 32, NT = 2;
  __shared__ u16 As[2][128 * 64];
  __shared__ u16 B1s[2][BN * 64];
  __shared__ u16 B2s[2][BN * 64];
  int t = threadIdx.x;
  int l = t & 63, w = t >> 6;
  int wr = w >> 1, wc = w & 1;
  int lg = l >> 4, ll = l & 15;
  int rx = ll & 7;
  int tm, tn;
  xcd_tile(ncolChunks, cr, cc, tm, tn);
  long rowTile = (long)tm * 128;
  long colTile = (long)tn * BN;
  const u16* Ap = A + rowTile * K;
  const u16* B1p = B1t + colTile * K;
  const u16* B2p = B2t + colTile * K;
  int srow = t >> 3;
  int sck = ((t & 7) ^ (srow & 7)) * 8;

  auto stage = [&](int buf, int k0) {
#pragma unroll
    for (int i = 0; i < 4; ++i)
      gload_lds16(Ap + (long)(i * 32 + srow) * K + k0 + sck, &As[buf][(i * 256 + t) * 8]);
#pragma unroll
    for (int i = 0; i < 2; ++i) {
      gload_lds16(B1p + (long)(i * 32 + srow) * K + k0 + sck, &B1s[buf][(i * 256 + t) * 8]);
      gload_lds16(B2p + (long)(i * 32 + srow) * K + k0 + sck, &B2s[buf][(i * 256 + t) * 8]);
    }
  };

  const int ntk = K >> 6;
  stage(0, 0);
  if (ntk > 1) stage(1, 64);

  f32x4 acc1[4][NT] = {}, acc2[4][NT] = {};
  int cur = 0;
  for (int i = 0; i < ntk; ++i) {
    if (i + 1 < ntk) {
      asm volatile("s_waitcnt vmcnt(8)" ::: "memory");
    } else {
      asm volatile("s_waitcnt vmcnt(0)" ::: "memory");
    }
    __builtin_amdgcn_s_barrier();
    const u16* Ac = As[cur];
    const u16* B1c = B1s[cur];
    const u16* B2c = B2s[cur];
    short8 af[2][4], b1f[2][NT], b2f[2][NT];
#pragma unroll
    for (int kk = 0; kk < 2; ++kk) {
#pragma unroll
      for (int m2 = 0; m2 < 4; ++m2)
        af[kk][m2] =
            *(const short8*)&Ac[(wr * 64 + m2 * 16 + ll) * 64 + (((kk * 4 + lg) ^ rx) << 3)];
#pragma unroll
      for (int n2 = 0; n2 < NT; ++n2) {
        int off = (wc * WC + n2 * 16 + ll) * 64 + (((kk * 4 + lg) ^ rx) << 3);
        b1f[kk][n2] = *(const short8*)&B1c[off];
        b2f[kk][n2] = *(const short8*)&B2c[off];
      }
    }
    asm volatile("s_waitcnt lgkmcnt(0)" ::: "memory");
    __builtin_amdgcn_sched_barrier(0);
    __builtin_amdgcn_s_barrier();
    if (i + 2 < ntk) stage(cur, (i + 2) * 64);
    __builtin_amdgcn_s_setprio(1);
#pragma unroll
    for (int kk = 0; kk < 2; ++kk)
#pragma unroll
      for (int m2 = 0; m2 < 4; ++m2)
#pragma unroll
        for (int n2 = 0; n2 < NT; ++n2) {
          acc1[m2][n2] = __builtin_amdgcn_mfma_f32_16x16x32_bf16(af[kk][m2], b1f[kk][n2],
                                                                 acc1[m2][n2], 0, 0, 0);
          acc2[m2][n2] = __builtin_amdgcn_mfma_f32_16x16x32_bf16(af[kk][m2], b2f[kk][n2],
                                                                 acc2[m2][n2], 0, 0, 0);
        }
    __builtin_amdgcn_s_setprio(0);
    cur ^= 1;
  }
#pragma unroll
  for (int n2 = 0; n2 < NT; ++n2) {
    long cg = colTile + wc * WC + n2 * 16 + ll;
    float bv1 = (cg < biasN) ? b1[cg] : 0.f;
    float bv2 = (cg < biasN) ? b2[cg] : 0.f;
#pragma unroll
    for (int m2 = 0; m2 < 4; ++m2) {
#pragma unroll
      for (int r = 0; r < 4; ++r) {
        long rg = rowTile + wr * 64 + m2 * 16 + lg * 4 + r;
        float v1 = acc1[m2][n2][r] + bv1;
        float v2 = acc2[m2][n2][r] + bv2;
        float sg = v1 / (1.f + __expf(-v1));
        outb[rg * ldc + cg] = f2bf(sg * v2);
      }
    }
  }
}

// ---------------- flash attention v7: 8-wave QBLK=128, log2 softmax --------
__global__ __launch_bounds__(512, 2) void attn_kernel(
    const u16* __restrict__ qb, int qStride, const u16* __restrict__ kb, int kvStride,
    const u16* __restrict__ vt, const float* __restrict__ qn, u16* __restrict__ outp,
    int Nk, int Mpb) {
  __shared__ u16 Qs[128 * 64];
  __shared__ u16 Ks[2][64 * 64];
  __shared__ u16 Vs[2][64 * 64];
  __shared__ u16 Ps[8][16 * 64];
  int t = threadIdx.x, w = t >> 6, l = t & 63;
  int h = blockIdx.x, b = blockIdx.y, qt = blockIdx.z;
  int lg = l >> 4, ll = l & 15;
  int rx = ll & 7;

  const u16* Qbase = qb + ((long)(b * NN + qt * 128)) * qStride + h * 64;
  const u16* Kbase = kb + ((long)b * Mpb) * kvStride + h * 64;
  const u16* Vbase = vt + ((long)(b * 16 + h) * 64) * 1024;

  int srow = t >> 3;
  int schunk = t & 7;

#pragma unroll
  for (int sh = 0; sh < 2; ++sh) {
    int row = sh * 64 + srow;
    int ck = schunk ^ (row & 7);
    gload_lds16(Qbase + (long)row * qStride + ck * 8, &Qs[sh * 4096 + t * 8]);
  }
  auto stageKV = [&](int buf, int kt) {
    const u16* kn = Kbase + (long)kt * 64 * kvStride;
    const u16* vn = Vbase + kt * 64;
    int ck = schunk ^ (srow & 7);
    gload_lds16(kn + (long)srow * kvStride + ck * 8, &Ks[buf][t * 8]);
    gload_lds16(vn + (long)srow * 1024 + ck * 8, &Vs[buf][t * 8]);
  };
  const int ntk = Nk >> 6;
  stageKV(0, 0);
  if (ntk > 1) stageKV(1, 1);

  short8 qf0, qf1;
  float mrun = -1e30f, ssum = 0.f;
  f32x4 o[4] = {};

  int cur = 0;
  for (int kt = 0; kt < ntk; ++kt) {
    if (kt + 1 < ntk) {
      asm volatile("s_waitcnt vmcnt(2)" ::: "memory");
    } else {
      asm volatile("s_waitcnt vmcnt(0)" ::: "memory");
    }
    __builtin_amdgcn_s_barrier();
    if (kt == 0) {
      qf0 = *(const short8*)&Qs[(w * 16 + ll) * 64 + ((lg ^ rx) << 3)];
      qf1 = *(const short8*)&Qs[(w * 16 + ll) * 64 + (((4 + lg) ^ rx) << 3)];
      float qv0[8], qv1[8], ss = 0.f;
#pragma unroll
      for (int j = 0; j < 8; ++j) {
        qv0[j] = bf2f((u16)qf0[j]);
        qv1[j] = bf2f((u16)qf1[j]);
        ss += qv0[j] * qv0[j] + qv1[j] * qv1[j];
      }
      ss += __shfl_xor(ss, 16);
      ss += __shfl_xor(ss, 32);
      float inv = rsqrtf(ss * (1.f / 64) + 1e-6f) * (0.125f * 1.44269504f);
      int d0 = (lg ^ rx) << 3, d1 = ((4 + lg) ^ rx) << 3;
      u16 t0[8], t1[8];
#pragma unroll
      for (int j = 0; j < 8; ++j) {
        t0[j] = f2bf(qv0[j] * inv * qn[d0 + j]);
        t1[j] = f2bf(qv1[j] * inv * qn[d1 + j]);
      }
      qf0 = *(short8*)t0;
      qf1 = *(short8*)t1;
    }
    const u16* Kc = Ks[cur];
    f32x4 s[4] = {};
#pragma unroll
    for (int n = 0; n < 4; ++n) {
      short8 kf0 = *(const short8*)&Kc[(n * 16 + ll) * 64 + ((lg ^ rx) << 3)];
      short8 kf1 = *(const short8*)&Kc[(n * 16 + ll) * 64 + (((4 + lg) ^ rx) << 3)];
      s[n] = __builtin_amdgcn_mfma_f32_16x16x32_bf16(kf0, qf0, s[n], 0, 0, 0);
      s[n] = __builtin_amdgcn_mfma_f32_16x16x32_bf16(kf1, qf1, s[n], 0, 0, 0);
    }
    float t0 = fmaxf(fmaxf(s[0][0], s[0][1]), fmaxf(s[0][2], s[0][3]));
    float t1 = fmaxf(fmaxf(s[1][0], s[1][1]), fmaxf(s[1][2], s[1][3]));
    float t2 = fmaxf(fmaxf(s[2][0], s[2][1]), fmaxf(s[2][2], s[2][3]));
    float t3 = fmaxf(fmaxf(s[3][0], s[3][1]), fmaxf(s[3][2], s[3][3]));
    float pm = fmaxf(fmaxf(t0, t1), fmaxf(t2, t3));
    pm = fmaxf(pm, __shfl_xor(pm, 16));
    pm = fmaxf(pm, __shfl_xor(pm, 32));
    bool resc = !__all(pm - mrun <= 8.f);
    float nm = resc ? fmaxf(mrun, pm) : mrun;
    float pn[4][4];
#pragma unroll
    for (int n = 0; n < 4; ++n)
#pragma unroll
      for (int r = 0; r < 4; ++r) pn[n][r] = exp2x(s[n][r] - nm);
    float r0 = (pn[0][0] + pn[0][1]) + (pn[0][2] + pn[0][3]);
    float r1 = (pn[1][0] + pn[1][1]) + (pn[1][2] + pn[1][3]);
    float r2 = (pn[2][0] + pn[2][1]) + (pn[2][2] + pn[2][3]);
    float r3 = (pn[3][0] + pn[3][1]) + (pn[3][2] + pn[3][3]);
    float rs = (r0 + r1) + (r2 + r3);
    rs += __shfl_xor(rs, 16);
    rs += __shfl_xor(rs, 32);
    if (resc) {
      float alpha = exp2x(mrun - nm);
      ssum = ssum * alpha + rs;
      float a0 = __shfl(alpha, lg * 4 + 0);
      float a1 = __shfl(alpha, lg * 4 + 1);
      float a2 = __shfl(alpha, lg * 4 + 2);
      float a3 = __shfl(alpha, lg * 4 + 3);
#pragma unroll
      for (int n = 0; n < 4; ++n) {
        o[n][0] *= a0;
        o[n][1] *= a1;
        o[n][2] *= a2;
        o[n][3] *= a3;
      }
    } else {
      ssum += rs;
    }
    mrun = nm;
#pragma unroll
    for (int n = 0; n < 4; ++n) {
      uint2 pkd;
      pkd.x = cvtpk_bf16(pn[n][0], pn[n][1]);
      pkd.y = cvtpk_bf16(pn[n][2], pn[n][3]);
      int gran = n * 2 + (lg >> 1);
      int perm = gran ^ rx;
      *(uint2*)&Ps[w][ll * 64 + perm * 8 + (lg & 1) * 4] = pkd;
    }
    short8 pf0 = *(const short8*)&Ps[w][ll * 64 + ((lg ^ rx) << 3)];
    short8 pf1 = *(const short8*)&Ps[w][ll * 64 + (((4 + lg) ^ rx) << 3)];
    const u16* Vc = Vs[cur];
    short8 vfr[4][2];
#pragma unroll
    for (int n = 0; n < 4; ++n) {
      vfr[n][0] = *(const short8*)&Vc[(n * 16 + ll) * 64 + ((lg ^ rx) << 3)];
      vfr[n][1] = *(const short8*)&Vc[(n * 16 + ll) * 64 + (((4 + lg) ^ rx) << 3)];
    }
    asm volatile("s_waitcnt lgkmcnt(0)" ::: "memory");
    __builtin_amdgcn_sched_barrier(0);
    __builtin_amdgcn_s_barrier();
    if (kt + 2 < ntk) stageKV(cur, kt + 2);
    __builtin_amdgcn_s_setprio(1);
#pragma unroll
    for (int n = 0; n < 4; ++n) {
      o[n] = __builtin_amdgcn_mfma_f32_16x16x32_bf16(pf0, vfr[n][0], o[n], 0, 0, 0);
      o[n] = __builtin_amdgcn_mfma_f32_16x16x32_bf16(pf1, vfr[n][1], o[n], 0, 0, 0);
    }
    __builtin_amdgcn_s_setprio(0);
    cur ^= 1;
  }
  float s0 = __shfl(ssum, lg * 4 + 0);
  float s1 = __shfl(ssum, lg * 4 + 1);
  float s2 = __shfl(ssum, lg * 4 + 2);
  float s3 = __shfl(ssum, lg * 4 + 3);
  float i0 = 1.f / s0, i1 = 1.f / s1, i2 = 1.f / s2, i3 = 1.f / s3;
#pragma unroll
  for (int n = 0; n < 4; ++n) {
    float ir[4] = {i0, i1, i2, i3};
#pragma unroll
    for (int r = 0; r < 4; ++r) {
      long row = (long)b * NN + qt * 128 + w * 16 + lg * 4 + r;
      int col = h * 64 + n * 16 + ll;
      outp[row * DD + col] = f2bf(o[n][r] * ir[r]);
    }
  }
}

extern "C" void kernel_launch(void* const* d_in, const int* in_sizes, int n_in,
                              void* d_out, int out_size, void* d_ws, size_t ws_size,
                              hipStream_t stream) {
  const float* x = (const float*)d_in[0];
  const float* src = (const float*)d_in[1];
  const float* c = (const float*)d_in[2];
  const float* ada_w = (const float*)d_in[3];
  const float* ada_b = (const float*)d_in[4];
  const float* n1_w = (const float*)d_in[5];
  const float* nc_w = (const float*)d_in[6];
  const float* n2_w = (const float*)d_in[7];
  const float* sa_qkv_w = (const float*)d_in[8];
  const float* sa_qkv_b = (const float*)d_in[9];
  const float* sa_qn_w = (const float*)d_in[10];
  const float* sa_kn_w = (const float*)d_in[11];
  const float* sa_o_w = (const float*)d_in[12];
  const float* sa_o_b = (const float*)d_in[13];
  const float* ca_q_w = (const float*)d_in[14];
  const float* ca_q_b = (const float*)d_in[15];
  const float* ca_kv_w = (const float*)d_in[16];
  const float* ca_kv_b = (const float*)d_in[17];
  const float* ca_qn_w = (const float*)d_in[18];
  const float* ca_kn_w = (const float*)d_in[19];
  const float* ca_o_w = (const float*)d_in[20];
  const float* ca_o_b = (const float*)d_in[21];
  const float* mlp_w1 = (const float*)d_in[22];
  const float* mlp_b1 = (const float*)d_in[23];
  const float* mlp_w2 = (const float*)d_in[24];
  const float* mlp_b2 = (const float*)d_in[25];
  const float* mlp_w3 = (const float*)d_in[26];
  const float* mlp_b3 = (const float*)d_in[27];
  float* out = (float*)d_out;

  char* p = (char*)d_ws;
  auto alloc = [&](size_t bytes) {
    char* r = p;
    p += (bytes + 255) & ~(size_t)255;
    return r;
  };
  float* mods = (float*)alloc(4l * 9216 * 4);
  float* part = (float*)alloc((long)MODS_KS * 4 * 9216 * 4);
  u16* qkvT = (u16*)alloc(3072l * 1024 * 2);
  u16* saoT = (u16*)alloc(1024l * 1024 * 2);
  u16* caqT = (u16*)alloc(1024l * 1024 * 2);
  u16* cakvT = (u16*)alloc(2048l * 1024 * 2);
  u16* caoT = (u16*)alloc(1024l * 1024 * 2);
  u16* w1T = (u16*)alloc(2816l * 1024 * 2);
  u16* w2T = (u16*)alloc(2816l * 1024 * 2);
  u16* w3T = (u16*)alloc(1024l * 2816 * 2);
  u16* xnb = (u16*)alloc(4096l * 1024 * 2);
  u16* srcb = (u16*)alloc(4096l * 1024 * 2);
  u16* bufA = (u16*)alloc(4096l * 3072 * 2);
  u16* bufB = (u16*)alloc(4096l * 2048 * 2);
  u16* attO = (u16*)alloc(4096l * 1024 * 2);
  u16* vtb = (u16*)alloc(4096l * 1024 * 2);  // dedicated: written inside qkv/cakv GEMMs

  TPack tp;
  tp.t[0] = {sa_qkv_w, qkvT, 1024, 3072, 1024, 3072, 32, 0};
  tp.t[1] = {sa_o_w, saoT, 1024, 1024, 1024, 1024, 32, 3072};
  tp.t[2] = {ca_q_w, caqT, 1024, 1024, 1024, 1024, 32, 4096};
  tp.t[3] = {ca_kv_w, cakvT, 1024, 2048, 1024, 2048, 32, 5120};
  tp.t[4] = {ca_o_w, caoT, 1024, 1024, 1024, 1024, 32, 7168};
  tp.t[5] = {mlp_w1, w1T, 1024, 2730, 1024, 2816, 32, 8192};
  tp.t[6] = {mlp_w2, w2T, 1024, 2730, 1024, 2816, 32, 11008};
  tp.t[7] = {mlp_w3, w3T, 2730, 1024, 2816, 1024, 88, 13824};
  transpose_all<<<16640, dim3(32, 8), 0, stream>>>(tp);
  cvt_bf16_kernel<<<4096, 256, 0, stream>>>(src, srcb, 4096l * 1024 / 4);
  mods_partial<<<dim3(36, MODS_KS), 256, 0, stream>>>(c, ada_w, part);
  mods_reduce<<<dim3(36, 4), 256, 0, stream>>>(part, ada_b, mods);

  // ---- self-attention sublayer (k-norm + V-transpose fused into qkv)
  rmsmod_kernel<<<4096, 256, 0, stream>>>(x, n1_w, mods, 0, 1024, xnb);
  gemm_bf16<0, 128, 2, 1, 1><<<768, 256, 0, stream>>>(
      xnb, qkvT, 1024, 3072, sa_qkv_b, 3072, bufA, nullptr, nullptr, nullptr, 0, 4, 16, 6,
      sa_kn_w, 8, 16, 1.0f, vtb, 16, 24, 2048);
  attn_kernel<<<dim3(16, 4, 8), 512, 0, stream>>>(bufA, 3072, bufA + 1024, 3072, vtb, sa_qn_w,
                                                  attO, 1024, 1024);
  gemm_bf16<1, 64, 3, 0, 0><<<512, 256, 0, stream>>>(
      attO, saoT, 1024, 1024, sa_o_b, 1024, nullptr, out, x, mods, 2048, 2, 8, 8, nullptr, 0,
      0, 0.f, nullptr, 0, 0, 0);

  // ---- cross-attention sublayer (k-norm + V-transpose fused into cakv)
  rmsmod_kernel<<<4096, 256, 0, stream>>>(out, nc_w, mods, 3072, 4096, xnb);
  gemm_bf16<0, 64, 3, 0, 0><<<512, 256, 0, stream>>>(
      xnb, caqT, 1024, 1024, ca_q_b, 1024, bufA, nullptr, nullptr, nullptr, 0, 2, 8, 8,
      nullptr, 0, 0, 0.f, nullptr, 0, 0, 0);
  gemm_bf16<0, 128, 2, 1, 1><<<512, 256, 0, stream>>>(
      srcb, cakvT, 1024, 2048, ca_kv_b, 2048, bufB, nullptr, nullptr, nullptr, 0, 2, 8, 8,
      ca_kn_w, 0, 8, 1.0f, vtb, 8, 16, 1024);
  attn_kernel<<<dim3(16, 4, 8), 512, 0, stream>>>(bufA, 1024, bufB, 2048, vtb, ca_qn_w, attO,
                                                  1024, 1024);
  gemm_bf16<1, 64, 3, 0, 0><<<512, 256, 0, stream>>>(
      attO, caoT, 1024, 1024, ca_o_b, 1024, nullptr, out, out, mods, 5120, 2, 8, 8, nullptr,
      0, 0, 0.f, nullptr, 0, 0, 0);

  // ---- SwiGLU FFN sublayer: fused dual GEMM, h1 never materialized
  rmsmod_kernel<<<4096, 256, 0, stream>>>(out, n2_w, mods, 6144, 7168, xnb);
  gemm_dual_swiglu<<<1408, 256, 0, stream>>>(xnb, w1T, w2T, 1024, 2816, mlp_b1, mlp_b2, 2730,
                                             bufA, 4, 16, 11);
  gemm_bf16<1, 64, 3, 0, 0><<<512, 256, 0, stream>>>(
      bufA, w3T, 2816, 1024, mlp_b3, 1024, nullptr, out, out, mods, 8192, 2, 8, 8, nullptr, 0,
      0, 0.f, nullptr, 0, 0, 0);
}